// Round 1
// baseline (5553.876 us; speedup 1.0000x reference)
//
#include <hip/hip_runtime.h>

#define NB 8
#define NN 4096
#define KK 20
#define CFEAT 64
#define CCAT 144
#define CHN 64
#define NHEAD 8
#define DKK 32
#define DVV 16
#define NQC 256
#define EPSV 1e-5f
#define BNTOT (NB*NN)      /* 32768 */
#define ITEMS (BNTOT*KK)   /* 655360 */

// ---------- helpers ----------

__device__ __forceinline__ float wred(float v) {
#pragma unroll
  for (int off = 32; off > 0; off >>= 1) v += __shfl_down(v, off);
  return v;
}

__device__ __forceinline__ float dot144(const float* __restrict__ w, const float* fc) {
  float a0 = 0.f, a1 = 0.f, a2 = 0.f, a3 = 0.f;
#pragma unroll
  for (int c = 0; c < CCAT; c += 4) {
    a0 = fmaf(w[c + 0], fc[c + 0], a0);
    a1 = fmaf(w[c + 1], fc[c + 1], a1);
    a2 = fmaf(w[c + 2], fc[c + 2], a2);
    a3 = fmaf(w[c + 3], fc[c + 3], a3);
  }
  return (a0 + a1) + (a2 + a3);
}

__device__ __forceinline__ void build_fcat(
    const float4* __restrict__ xyz4, const float* __restrict__ feat,
    const int* __restrict__ idxb, const float* __restrict__ Wh,
    int bn, int b, int k, float* fc)
{
  int nb = idxb[(size_t)bn * KK + k];
  const float* fme = feat + (size_t)bn * CFEAT;
  const float* fnb = feat + ((size_t)b * NN + nb) * CFEAT;
#pragma unroll
  for (int c = 0; c < CFEAT; c += 4) {
    float4 a = *(const float4*)(fnb + c);
    float4 m = *(const float4*)(fme + c);
    fc[c + 0] = a.x - m.x; fc[c + 1] = a.y - m.y;
    fc[c + 2] = a.z - m.z; fc[c + 3] = a.w - m.w;
    fc[CFEAT + c + 0] = m.x; fc[CFEAT + c + 1] = m.y;
    fc[CFEAT + c + 2] = m.z; fc[CFEAT + c + 3] = m.w;
  }
  float4 pn = xyz4[(size_t)b * NN + nb];
  float4 pm = xyz4[bn];
  float rx = pn.x - pm.x, ry = pn.y - pm.y, rz = pn.z - pm.z;
#pragma unroll
  for (int v = 0; v < DVV; ++v)
    fc[2 * CFEAT + v] = Wh[v * 3 + 0] * rx + Wh[v * 3 + 1] * ry + Wh[v * 3 + 2] * rz;
}

// ---------- kernels ----------

// deinterleave x -> xyz4 (with |p|^2 in .w), feat; write xyz to d_out
__global__ void __launch_bounds__(256) k_prep(const float* __restrict__ x,
                                              float4* __restrict__ xyz4,
                                              float* __restrict__ feat,
                                              float* __restrict__ outp)
{
  int i = blockIdx.x * 256 + threadIdx.x;           // b*N+n, grid exact
  const float* xr = x + (size_t)i * 67;
  float a = xr[0], b = xr[1], c = xr[2];
  xyz4[i] = make_float4(a, b, c, a * a + b * b + c * c);
  outp[i * 3 + 0] = a; outp[i * 3 + 1] = b; outp[i * 3 + 2] = c;
  float* fd = feat + (size_t)i * CFEAT;
#pragma unroll
  for (int cc = 0; cc < CFEAT; ++cc) fd[cc] = xr[3 + cc];
}

// exact K=20 nearest neighbors per point (per batch), strict-< keeps lowest index on ties
__global__ void __launch_bounds__(256) k_knn(const float4* __restrict__ xyz4,
                                             int* __restrict__ idxb)
{
  int b = blockIdx.x >> 4;
  int n = ((blockIdx.x & 15) << 8) + threadIdx.x;
  const float4* pts = xyz4 + (size_t)b * NN;
  float4 me = pts[n];
  float bd[KK]; int bi[KK];
#pragma unroll
  for (int j = 0; j < KK; ++j) { bd[j] = 3.4e38f; bi[j] = -1; }
  for (int m = 0; m < NN; ++m) {
    float4 p = pts[m];                 // wave-uniform -> scalar load
    float dot = me.x * p.x + me.y * p.y + me.z * p.z;
    float d = me.w + p.w - 2.f * dot;
    if (d < bd[KK - 1]) {
      bd[KK - 1] = d; bi[KK - 1] = m;
#pragma unroll
      for (int j = KK - 1; j > 0; --j) {
        if (bd[j] < bd[j - 1]) {
          float td = bd[j]; bd[j] = bd[j - 1]; bd[j - 1] = td;
          int ti = bi[j]; bi[j] = bi[j - 1]; bi[j - 1] = ti;
        }
      }
    }
  }
  int* op = idxb + ((size_t)b * NN + n) * KK;
#pragma unroll
  for (int j = 0; j < KK; ++j) op[j] = bi[j];
}

// stats of t1 = W1@fcat (64ch) and tv = Wv@fcat (16ch) over all (b,n,k)
__global__ void __launch_bounds__(256, 2) k_s1(
    const float4* __restrict__ xyz4, const float* __restrict__ feat,
    const int* __restrict__ idxb, const float* __restrict__ W1,
    const float* __restrict__ Wv, const float* __restrict__ Wh,
    float* __restrict__ st1)
{
  int t = blockIdx.x * 256 + threadIdx.x;           // exact ITEMS
  int bn = t / KK, k = t - bn * KK, b = bn >> 12;
  float fc[CCAT];
  build_fcat(xyz4, feat, idxb, Wh, bn, b, k, fc);
  float* slot = st1 + (blockIdx.x & 63) * 160;
  int lane = threadIdx.x & 63;
  for (int o = 0; o < CHN; ++o) {
    float v = dot144(W1 + o * CCAT, fc);
    float s = wred(v), s2 = wred(v * v);
    if (lane == 0) { atomicAdd(&slot[o], s); atomicAdd(&slot[CHN + o], s2); }
  }
  for (int o = 0; o < DVV; ++o) {
    float v = dot144(Wv + o * CCAT, fc);
    float s = wred(v), s2 = wred(v * v);
    if (lane == 0) { atomicAdd(&slot[128 + o], s); atomicAdd(&slot[128 + DVV + o], s2); }
  }
}

__global__ void k_red1(const float* __restrict__ st1, const float* __restrict__ g1,
                       const float* __restrict__ b1, const float* __restrict__ gv,
                       const float* __restrict__ bv, float* __restrict__ par)
{
  int o = threadIdx.x;
  const float inv = 1.f / (float)ITEMS;
  if (o < 64) {
    float s = 0.f, s2 = 0.f;
    for (int j = 0; j < 64; ++j) { s += st1[j * 160 + o]; s2 += st1[j * 160 + 64 + o]; }
    float mu = s * inv, var = s2 * inv - mu * mu;
    float a = g1[o] * rsqrtf(var + EPSV);
    par[o] = a; par[64 + o] = b1[o] - mu * a;
  } else if (o < 80) {
    int v = o - 64;
    float s = 0.f, s2 = 0.f;
    for (int j = 0; j < 64; ++j) { s += st1[j * 160 + 128 + v]; s2 += st1[j * 160 + 144 + v]; }
    float mu = s * inv, var = s2 * inv - mu * mu;
    float a = gv[v] * rsqrtf(var + EPSV);
    par[128 + v] = a; par[144 + v] = bv[v] - mu * a;
  }
}

// stats of t2 = W2@relu(bn1(W1@fcat)); column-wise accumulation keeps h1 scalar
__global__ void __launch_bounds__(256, 2) k_s2(
    const float4* __restrict__ xyz4, const float* __restrict__ feat,
    const int* __restrict__ idxb, const float* __restrict__ W1,
    const float* __restrict__ W2, const float* __restrict__ Wh,
    const float* __restrict__ par, float* __restrict__ st2)
{
  int t = blockIdx.x * 256 + threadIdx.x;
  int bn = t / KK, k = t - bn * KK, b = bn >> 12;
  float fc[CCAT];
  build_fcat(xyz4, feat, idxb, Wh, bn, b, k, fc);
  float acc[CHN];
#pragma unroll
  for (int o = 0; o < CHN; ++o) acc[o] = 0.f;
  for (int c = 0; c < CHN; ++c) {
    float t1 = dot144(W1 + c * CCAT, fc);
    float h1 = fmaxf(fmaf(t1, par[c], par[64 + c]), 0.f);
    const float* w2c = W2 + c;
#pragma unroll
    for (int o = 0; o < CHN; ++o) acc[o] = fmaf(w2c[o * CHN], h1, acc[o]);
  }
  float* slot = st2 + (blockIdx.x & 63) * 128;
  int lane = threadIdx.x & 63;
#pragma unroll
  for (int o = 0; o < CHN; ++o) {
    float s = wred(acc[o]), s2 = wred(acc[o] * acc[o]);
    if (lane == 0) { atomicAdd(&slot[o], s); atomicAdd(&slot[64 + o], s2); }
  }
}

__global__ void k_red2(const float* __restrict__ st2, const float* __restrict__ g2,
                       const float* __restrict__ b2, float* __restrict__ par)
{
  int o = threadIdx.x; // 64
  float s = 0.f, s2 = 0.f;
  for (int j = 0; j < 64; ++j) { s += st2[j * 128 + o]; s2 += st2[j * 128 + 64 + o]; }
  const float inv = 1.f / (float)ITEMS;
  float mu = s * inv, var = s2 * inv - mu * mu;
  float a = g2[o] * rsqrtf(var + EPSV);
  par[160 + o] = a; par[224 + o] = b2[o] - mu * a;
}

// main pass: h2, fq=max_k h2 -> ws; logits+v -> softmax over k -> kv -> ws
#define P3P 12
__global__ void __launch_bounds__(256, 2) k_p3(
    const float4* __restrict__ xyz4, const float* __restrict__ feat,
    const int* __restrict__ idxb, const float* __restrict__ W1,
    const float* __restrict__ W2, const float* __restrict__ Wk,
    const float* __restrict__ Wv, const float* __restrict__ Wh,
    const float* __restrict__ par, float* __restrict__ fqg, float* __restrict__ kvg)
{
  __shared__ float sl[P3P][KK][DKK + 1];
  __shared__ float sv[P3P][KK][DVV + 1];
  __shared__ unsigned sfq[P3P][CHN];
  __shared__ float sm[P3P][DKK], ssi[P3P][DKK];
  int tid = threadIdx.x;
  int npts = min(P3P, BNTOT - blockIdx.x * P3P);
  for (int i = tid; i < P3P * CHN; i += 256) ((unsigned*)sfq)[i] = 0u;
  __syncthreads();
  int p = tid / KK, k = tid - p * KK;
  int bn = blockIdx.x * P3P + p;
  bool act = (tid < 240) && (p < npts);
  if (act) {
    int b = bn >> 12;
    float fc[CCAT];
    build_fcat(xyz4, feat, idxb, Wh, bn, b, k, fc);
    float acc[CHN];
#pragma unroll
    for (int o = 0; o < CHN; ++o) acc[o] = 0.f;
    for (int c = 0; c < CHN; ++c) {
      float t1 = dot144(W1 + c * CCAT, fc);
      float h1 = fmaxf(fmaf(t1, par[c], par[64 + c]), 0.f);
      const float* w2c = W2 + c;
#pragma unroll
      for (int o = 0; o < CHN; ++o) acc[o] = fmaf(w2c[o * CHN], h1, acc[o]);
    }
#pragma unroll
    for (int o = 0; o < CHN; ++o) {
      float h2 = fmaxf(fmaf(acc[o], par[160 + o], par[224 + o]), 0.f);
      atomicMax(&sfq[p][o], __float_as_uint(h2));   // h2 >= 0 -> uint max == float max
    }
    for (int d = 0; d < DKK; ++d) sl[p][k][d] = dot144(Wk + d * CCAT, fc);
    for (int v = 0; v < DVV; ++v) {
      float tv = dot144(Wv + v * CCAT, fc);
      sv[p][k][v] = fmaf(tv, par[128 + v], par[144 + v]);
    }
  }
  __syncthreads();
  for (int i = tid; i < npts * CHN; i += 256)
    fqg[(size_t)(blockIdx.x * P3P) * CHN + i] = __uint_as_float(sfq[i >> 6][i & 63]);
  for (int pd = tid; pd < npts * DKK; pd += 256) {
    int pp = pd >> 5, d = pd & 31;
    float m = -1e30f;
#pragma unroll
    for (int q = 0; q < KK; ++q) m = fmaxf(m, sl[pp][q][d]);
    float S = 0.f;
#pragma unroll
    for (int q = 0; q < KK; ++q) S += __expf(sl[pp][q][d] - m);
    sm[pp][d] = m; ssi[pp][d] = 1.f / S;
  }
  __syncthreads();
  for (int pd = tid; pd < npts * DKK; pd += 256) {
    int pp = pd >> 5, d = pd & 31;
    float m = sm[pp][d], Si = ssi[pp][d];
    float a[DVV];
#pragma unroll
    for (int v = 0; v < DVV; ++v) a[v] = 0.f;
#pragma unroll
    for (int q = 0; q < KK; ++q) {
      float wgt = __expf(sl[pp][q][d] - m) * Si;
#pragma unroll
      for (int v = 0; v < DVV; ++v) a[v] = fmaf(wgt, sv[pp][q][v], a[v]);
    }
    float* dst = kvg + ((size_t)(blockIdx.x * P3P + pp) * DKK + d) * DVV;
#pragma unroll
    for (int v = 0; v < DVV; ++v) dst[v] = a[v];
  }
}

// stats of tq = Wq@fq over (b,n)
__global__ void __launch_bounds__(256, 2) k_pq(const float* __restrict__ fqg,
                                               const float* __restrict__ Wq,
                                               float* __restrict__ stq)
{
  int bn = blockIdx.x * 256 + threadIdx.x;          // exact BNTOT
  float fq[CHN];
#pragma unroll
  for (int c = 0; c < CHN; c += 4) {
    float4 v4 = *(const float4*)(fqg + (size_t)bn * CHN + c);
    fq[c] = v4.x; fq[c + 1] = v4.y; fq[c + 2] = v4.z; fq[c + 3] = v4.w;
  }
  float* slot = stq + (blockIdx.x & 63) * 512;
  int lane = threadIdx.x & 63;
  for (int o = 0; o < NQC; ++o) {
    const float* w = Wq + o * CHN;
    float a0 = 0.f, a1 = 0.f, a2 = 0.f, a3 = 0.f;
#pragma unroll
    for (int c = 0; c < CHN; c += 4) {
      a0 = fmaf(w[c], fq[c], a0); a1 = fmaf(w[c + 1], fq[c + 1], a1);
      a2 = fmaf(w[c + 2], fq[c + 2], a2); a3 = fmaf(w[c + 3], fq[c + 3], a3);
    }
    float v = (a0 + a1) + (a2 + a3);
    float s = wred(v), s2 = wred(v * v);
    if (lane == 0) { atomicAdd(&slot[o], s); atomicAdd(&slot[256 + o], s2); }
  }
}

__global__ void k_redq(const float* __restrict__ stq, const float* __restrict__ gq,
                       const float* __restrict__ bq, float* __restrict__ par)
{
  int o = threadIdx.x; // 256
  float s = 0.f, s2 = 0.f;
  for (int j = 0; j < 64; ++j) { s += stq[j * 512 + o]; s2 += stq[j * 512 + 256 + o]; }
  const float inv = 1.f / (float)BNTOT;
  float mu = s * inv, var = s2 * inv - mu * mu;
  float a = gq[o] * rsqrtf(var + EPSV);
  par[288 + o] = a; par[544 + o] = bq[o] - mu * a;
}

// q = relu(bnq(Wq@fq)); out[h*16+v] = sum_d q[h*32+d]*kv[d][v]
__global__ void __launch_bounds__(64) k_p4(const float* __restrict__ fqg,
                                           const float* __restrict__ kvg,
                                           const float* __restrict__ Wq,
                                           const float* __restrict__ par,
                                           float* __restrict__ outp)
{
  __shared__ float sfq[CHN], sq2[NQC], skv[DKK * DVV];
  int t = threadIdx.x;
  int b = blockIdx.x & 7, n = blockIdx.x >> 3;      // XCD-friendly: same-XCD blocks -> consecutive n
  int bn = (b << 12) | n;
  sfq[t] = fqg[(size_t)bn * CHN + t];
#pragma unroll
  for (int j = 0; j < 8; ++j) skv[t + 64 * j] = kvg[(size_t)bn * 512 + t + 64 * j];
  __syncthreads();
#pragma unroll
  for (int j = 0; j < 4; ++j) {
    int o = t + 64 * j;
    const float* w = Wq + o * CHN;
    float a0 = 0.f, a1 = 0.f, a2 = 0.f, a3 = 0.f;
#pragma unroll
    for (int c = 0; c < CHN; c += 4) {
      a0 = fmaf(w[c], sfq[c], a0); a1 = fmaf(w[c + 1], sfq[c + 1], a1);
      a2 = fmaf(w[c + 2], sfq[c + 2], a2); a3 = fmaf(w[c + 3], sfq[c + 3], a3);
    }
    float v = (a0 + a1) + (a2 + a3);
    sq2[o] = fmaxf(fmaf(v, par[288 + o], par[544 + o]), 0.f);
  }
  __syncthreads();
#pragma unroll
  for (int j = 0; j < 2; ++j) {
    int ch = t + 64 * j, h = ch >> 4, vv = ch & 15;
    float a = 0.f;
#pragma unroll
    for (int d = 0; d < DKK; ++d) a = fmaf(sq2[h * DKK + d], skv[d * DVV + vv], a);
    outp[(size_t)BNTOT * 3 + ((size_t)(b * 128 + ch)) * NN + n] = a;
  }
}

// ---------- launch ----------

extern "C" void kernel_launch(void* const* d_in, const int* in_sizes, int n_in,
                              void* d_out, int out_size, void* d_ws, size_t ws_size,
                              hipStream_t stream)
{
  const float* x  = (const float*)d_in[0];
  const float* W1 = (const float*)d_in[1];
  const float* g1 = (const float*)d_in[2];
  const float* b1 = (const float*)d_in[3];
  const float* W2 = (const float*)d_in[4];
  const float* g2 = (const float*)d_in[5];
  const float* b2 = (const float*)d_in[6];
  const float* Wv = (const float*)d_in[7];
  const float* gv = (const float*)d_in[8];
  const float* bv = (const float*)d_in[9];
  const float* Wk = (const float*)d_in[10];
  const float* Wq = (const float*)d_in[11];
  const float* gq = (const float*)d_in[12];
  const float* bq = (const float*)d_in[13];
  const float* Wh = (const float*)d_in[14];

  float* ws = (float*)d_ws;
  // layout (floats): total ~21.81M floats = 87.2 MB
  float4* xyz4 = (float4*)ws;                 // 131072
  float*  feat = ws + 131072;                 // 2097152
  int*    idxb = (int*)(ws + 2228224);        // 655360
  float*  st1  = ws + 2883584;                // 10240
  float*  st2  = ws + 2893824;                // 8192
  float*  stq  = ws + 2902016;                // 32768
  float*  par  = ws + 2934784;                // 800
  float*  fqg  = ws + 2935584;                // 2097152
  float*  kvg  = ws + 5032736;                // 16777216
  float*  outp = (float*)d_out;

  hipMemsetAsync(st1, 0, (size_t)(10240 + 8192 + 32768) * sizeof(float), stream);
  k_prep<<<128, 256, 0, stream>>>(x, xyz4, feat, outp);
  k_knn <<<128, 256, 0, stream>>>(xyz4, idxb);
  k_s1  <<<2560, 256, 0, stream>>>(xyz4, feat, idxb, W1, Wv, Wh, st1);
  k_red1<<<1, 128, 0, stream>>>(st1, g1, b1, gv, bv, par);
  k_s2  <<<2560, 256, 0, stream>>>(xyz4, feat, idxb, W1, W2, Wh, par, st2);
  k_red2<<<1, 64, 0, stream>>>(st2, g2, b2, par);
  k_p3  <<<2731, 256, 0, stream>>>(xyz4, feat, idxb, W1, W2, Wk, Wv, Wh, par, fqg, kvg);
  k_pq  <<<128, 256, 0, stream>>>(fqg, Wq, stq);
  k_redq<<<1, 256, 0, stream>>>(stq, gq, bq, par);
  k_p4  <<<32768, 64, 0, stream>>>(fqg, kvg, Wq, par, outp);
}

// Round 2
// 3152.002 us; speedup vs baseline: 1.7620x; 1.7620x over previous
//
#include <hip/hip_runtime.h>
#include <hip/hip_bf16.h>

#define NB 8
#define NN 4096
#define KK 20
#define CFEAT 64
#define CCAT 144
#define CHN 64
#define NHEAD 8
#define DKK 32
#define DVV 16
#define NQC 256
#define EPSV 1e-5f
#define BNTOT (NB*NN)      /* 32768 */
#define ITEMS (BNTOT*KK)   /* 655360 */

// ---------- helpers ----------

__device__ __forceinline__ float wred(float v) {
#pragma unroll
  for (int off = 32; off > 0; off >>= 1) v += __shfl_down(v, off);
  return v;
}

// build 16 channels of fcat: ch 0..3 = gpn, 4..7 = feat(center), 8 = pos
__device__ __forceinline__ void build_chunk(int ch,
    const float* __restrict__ fme, const float* __restrict__ fnb,
    float rx, float ry, float rz, const float* __restrict__ Wh, float* fc)
{
  if (ch < 4) {
    int c0 = ch * 16;
#pragma unroll
    for (int j = 0; j < 16; j += 4) {
      float4 a = *(const float4*)(fnb + c0 + j);
      float4 m = *(const float4*)(fme + c0 + j);
      fc[j + 0] = a.x - m.x; fc[j + 1] = a.y - m.y;
      fc[j + 2] = a.z - m.z; fc[j + 3] = a.w - m.w;
    }
  } else if (ch < 8) {
    int c0 = (ch - 4) * 16;
#pragma unroll
    for (int j = 0; j < 16; j += 4) {
      float4 m = *(const float4*)(fme + c0 + j);
      fc[j + 0] = m.x; fc[j + 1] = m.y; fc[j + 2] = m.z; fc[j + 3] = m.w;
    }
  } else {
#pragma unroll
    for (int v = 0; v < 16; ++v)
      fc[v] = fmaf(Wh[v * 3], rx, fmaf(Wh[v * 3 + 1], ry, Wh[v * 3 + 2] * rz));
  }
}

template<int NO>
__device__ __forceinline__ void accum_chunk(const float* __restrict__ W, int ch,
                                            const float* fc, float* acc)
{
  const float* wb = W + ch * 16;
#pragma unroll
  for (int o = 0; o < NO; ++o) {
    const float* w = wb + o * CCAT;   // wave-uniform -> s_load
#pragma unroll
    for (int j = 0; j < 16; ++j) acc[o] = fmaf(w[j], fc[j], acc[o]);
  }
}

// ---------- kernels ----------

__global__ void __launch_bounds__(256) k_prep(const float* __restrict__ x,
                                              float4* __restrict__ xyz4,
                                              float* __restrict__ feat,
                                              float* __restrict__ outp)
{
  int i = blockIdx.x * 256 + threadIdx.x;
  const float* xr = x + (size_t)i * 67;
  float a = xr[0], b = xr[1], c = xr[2];
  xyz4[i] = make_float4(a, b, c, a * a + b * b + c * c);
  outp[i * 3 + 0] = a; outp[i * 3 + 1] = b; outp[i * 3 + 2] = c;
  float* fd = feat + (size_t)i * CFEAT;
#pragma unroll
  for (int cc = 0; cc < CFEAT; ++cc) fd[cc] = xr[3 + cc];
}

// exact K=20 NN per point; strict-< keeps lowest index on ties (matches top_k)
__global__ void __launch_bounds__(64) k_knn(const float4* __restrict__ xyz4,
                                            int* __restrict__ idxb)
{
  int b = blockIdx.x >> 6;
  int n = ((blockIdx.x & 63) << 6) + threadIdx.x;
  const float4* pts = xyz4 + (size_t)b * NN;
  float4 me = pts[n];
  float bd[KK]; int bi[KK];
#pragma unroll
  for (int j = 0; j < KK; ++j) { bd[j] = 3.4e38f; bi[j] = -1; }
  for (int m = 0; m < NN; ++m) {
    float4 p = pts[m];                 // wave-uniform -> scalar load
    float dot = me.x * p.x + me.y * p.y + me.z * p.z;
    float d = me.w + p.w - 2.f * dot;
    if (d < bd[KK - 1]) {
      bd[KK - 1] = d; bi[KK - 1] = m;
#pragma unroll
      for (int j = KK - 1; j > 0; --j) {
        if (bd[j] < bd[j - 1]) {
          float td = bd[j]; bd[j] = bd[j - 1]; bd[j - 1] = td;
          int ti = bi[j]; bi[j] = bi[j - 1]; bi[j - 1] = ti;
        }
      }
    }
  }
  int* op = idxb + ((size_t)b * NN + n) * KK;
#pragma unroll
  for (int j = 0; j < KK; ++j) op[j] = bi[j];
}

// stats of t1 = W1@fcat (64) and tv = Wv@fcat (16) over (b,n,k)
__global__ void __launch_bounds__(256, 3) k_s1(
    const float4* __restrict__ xyz4, const float* __restrict__ feat,
    const int* __restrict__ idxb, const float* __restrict__ W1,
    const float* __restrict__ Wv, const float* __restrict__ Wh,
    float* __restrict__ st1)
{
  int t = blockIdx.x * 256 + threadIdx.x;
  int bn = t / KK, k = t - bn * KK, b = bn >> 12;
  int nb = idxb[(size_t)bn * KK + k];
  const float* fme = feat + (size_t)bn * CFEAT;
  const float* fnb = feat + ((size_t)b * NN + nb) * CFEAT;
  float4 pn = xyz4[(size_t)b * NN + nb];
  float4 pm = xyz4[bn];
  float rx = pn.x - pm.x, ry = pn.y - pm.y, rz = pn.z - pm.z;
  float a1[CHN], av[DVV];
#pragma unroll
  for (int o = 0; o < CHN; ++o) a1[o] = 0.f;
#pragma unroll
  for (int o = 0; o < DVV; ++o) av[o] = 0.f;
#pragma unroll 1
  for (int ch = 0; ch < 9; ++ch) {
    float fc[16];
    build_chunk(ch, fme, fnb, rx, ry, rz, Wh, fc);
    accum_chunk<CHN>(W1, ch, fc, a1);
    accum_chunk<DVV>(Wv, ch, fc, av);
  }
  float* slot = st1 + (blockIdx.x & 63) * 160;
  int lane = threadIdx.x & 63;
#pragma unroll
  for (int o = 0; o < CHN; ++o) {
    float s = wred(a1[o]), s2 = wred(a1[o] * a1[o]);
    if (lane == 0) { atomicAdd(&slot[o], s); atomicAdd(&slot[CHN + o], s2); }
  }
#pragma unroll
  for (int o = 0; o < DVV; ++o) {
    float s = wred(av[o]), s2 = wred(av[o] * av[o]);
    if (lane == 0) { atomicAdd(&slot[128 + o], s); atomicAdd(&slot[128 + DVV + o], s2); }
  }
}

__global__ void k_red1(const float* __restrict__ st1, const float* __restrict__ g1,
                       const float* __restrict__ b1, const float* __restrict__ gv,
                       const float* __restrict__ bv, float* __restrict__ par)
{
  int o = threadIdx.x;
  const float inv = 1.f / (float)ITEMS;
  if (o < 64) {
    float s = 0.f, s2 = 0.f;
    for (int j = 0; j < 64; ++j) { s += st1[j * 160 + o]; s2 += st1[j * 160 + 64 + o]; }
    float mu = s * inv, var = s2 * inv - mu * mu;
    float a = g1[o] * rsqrtf(var + EPSV);
    par[o] = a; par[64 + o] = b1[o] - mu * a;
  } else if (o < 80) {
    int v = o - 64;
    float s = 0.f, s2 = 0.f;
    for (int j = 0; j < 64; ++j) { s += st1[j * 160 + 128 + v]; s2 += st1[j * 160 + 144 + v]; }
    float mu = s * inv, var = s2 * inv - mu * mu;
    float a = gv[v] * rsqrtf(var + EPSV);
    par[128 + v] = a; par[144 + v] = bv[v] - mu * a;
  }
}

// stats of t2 = W2@relu(bn1(W1@fcat))
__global__ void __launch_bounds__(256, 3) k_s2(
    const float4* __restrict__ xyz4, const float* __restrict__ feat,
    const int* __restrict__ idxb, const float* __restrict__ W1,
    const float* __restrict__ W2, const float* __restrict__ Wh,
    const float* __restrict__ par, float* __restrict__ st2)
{
  int t = blockIdx.x * 256 + threadIdx.x;
  int bn = t / KK, k = t - bn * KK, b = bn >> 12;
  int nb = idxb[(size_t)bn * KK + k];
  const float* fme = feat + (size_t)bn * CFEAT;
  const float* fnb = feat + ((size_t)b * NN + nb) * CFEAT;
  float4 pn = xyz4[(size_t)b * NN + nb];
  float4 pm = xyz4[bn];
  float rx = pn.x - pm.x, ry = pn.y - pm.y, rz = pn.z - pm.z;
  float a1[CHN];
#pragma unroll
  for (int o = 0; o < CHN; ++o) a1[o] = 0.f;
#pragma unroll 1
  for (int ch = 0; ch < 9; ++ch) {
    float fc[16];
    build_chunk(ch, fme, fnb, rx, ry, rz, Wh, fc);
    accum_chunk<CHN>(W1, ch, fc, a1);
  }
  // h1 in place
#pragma unroll
  for (int c = 0; c < CHN; ++c) a1[c] = fmaxf(fmaf(a1[c], par[c], par[64 + c]), 0.f);
  float* slot = st2 + (blockIdx.x & 63) * 128;
  int lane = threadIdx.x & 63;
#pragma unroll 1
  for (int o = 0; o < CHN; ++o) {
    const float* w = W2 + o * CHN;
    float c0 = 0.f, c1 = 0.f, c2 = 0.f, c3 = 0.f;
#pragma unroll
    for (int c = 0; c < CHN; c += 4) {
      c0 = fmaf(w[c + 0], a1[c + 0], c0); c1 = fmaf(w[c + 1], a1[c + 1], c1);
      c2 = fmaf(w[c + 2], a1[c + 2], c2); c3 = fmaf(w[c + 3], a1[c + 3], c3);
    }
    float v = (c0 + c1) + (c2 + c3);
    float s = wred(v), s2 = wred(v * v);
    if (lane == 0) { atomicAdd(&slot[o], s); atomicAdd(&slot[64 + o], s2); }
  }
}

__global__ void k_red2(const float* __restrict__ st2, const float* __restrict__ g2,
                       const float* __restrict__ b2, float* __restrict__ par)
{
  int o = threadIdx.x; // 64
  float s = 0.f, s2 = 0.f;
  for (int j = 0; j < 64; ++j) { s += st2[j * 128 + o]; s2 += st2[j * 128 + 64 + o]; }
  const float inv = 1.f / (float)ITEMS;
  float mu = s * inv, var = s2 * inv - mu * mu;
  float a = g2[o] * rsqrtf(var + EPSV);
  par[160 + o] = a; par[224 + o] = b2[o] - mu * a;
}

// main pass: fq = max_k h2; softmax over k; kv (bf16)
#define P3P 16
__global__ void __launch_bounds__(320, 2) k_p3(
    const float4* __restrict__ xyz4, const float* __restrict__ feat,
    const int* __restrict__ idxb, const float* __restrict__ W1,
    const float* __restrict__ W2, const float* __restrict__ Wk,
    const float* __restrict__ Wv, const float* __restrict__ Wh,
    const float* __restrict__ par, float* __restrict__ fqg,
    __hip_bfloat16* __restrict__ kvg)
{
  __shared__ float sl[P3P][KK][DKK + 1];   // 42240 B
  __shared__ float sv[P3P][KK][DVV + 1];   // 21760 B
  __shared__ unsigned sfq[P3P][CHN];       //  4096 B
  __shared__ float sm[P3P][DKK], ssi[P3P][DKK]; // 4096 B
  int tid = threadIdx.x;
  for (int i = tid; i < P3P * CHN; i += 320) ((unsigned*)sfq)[i] = 0u;
  __syncthreads();
  int p = tid / KK, k = tid - p * KK;      // 320 = 16*20 exact
  int bn = blockIdx.x * P3P + p, b = bn >> 12;
  int nb = idxb[(size_t)bn * KK + k];
  const float* fme = feat + (size_t)bn * CFEAT;
  const float* fnb = feat + ((size_t)b * NN + nb) * CFEAT;
  float4 pn = xyz4[(size_t)b * NN + nb];
  float4 pm = xyz4[bn];
  float rx = pn.x - pm.x, ry = pn.y - pm.y, rz = pn.z - pm.z;
  float a1[CHN], ak[DKK], av[DVV];
#pragma unroll
  for (int o = 0; o < CHN; ++o) a1[o] = 0.f;
#pragma unroll
  for (int o = 0; o < DKK; ++o) ak[o] = 0.f;
#pragma unroll
  for (int o = 0; o < DVV; ++o) av[o] = 0.f;
#pragma unroll 1
  for (int ch = 0; ch < 9; ++ch) {
    float fc[16];
    build_chunk(ch, fme, fnb, rx, ry, rz, Wh, fc);
    accum_chunk<CHN>(W1, ch, fc, a1);
    accum_chunk<DKK>(Wk, ch, fc, ak);
    accum_chunk<DVV>(Wv, ch, fc, av);
  }
  // park logits + v in LDS (frees 48 regs)
#pragma unroll
  for (int d = 0; d < DKK; ++d) sl[p][k][d] = ak[d];
#pragma unroll
  for (int v = 0; v < DVV; ++v)
    sv[p][k][v] = fmaf(av[v], par[128 + v], par[144 + v]);
  // h1 in place
#pragma unroll
  for (int c = 0; c < CHN; ++c) a1[c] = fmaxf(fmaf(a1[c], par[c], par[64 + c]), 0.f);
  // t2 -> h2 -> per-point max (h2 >= 0 so uint max == float max)
#pragma unroll 1
  for (int o = 0; o < CHN; ++o) {
    const float* w = W2 + o * CHN;
    float c0 = 0.f, c1 = 0.f, c2 = 0.f, c3 = 0.f;
#pragma unroll
    for (int c = 0; c < CHN; c += 4) {
      c0 = fmaf(w[c + 0], a1[c + 0], c0); c1 = fmaf(w[c + 1], a1[c + 1], c1);
      c2 = fmaf(w[c + 2], a1[c + 2], c2); c3 = fmaf(w[c + 3], a1[c + 3], c3);
    }
    float v = (c0 + c1) + (c2 + c3);
    float h2 = fmaxf(fmaf(v, par[160 + o], par[224 + o]), 0.f);
    atomicMax(&sfq[p][o], __float_as_uint(h2));
  }
  __syncthreads();
  for (int i = tid; i < P3P * CHN; i += 320)
    fqg[(size_t)blockIdx.x * (P3P * CHN) + i] = __uint_as_float(sfq[i >> 6][i & 63]);
  for (int pd = tid; pd < P3P * DKK; pd += 320) {
    int pp = pd >> 5, d = pd & 31;
    float m = -1e30f;
#pragma unroll
    for (int q = 0; q < KK; ++q) m = fmaxf(m, sl[pp][q][d]);
    float S = 0.f;
#pragma unroll
    for (int q = 0; q < KK; ++q) S += __expf(sl[pp][q][d] - m);
    sm[pp][d] = m; ssi[pp][d] = 1.f / S;
  }
  __syncthreads();
  for (int pd = tid; pd < P3P * DKK; pd += 320) {
    int pp = pd >> 5, d = pd & 31;
    float m = sm[pp][d], Si = ssi[pp][d];
    float a[DVV];
#pragma unroll
    for (int v = 0; v < DVV; ++v) a[v] = 0.f;
#pragma unroll
    for (int q = 0; q < KK; ++q) {
      float wgt = __expf(sl[pp][q][d] - m) * Si;
#pragma unroll
      for (int v = 0; v < DVV; ++v) a[v] = fmaf(wgt, sv[pp][q][v], a[v]);
    }
    __hip_bfloat162* dst = (__hip_bfloat162*)
        (kvg + ((size_t)(blockIdx.x * P3P + pp) * DKK + d) * DVV);
#pragma unroll
    for (int v = 0; v < DVV; v += 2) {
      float2 f2; f2.x = a[v]; f2.y = a[v + 1];
      dst[v >> 1] = __float22bfloat162_rn(f2);
    }
  }
}

// tq = Wq@fq: stats + store pre-BN q2
__global__ void __launch_bounds__(128, 2) k_pq(const float* __restrict__ fqg,
                                               const float* __restrict__ Wq,
                                               float* __restrict__ stq,
                                               float* __restrict__ q2g)
{
  int bn = blockIdx.x * 128 + threadIdx.x;          // grid 256x128 exact
  float fq[CHN];
#pragma unroll
  for (int c = 0; c < CHN; c += 4) {
    float4 v4 = *(const float4*)(fqg + (size_t)bn * CHN + c);
    fq[c] = v4.x; fq[c + 1] = v4.y; fq[c + 2] = v4.z; fq[c + 3] = v4.w;
  }
  float* slot = stq + (blockIdx.x & 63) * 512;
  int lane = threadIdx.x & 63;
#pragma unroll 1
  for (int o = 0; o < NQC; ++o) {
    const float* w = Wq + o * CHN;
    float a0 = 0.f, a1 = 0.f, a2 = 0.f, a3 = 0.f;
#pragma unroll
    for (int c = 0; c < CHN; c += 4) {
      a0 = fmaf(w[c], fq[c], a0); a1 = fmaf(w[c + 1], fq[c + 1], a1);
      a2 = fmaf(w[c + 2], fq[c + 2], a2); a3 = fmaf(w[c + 3], fq[c + 3], a3);
    }
    float v = (a0 + a1) + (a2 + a3);
    q2g[(size_t)bn * NQC + o] = v;
    float s = wred(v), s2 = wred(v * v);
    if (lane == 0) { atomicAdd(&slot[o], s); atomicAdd(&slot[256 + o], s2); }
  }
}

__global__ void k_redq(const float* __restrict__ stq, const float* __restrict__ gq,
                       const float* __restrict__ bq, float* __restrict__ par)
{
  int o = threadIdx.x; // 256
  float s = 0.f, s2 = 0.f;
  for (int j = 0; j < 64; ++j) { s += stq[j * 512 + o]; s2 += stq[j * 512 + 256 + o]; }
  const float inv = 1.f / (float)BNTOT;
  float mu = s * inv, var = s2 * inv - mu * mu;
  float a = gq[o] * rsqrtf(var + EPSV);
  par[288 + o] = a; par[544 + o] = bq[o] - mu * a;
}

// out[h*16+v] = sum_d relu(bnq(q2))[h*32+d] * kv[d][v]
__global__ void __launch_bounds__(64) k_p4(const float* __restrict__ q2g,
                                           const __hip_bfloat16* __restrict__ kvg,
                                           const float* __restrict__ par,
                                           float* __restrict__ outp)
{
  __shared__ float sq2[NQC], skv[DKK * DVV];
  int t = threadIdx.x;
  int b = blockIdx.x & 7, n = blockIdx.x >> 3;
  int bn = (b << 12) | n;
#pragma unroll
  for (int j = 0; j < 8; ++j)
    skv[t + 64 * j] = __bfloat162float(kvg[(size_t)bn * 512 + t + 64 * j]);
#pragma unroll
  for (int j = 0; j < 4; ++j) {
    int o = t + 64 * j;
    float v = q2g[(size_t)bn * NQC + o];
    sq2[o] = fmaxf(fmaf(v, par[288 + o], par[544 + o]), 0.f);
  }
  __syncthreads();
#pragma unroll
  for (int j = 0; j < 2; ++j) {
    int ch = t + 64 * j, h = ch >> 4, vv = ch & 15;
    float a = 0.f;
#pragma unroll
    for (int d = 0; d < DKK; ++d) a = fmaf(sq2[h * DKK + d], skv[d * DVV + vv], a);
    outp[(size_t)BNTOT * 3 + ((size_t)(b * 128 + ch)) * NN + n] = a;
  }
}

// ---------- launch ----------

extern "C" void kernel_launch(void* const* d_in, const int* in_sizes, int n_in,
                              void* d_out, int out_size, void* d_ws, size_t ws_size,
                              hipStream_t stream)
{
  const float* x  = (const float*)d_in[0];
  const float* W1 = (const float*)d_in[1];
  const float* g1 = (const float*)d_in[2];
  const float* b1 = (const float*)d_in[3];
  const float* W2 = (const float*)d_in[4];
  const float* g2 = (const float*)d_in[5];
  const float* b2 = (const float*)d_in[6];
  const float* Wv = (const float*)d_in[7];
  const float* gv = (const float*)d_in[8];
  const float* bv = (const float*)d_in[9];
  const float* Wk = (const float*)d_in[10];
  const float* Wq = (const float*)d_in[11];
  const float* gq = (const float*)d_in[12];
  const float* bq = (const float*)d_in[13];
  const float* Wh = (const float*)d_in[14];

  float* ws = (float*)d_ws;
  // layout (floats), total ~21.81M floats = 87.2 MB
  float4* xyz4 = (float4*)ws;                      // 131072
  float*  feat = ws + 131072;                      // 2097152
  int*    idxb = (int*)(ws + 2228224);             // 655360
  float*  st1  = ws + 2883584;                     // 10240
  float*  st2  = ws + 2893824;                     // 8192
  float*  stq  = ws + 2902016;                     // 32768
  float*  par  = ws + 2934784;                     // 800
  float*  fqg  = ws + 2935584;                     // 2097152
  float*  q2g  = ws + 5032736;                     // 8388608
  __hip_bfloat16* kvg = (__hip_bfloat16*)(ws + 13421344); // 16777216 bf16 = 8388608 floats
  float*  outp = (float*)d_out;

  hipMemsetAsync(st1, 0, (size_t)(10240 + 8192 + 32768) * sizeof(float), stream);
  k_prep<<<128, 256, 0, stream>>>(x, xyz4, feat, outp);
  k_knn <<<512, 64, 0, stream>>>(xyz4, idxb);
  k_s1  <<<2560, 256, 0, stream>>>(xyz4, feat, idxb, W1, Wv, Wh, st1);
  k_red1<<<1, 128, 0, stream>>>(st1, g1, b1, gv, bv, par);
  k_s2  <<<2560, 256, 0, stream>>>(xyz4, feat, idxb, W1, W2, Wh, par, st2);
  k_red2<<<1, 64, 0, stream>>>(st2, g2, b2, par);
  k_p3  <<<2048, 320, 0, stream>>>(xyz4, feat, idxb, W1, W2, Wk, Wv, Wh, par, fqg, kvg);
  k_pq  <<<256, 128, 0, stream>>>(fqg, Wq, stq, q2g);
  k_redq<<<1, 256, 0, stream>>>(stq, gq, bq, par);
  k_p4  <<<32768, 64, 0, stream>>>(q2g, kvg, par, outp);
}

// Round 3
// 2514.503 us; speedup vs baseline: 2.2087x; 1.2535x over previous
//
#include <hip/hip_runtime.h>
#include <hip/hip_bf16.h>

#define NB 8
#define NN 4096
#define KK 20
#define CFEAT 64
#define CCAT 144
#define CHN 64
#define NHEAD 8
#define DKK 32
#define DVV 16
#define NQC 256
#define EPSV 1e-5f
#define BNTOT (NB*NN)      /* 32768 */
#define ITEMS (BNTOT*KK)   /* 655360 */

// ---------- helpers ----------

__device__ __forceinline__ float wred(float v) {
#pragma unroll
  for (int off = 32; off > 0; off >>= 1) v += __shfl_down(v, off);
  return v;
}

// build 16 channels of fcat: ch 0..3 = gpn, 4..7 = feat(center), 8 = pos
__device__ __forceinline__ void build_chunk(int ch,
    const float* __restrict__ fme, const float* __restrict__ fnb,
    float rx, float ry, float rz, const float* __restrict__ Wh, float* fc)
{
  if (ch < 4) {
    int c0 = ch * 16;
#pragma unroll
    for (int j = 0; j < 16; j += 4) {
      float4 a = *(const float4*)(fnb + c0 + j);
      float4 m = *(const float4*)(fme + c0 + j);
      fc[j + 0] = a.x - m.x; fc[j + 1] = a.y - m.y;
      fc[j + 2] = a.z - m.z; fc[j + 3] = a.w - m.w;
    }
  } else if (ch < 8) {
    int c0 = (ch - 4) * 16;
#pragma unroll
    for (int j = 0; j < 16; j += 4) {
      float4 m = *(const float4*)(fme + c0 + j);
      fc[j + 0] = m.x; fc[j + 1] = m.y; fc[j + 2] = m.z; fc[j + 3] = m.w;
    }
  } else {
#pragma unroll
    for (int v = 0; v < 16; ++v)
      fc[v] = fmaf(Wh[v * 3], rx, fmaf(Wh[v * 3 + 1], ry, Wh[v * 3 + 2] * rz));
  }
}

template<int NO>
__device__ __forceinline__ void accum_chunk(const float* __restrict__ W, int ch,
                                            const float* fc, float* acc)
{
  const float* wb = W + ch * 16;
#pragma unroll
  for (int o = 0; o < NO; ++o) {
    const float* w = wb + o * CCAT;   // wave-uniform -> s_load
#pragma unroll
    for (int j = 0; j < 16; ++j) acc[o] = fmaf(w[j], fc[j], acc[o]);
  }
}

// identical in phase1/phase2 so d is bit-identical (explicit fma chain, no reassoc)
__device__ __forceinline__ float pdist(float4 me, float4 p) {
  float dot = fmaf(me.x, p.x, fmaf(me.y, p.y, me.z * p.z));
  return fmaf(-2.f, dot, me.w + p.w);
}

// ---------- kernels ----------

__global__ void __launch_bounds__(256) k_prep(const float* __restrict__ x,
                                              float4* __restrict__ xyz4,
                                              float* __restrict__ feat,
                                              float* __restrict__ outp)
{
  int i = blockIdx.x * 256 + threadIdx.x;
  const float* xr = x + (size_t)i * 67;
  float a = xr[0], b = xr[1], c = xr[2];
  xyz4[i] = make_float4(a, b, c, a * a + b * b + c * c);
  outp[i * 3 + 0] = a; outp[i * 3 + 1] = b; outp[i * 3 + 2] = c;
  float* fd = feat + (size_t)i * CFEAT;
#pragma unroll
  for (int cc = 0; cc < CFEAT; ++cc) fd[cc] = xr[3 + cc];
}

// exact K=20 NN. Block = 128 queries x 2 segments (wave-uniform segment).
// Phase1: branchless med3 top-20 distances per segment.
// Merge: tau = 20th smallest of the two sorted lists (multiset-exact).
// Phase2: rescan, scatter m with d<tau; ties d==tau -> lowest index first.
__global__ void __launch_bounds__(256) k_knn(const float4* __restrict__ xyz4,
                                             int* __restrict__ idxb)
{
  __shared__ float sbd[2 * 128 * 20];   // per (seg,query) sorted top-20 dists
  __shared__ float stau[128];
  __shared__ int   scnt[128];
  __shared__ int   stcnt[128];
  __shared__ int   sties[128 * 16];
  int t = threadIdx.x;
  int q = t & 127, s = t >> 7;          // s uniform per wave-pair
  int b = blockIdx.x >> 5;
  int n = ((blockIdx.x & 31) << 7) + q;
  const float4* pts = xyz4 + (size_t)b * NN;
  float4 me = pts[n];
  if (t < 128) { scnt[t] = 0; stcnt[t] = 0; }
  int m0 = s << 11;                     // 0 or 2048
  float bd[KK];
#pragma unroll
  for (int j = 0; j < KK; ++j) bd[j] = 3.4e38f;
#pragma unroll 2
  for (int m = m0; m < m0 + 2048; ++m) {
    float4 p = pts[m];                  // wave-uniform -> s_load_dwordx4
    float d = pdist(me, p);
#pragma unroll
    for (int j = KK - 1; j >= 1; --j)
      bd[j] = __builtin_amdgcn_fmed3f(d, bd[j - 1], bd[j]);
    bd[0] = fminf(bd[0], d);
  }
  float* myl = sbd + (s * 128 + q) * 20;
#pragma unroll
  for (int j = 0; j < KK; ++j) myl[j] = bd[j];
  __syncthreads();
  if (t < 128) {
    const float* A = sbd + t * 20;
    const float* Bl = sbd + (128 + t) * 20;
    int ia = 0, ib = 0; float tau = 0.f;
#pragma unroll 1
    for (int r = 0; r < KK; ++r) {
      float a = A[ia], bb = Bl[ib];
      if (a <= bb) { tau = a; ++ia; } else { tau = bb; ++ib; }
    }
    stau[t] = tau;
  }
  __syncthreads();
  float tau = stau[q];
  size_t obase = ((size_t)b * NN + n) * KK;
#pragma unroll 2
  for (int m = m0; m < m0 + 2048; ++m) {
    float4 p = pts[m];
    float d = pdist(me, p);
    if (d < tau) {
      int slot = atomicAdd(&scnt[q], 1);
      idxb[obase + slot] = m;
    } else if (d == tau) {
      int ts_ = atomicAdd(&stcnt[q], 1);
      if (ts_ < 16) sties[q * 16 + ts_] = m;
    }
  }
  __syncthreads();
  if (t < 128) {
    int c1 = scnt[t];                   // provably <= 19
    int tc = min(stcnt[t], 16);
    int need = KK - c1;
    size_t ob = ((size_t)b * NN + (((blockIdx.x & 31) << 7) + t)) * KK;
    int last = -1;
#pragma unroll 1
    for (int r = 0; r < need; ++r) {
      int best = 0x7fffffff;
      for (int u = 0; u < tc; ++u) {
        int mv = sties[t * 16 + u];
        if (mv > last && mv < best) best = mv;
      }
      if (best == 0x7fffffff) best = 0; // unreachable safety
      idxb[ob + c1 + r] = best;
      last = best;
    }
  }
}

// stats of t1 = W1@fcat (64) and tv = Wv@fcat (16) over (b,n,k)
__global__ void __launch_bounds__(256, 3) k_s1(
    const float4* __restrict__ xyz4, const float* __restrict__ feat,
    const int* __restrict__ idxb, const float* __restrict__ W1,
    const float* __restrict__ Wv, const float* __restrict__ Wh,
    float* __restrict__ st1)
{
  int t = blockIdx.x * 256 + threadIdx.x;
  int bn = t / KK, k = t - bn * KK, b = bn >> 12;
  int nb = idxb[(size_t)bn * KK + k];
  const float* fme = feat + (size_t)bn * CFEAT;
  const float* fnb = feat + ((size_t)b * NN + nb) * CFEAT;
  float4 pn = xyz4[(size_t)b * NN + nb];
  float4 pm = xyz4[bn];
  float rx = pn.x - pm.x, ry = pn.y - pm.y, rz = pn.z - pm.z;
  float a1[CHN], av[DVV];
#pragma unroll
  for (int o = 0; o < CHN; ++o) a1[o] = 0.f;
#pragma unroll
  for (int o = 0; o < DVV; ++o) av[o] = 0.f;
#pragma unroll 1
  for (int ch = 0; ch < 9; ++ch) {
    float fc[16];
    build_chunk(ch, fme, fnb, rx, ry, rz, Wh, fc);
    accum_chunk<CHN>(W1, ch, fc, a1);
    accum_chunk<DVV>(Wv, ch, fc, av);
  }
  float* slot = st1 + (blockIdx.x & 63) * 160;
  int lane = threadIdx.x & 63;
#pragma unroll
  for (int o = 0; o < CHN; ++o) {
    float s = wred(a1[o]), s2 = wred(a1[o] * a1[o]);
    if (lane == 0) { atomicAdd(&slot[o], s); atomicAdd(&slot[CHN + o], s2); }
  }
#pragma unroll
  for (int o = 0; o < DVV; ++o) {
    float s = wred(av[o]), s2 = wred(av[o] * av[o]);
    if (lane == 0) { atomicAdd(&slot[128 + o], s); atomicAdd(&slot[128 + DVV + o], s2); }
  }
}

__global__ void k_red1(const float* __restrict__ st1, const float* __restrict__ g1,
                       const float* __restrict__ b1, const float* __restrict__ gv,
                       const float* __restrict__ bv, float* __restrict__ par)
{
  int o = threadIdx.x;
  const float inv = 1.f / (float)ITEMS;
  if (o < 64) {
    float s = 0.f, s2 = 0.f;
    for (int j = 0; j < 64; ++j) { s += st1[j * 160 + o]; s2 += st1[j * 160 + 64 + o]; }
    float mu = s * inv, var = s2 * inv - mu * mu;
    float a = g1[o] * rsqrtf(var + EPSV);
    par[o] = a; par[64 + o] = b1[o] - mu * a;
  } else if (o < 80) {
    int v = o - 64;
    float s = 0.f, s2 = 0.f;
    for (int j = 0; j < 64; ++j) { s += st1[j * 160 + 128 + v]; s2 += st1[j * 160 + 144 + v]; }
    float mu = s * inv, var = s2 * inv - mu * mu;
    float a = gv[v] * rsqrtf(var + EPSV);
    par[128 + v] = a; par[144 + v] = bv[v] - mu * a;
  }
}

// stats of t2 = W2@relu(bn1(W1@fcat))
__global__ void __launch_bounds__(256, 3) k_s2(
    const float4* __restrict__ xyz4, const float* __restrict__ feat,
    const int* __restrict__ idxb, const float* __restrict__ W1,
    const float* __restrict__ W2, const float* __restrict__ Wh,
    const float* __restrict__ par, float* __restrict__ st2)
{
  int t = blockIdx.x * 256 + threadIdx.x;
  int bn = t / KK, k = t - bn * KK, b = bn >> 12;
  int nb = idxb[(size_t)bn * KK + k];
  const float* fme = feat + (size_t)bn * CFEAT;
  const float* fnb = feat + ((size_t)b * NN + nb) * CFEAT;
  float4 pn = xyz4[(size_t)b * NN + nb];
  float4 pm = xyz4[bn];
  float rx = pn.x - pm.x, ry = pn.y - pm.y, rz = pn.z - pm.z;
  float a1[CHN];
#pragma unroll
  for (int o = 0; o < CHN; ++o) a1[o] = 0.f;
#pragma unroll 1
  for (int ch = 0; ch < 9; ++ch) {
    float fc[16];
    build_chunk(ch, fme, fnb, rx, ry, rz, Wh, fc);
    accum_chunk<CHN>(W1, ch, fc, a1);
  }
  // h1 in place
#pragma unroll
  for (int c = 0; c < CHN; ++c) a1[c] = fmaxf(fmaf(a1[c], par[c], par[64 + c]), 0.f);
  float* slot = st2 + (blockIdx.x & 63) * 128;
  int lane = threadIdx.x & 63;
#pragma unroll 1
  for (int o = 0; o < CHN; ++o) {
    const float* w = W2 + o * CHN;
    float c0 = 0.f, c1 = 0.f, c2 = 0.f, c3 = 0.f;
#pragma unroll
    for (int c = 0; c < CHN; c += 4) {
      c0 = fmaf(w[c + 0], a1[c + 0], c0); c1 = fmaf(w[c + 1], a1[c + 1], c1);
      c2 = fmaf(w[c + 2], a1[c + 2], c2); c3 = fmaf(w[c + 3], a1[c + 3], c3);
    }
    float v = (c0 + c1) + (c2 + c3);
    float s = wred(v), s2 = wred(v * v);
    if (lane == 0) { atomicAdd(&slot[o], s); atomicAdd(&slot[64 + o], s2); }
  }
}

__global__ void k_red2(const float* __restrict__ st2, const float* __restrict__ g2,
                       const float* __restrict__ b2, float* __restrict__ par)
{
  int o = threadIdx.x; // 64
  float s = 0.f, s2 = 0.f;
  for (int j = 0; j < 64; ++j) { s += st2[j * 128 + o]; s2 += st2[j * 128 + 64 + o]; }
  const float inv = 1.f / (float)ITEMS;
  float mu = s * inv, var = s2 * inv - mu * mu;
  float a = g2[o] * rsqrtf(var + EPSV);
  par[160 + o] = a; par[224 + o] = b2[o] - mu * a;
}

// main pass: fq = max_k h2; softmax over k; kv (bf16)
#define P3P 16
__global__ void __launch_bounds__(320, 2) k_p3(
    const float4* __restrict__ xyz4, const float* __restrict__ feat,
    const int* __restrict__ idxb, const float* __restrict__ W1,
    const float* __restrict__ W2, const float* __restrict__ Wk,
    const float* __restrict__ Wv, const float* __restrict__ Wh,
    const float* __restrict__ par, float* __restrict__ fqg,
    __hip_bfloat16* __restrict__ kvg)
{
  __shared__ float sl[P3P][KK][DKK + 1];
  __shared__ float sv[P3P][KK][DVV + 1];
  __shared__ unsigned sfq[P3P][CHN];
  __shared__ float sm[P3P][DKK], ssi[P3P][DKK];
  int tid = threadIdx.x;
  for (int i = tid; i < P3P * CHN; i += 320) ((unsigned*)sfq)[i] = 0u;
  __syncthreads();
  int p = tid / KK, k = tid - p * KK;
  int bn = blockIdx.x * P3P + p, b = bn >> 12;
  int nb = idxb[(size_t)bn * KK + k];
  const float* fme = feat + (size_t)bn * CFEAT;
  const float* fnb = feat + ((size_t)b * NN + nb) * CFEAT;
  float4 pn = xyz4[(size_t)b * NN + nb];
  float4 pm = xyz4[bn];
  float rx = pn.x - pm.x, ry = pn.y - pm.y, rz = pn.z - pm.z;
  float a1[CHN], ak[DKK], av[DVV];
#pragma unroll
  for (int o = 0; o < CHN; ++o) a1[o] = 0.f;
#pragma unroll
  for (int o = 0; o < DKK; ++o) ak[o] = 0.f;
#pragma unroll
  for (int o = 0; o < DVV; ++o) av[o] = 0.f;
#pragma unroll 1
  for (int ch = 0; ch < 9; ++ch) {
    float fc[16];
    build_chunk(ch, fme, fnb, rx, ry, rz, Wh, fc);
    accum_chunk<CHN>(W1, ch, fc, a1);
    accum_chunk<DKK>(Wk, ch, fc, ak);
    accum_chunk<DVV>(Wv, ch, fc, av);
  }
#pragma unroll
  for (int d = 0; d < DKK; ++d) sl[p][k][d] = ak[d];
#pragma unroll
  for (int v = 0; v < DVV; ++v)
    sv[p][k][v] = fmaf(av[v], par[128 + v], par[144 + v]);
#pragma unroll
  for (int c = 0; c < CHN; ++c) a1[c] = fmaxf(fmaf(a1[c], par[c], par[64 + c]), 0.f);
#pragma unroll 1
  for (int o = 0; o < CHN; ++o) {
    const float* w = W2 + o * CHN;
    float c0 = 0.f, c1 = 0.f, c2 = 0.f, c3 = 0.f;
#pragma unroll
    for (int c = 0; c < CHN; c += 4) {
      c0 = fmaf(w[c + 0], a1[c + 0], c0); c1 = fmaf(w[c + 1], a1[c + 1], c1);
      c2 = fmaf(w[c + 2], a1[c + 2], c2); c3 = fmaf(w[c + 3], a1[c + 3], c3);
    }
    float v = (c0 + c1) + (c2 + c3);
    float h2 = fmaxf(fmaf(v, par[160 + o], par[224 + o]), 0.f);
    atomicMax(&sfq[p][o], __float_as_uint(h2));
  }
  __syncthreads();
  for (int i = tid; i < P3P * CHN; i += 320)
    fqg[(size_t)blockIdx.x * (P3P * CHN) + i] = __uint_as_float(sfq[i >> 6][i & 63]);
  for (int pd = tid; pd < P3P * DKK; pd += 320) {
    int pp = pd >> 5, d = pd & 31;
    float m = -1e30f;
#pragma unroll
    for (int q = 0; q < KK; ++q) m = fmaxf(m, sl[pp][q][d]);
    float S = 0.f;
#pragma unroll
    for (int q = 0; q < KK; ++q) S += __expf(sl[pp][q][d] - m);
    sm[pp][d] = m; ssi[pp][d] = 1.f / S;
  }
  __syncthreads();
  for (int pd = tid; pd < P3P * DKK; pd += 320) {
    int pp = pd >> 5, d = pd & 31;
    float m = sm[pp][d], Si = ssi[pp][d];
    float a[DVV];
#pragma unroll
    for (int v = 0; v < DVV; ++v) a[v] = 0.f;
#pragma unroll
    for (int q = 0; q < KK; ++q) {
      float wgt = __expf(sl[pp][q][d] - m) * Si;
#pragma unroll
      for (int v = 0; v < DVV; ++v) a[v] = fmaf(wgt, sv[pp][q][v], a[v]);
    }
    __hip_bfloat162* dst = (__hip_bfloat162*)
        (kvg + ((size_t)(blockIdx.x * P3P + pp) * DKK + d) * DVV);
#pragma unroll
    for (int v = 0; v < DVV; v += 2) {
      float2 f2; f2.x = a[v]; f2.y = a[v + 1];
      dst[v >> 1] = __float22bfloat162_rn(f2);
    }
  }
}

// tq = Wq@fq: stats + store pre-BN q2
__global__ void __launch_bounds__(128, 2) k_pq(const float* __restrict__ fqg,
                                               const float* __restrict__ Wq,
                                               float* __restrict__ stq,
                                               float* __restrict__ q2g)
{
  int bn = blockIdx.x * 128 + threadIdx.x;
  float fq[CHN];
#pragma unroll
  for (int c = 0; c < CHN; c += 4) {
    float4 v4 = *(const float4*)(fqg + (size_t)bn * CHN + c);
    fq[c] = v4.x; fq[c + 1] = v4.y; fq[c + 2] = v4.z; fq[c + 3] = v4.w;
  }
  float* slot = stq + (blockIdx.x & 63) * 512;
  int lane = threadIdx.x & 63;
#pragma unroll 1
  for (int o = 0; o < NQC; ++o) {
    const float* w = Wq + o * CHN;
    float a0 = 0.f, a1 = 0.f, a2 = 0.f, a3 = 0.f;
#pragma unroll
    for (int c = 0; c < CHN; c += 4) {
      a0 = fmaf(w[c], fq[c], a0); a1 = fmaf(w[c + 1], fq[c + 1], a1);
      a2 = fmaf(w[c + 2], fq[c + 2], a2); a3 = fmaf(w[c + 3], fq[c + 3], a3);
    }
    float v = (a0 + a1) + (a2 + a3);
    q2g[(size_t)bn * NQC + o] = v;
    float s = wred(v), s2 = wred(v * v);
    if (lane == 0) { atomicAdd(&slot[o], s); atomicAdd(&slot[256 + o], s2); }
  }
}

__global__ void k_redq(const float* __restrict__ stq, const float* __restrict__ gq,
                       const float* __restrict__ bq, float* __restrict__ par)
{
  int o = threadIdx.x; // 256
  float s = 0.f, s2 = 0.f;
  for (int j = 0; j < 64; ++j) { s += stq[j * 512 + o]; s2 += stq[j * 512 + 256 + o]; }
  const float inv = 1.f / (float)BNTOT;
  float mu = s * inv, var = s2 * inv - mu * mu;
  float a = gq[o] * rsqrtf(var + EPSV);
  par[288 + o] = a; par[544 + o] = bq[o] - mu * a;
}

// out[h*16+v] = sum_d relu(bnq(q2))[h*32+d] * kv[d][v]
__global__ void __launch_bounds__(64) k_p4(const float* __restrict__ q2g,
                                           const __hip_bfloat16* __restrict__ kvg,
                                           const float* __restrict__ par,
                                           float* __restrict__ outp)
{
  __shared__ float sq2[NQC], skv[DKK * DVV];
  int t = threadIdx.x;
  int b = blockIdx.x & 7, n = blockIdx.x >> 3;
  int bn = (b << 12) | n;
#pragma unroll
  for (int j = 0; j < 8; ++j)
    skv[t + 64 * j] = __bfloat162float(kvg[(size_t)bn * 512 + t + 64 * j]);
#pragma unroll
  for (int j = 0; j < 4; ++j) {
    int o = t + 64 * j;
    float v = q2g[(size_t)bn * NQC + o];
    sq2[o] = fmaxf(fmaf(v, par[288 + o], par[544 + o]), 0.f);
  }
  __syncthreads();
#pragma unroll
  for (int j = 0; j < 2; ++j) {
    int ch = t + 64 * j, h = ch >> 4, vv = ch & 15;
    float a = 0.f;
#pragma unroll
    for (int d = 0; d < DKK; ++d) a = fmaf(sq2[h * DKK + d], skv[d * DVV + vv], a);
    outp[(size_t)BNTOT * 3 + ((size_t)(b * 128 + ch)) * NN + n] = a;
  }
}

// ---------- launch ----------

extern "C" void kernel_launch(void* const* d_in, const int* in_sizes, int n_in,
                              void* d_out, int out_size, void* d_ws, size_t ws_size,
                              hipStream_t stream)
{
  const float* x  = (const float*)d_in[0];
  const float* W1 = (const float*)d_in[1];
  const float* g1 = (const float*)d_in[2];
  const float* b1 = (const float*)d_in[3];
  const float* W2 = (const float*)d_in[4];
  const float* g2 = (const float*)d_in[5];
  const float* b2 = (const float*)d_in[6];
  const float* Wv = (const float*)d_in[7];
  const float* gv = (const float*)d_in[8];
  const float* bv = (const float*)d_in[9];
  const float* Wk = (const float*)d_in[10];
  const float* Wq = (const float*)d_in[11];
  const float* gq = (const float*)d_in[12];
  const float* bq = (const float*)d_in[13];
  const float* Wh = (const float*)d_in[14];

  float* ws = (float*)d_ws;
  float4* xyz4 = (float4*)ws;                      // 131072
  float*  feat = ws + 131072;                      // 2097152
  int*    idxb = (int*)(ws + 2228224);             // 655360
  float*  st1  = ws + 2883584;                     // 10240
  float*  st2  = ws + 2893824;                     // 8192
  float*  stq  = ws + 2902016;                     // 32768
  float*  par  = ws + 2934784;                     // 800
  float*  fqg  = ws + 2935584;                     // 2097152
  float*  q2g  = ws + 5032736;                     // 8388608
  __hip_bfloat16* kvg = (__hip_bfloat16*)(ws + 13421344); // 16777216 bf16
  float*  outp = (float*)d_out;

  hipMemsetAsync(st1, 0, (size_t)(10240 + 8192 + 32768) * sizeof(float), stream);
  k_prep<<<128, 256, 0, stream>>>(x, xyz4, feat, outp);
  k_knn <<<256, 256, 0, stream>>>(xyz4, idxb);
  k_s1  <<<2560, 256, 0, stream>>>(xyz4, feat, idxb, W1, Wv, Wh, st1);
  k_red1<<<1, 128, 0, stream>>>(st1, g1, b1, gv, bv, par);
  k_s2  <<<2560, 256, 0, stream>>>(xyz4, feat, idxb, W1, W2, Wh, par, st2);
  k_red2<<<1, 64, 0, stream>>>(st2, g2, b2, par);
  k_p3  <<<2048, 320, 0, stream>>>(xyz4, feat, idxb, W1, W2, Wk, Wv, Wh, par, fqg, kvg);
  k_pq  <<<256, 128, 0, stream>>>(fqg, Wq, stq, q2g);
  k_redq<<<1, 256, 0, stream>>>(stq, gq, bq, par);
  k_p4  <<<32768, 64, 0, stream>>>(q2g, kvg, par, outp);
}

// Round 4
// 1716.007 us; speedup vs baseline: 3.2365x; 1.4653x over previous
//
#include <hip/hip_runtime.h>
#include <hip/hip_bf16.h>

#define NB 8
#define NN 4096
#define KK 20
#define CFEAT 64
#define CCAT 144
#define CHN 64
#define NHEAD 8
#define DKK 32
#define DVV 16
#define NQC 256
#define EPSV 1e-5f
#define BNTOT (NB*NN)      /* 32768 */
#define ITEMS (BNTOT*KK)   /* 655360 */

// ---------- helpers ----------

__device__ __forceinline__ float wred(float v) {
#pragma unroll
  for (int off = 32; off > 0; off >>= 1) v += __shfl_down(v, off);
  return v;
}

// build 16 channels of fcat: ch 0..3 = gpn, 4..7 = feat(center), 8 = pos
__device__ __forceinline__ void build_chunk(int ch,
    const float* __restrict__ fme, const float* __restrict__ fnb,
    float rx, float ry, float rz, const float* __restrict__ Wh, float* fc)
{
  if (ch < 4) {
    int c0 = ch * 16;
#pragma unroll
    for (int j = 0; j < 16; j += 4) {
      float4 a = *(const float4*)(fnb + c0 + j);
      float4 m = *(const float4*)(fme + c0 + j);
      fc[j + 0] = a.x - m.x; fc[j + 1] = a.y - m.y;
      fc[j + 2] = a.z - m.z; fc[j + 3] = a.w - m.w;
    }
  } else if (ch < 8) {
    int c0 = (ch - 4) * 16;
#pragma unroll
    for (int j = 0; j < 16; j += 4) {
      float4 m = *(const float4*)(fme + c0 + j);
      fc[j + 0] = m.x; fc[j + 1] = m.y; fc[j + 2] = m.z; fc[j + 3] = m.w;
    }
  } else {
#pragma unroll
    for (int v = 0; v < 16; ++v)
      fc[v] = fmaf(Wh[v * 3], rx, fmaf(Wh[v * 3 + 1], ry, Wh[v * 3 + 2] * rz));
  }
}

template<int NO>
__device__ __forceinline__ void accum_chunk(const float* __restrict__ W, int ch,
                                            const float* fc, float* acc)
{
  const float* wb = W + ch * 16;
#pragma unroll
  for (int o = 0; o < NO; ++o) {
    const float* w = wb + o * CCAT;   // wave-uniform -> s_load
#pragma unroll
    for (int j = 0; j < 16; ++j) acc[o] = fmaf(w[j], fc[j], acc[o]);
  }
}

// identical in phase1/phase2 so d is bit-identical
__device__ __forceinline__ float pdist(float4 me, float4 p) {
  float dot = fmaf(me.x, p.x, fmaf(me.y, p.y, me.z * p.z));
  return fmaf(-2.f, dot, me.w + p.w);
}

// ---------- shared kernels ----------

__global__ void __launch_bounds__(256) k_prep(const float* __restrict__ x,
                                              float4* __restrict__ xyz4,
                                              float* __restrict__ feat,
                                              float* __restrict__ outp)
{
  int i = blockIdx.x * 256 + threadIdx.x;
  const float* xr = x + (size_t)i * 67;
  float a = xr[0], b = xr[1], c = xr[2];
  xyz4[i] = make_float4(a, b, c, a * a + b * b + c * c);
  outp[i * 3 + 0] = a; outp[i * 3 + 1] = b; outp[i * 3 + 2] = c;
  float* fd = feat + (size_t)i * CFEAT;
#pragma unroll
  for (int cc = 0; cc < CFEAT; ++cc) fd[cc] = xr[3 + cc];
}

__global__ void __launch_bounds__(256) k_knn(const float4* __restrict__ xyz4,
                                             int* __restrict__ idxb)
{
  __shared__ float sbd[2 * 128 * 20];
  __shared__ float stau[128];
  __shared__ int   scnt[128];
  __shared__ int   stcnt[128];
  __shared__ int   sties[128 * 16];
  int t = threadIdx.x;
  int q = t & 127, s = t >> 7;
  int b = blockIdx.x >> 5;
  int n = ((blockIdx.x & 31) << 7) + q;
  const float4* pts = xyz4 + (size_t)b * NN;
  float4 me = pts[n];
  if (t < 128) { scnt[t] = 0; stcnt[t] = 0; }
  int m0 = s << 11;
  float bd[KK];
#pragma unroll
  for (int j = 0; j < KK; ++j) bd[j] = 3.4e38f;
#pragma unroll 2
  for (int m = m0; m < m0 + 2048; ++m) {
    float4 p = pts[m];
    float d = pdist(me, p);
#pragma unroll
    for (int j = KK - 1; j >= 1; --j)
      bd[j] = __builtin_amdgcn_fmed3f(d, bd[j - 1], bd[j]);
    bd[0] = fminf(bd[0], d);
  }
  float* myl = sbd + (s * 128 + q) * 20;
#pragma unroll
  for (int j = 0; j < KK; ++j) myl[j] = bd[j];
  __syncthreads();
  if (t < 128) {
    const float* A = sbd + t * 20;
    const float* Bl = sbd + (128 + t) * 20;
    int ia = 0, ib = 0; float tau = 0.f;
#pragma unroll 1
    for (int r = 0; r < KK; ++r) {
      float a = A[ia], bb = Bl[ib];
      if (a <= bb) { tau = a; ++ia; } else { tau = bb; ++ib; }
    }
    stau[t] = tau;
  }
  __syncthreads();
  float tau = stau[q];
  size_t obase = ((size_t)b * NN + n) * KK;
#pragma unroll 2
  for (int m = m0; m < m0 + 2048; ++m) {
    float4 p = pts[m];
    float d = pdist(me, p);
    if (d < tau) {
      int slot = atomicAdd(&scnt[q], 1);
      idxb[obase + slot] = m;
    } else if (d == tau) {
      int ts_ = atomicAdd(&stcnt[q], 1);
      if (ts_ < 16) sties[q * 16 + ts_] = m;
    }
  }
  __syncthreads();
  if (t < 128) {
    int c1 = scnt[t];
    int tc = min(stcnt[t], 16);
    int need = KK - c1;
    size_t ob = ((size_t)b * NN + (((blockIdx.x & 31) << 7) + t)) * KK;
    int last = -1;
#pragma unroll 1
    for (int r = 0; r < need; ++r) {
      int best = 0x7fffffff;
      for (int u = 0; u < tc; ++u) {
        int mv = sties[t * 16 + u];
        if (mv > last && mv < best) best = mv;
      }
      if (best == 0x7fffffff) best = 0;
      idxb[ob + c1 + r] = best;
      last = best;
    }
  }
}

__global__ void k_red1(const float* __restrict__ st1, const float* __restrict__ g1,
                       const float* __restrict__ b1, const float* __restrict__ gv,
                       const float* __restrict__ bv, float* __restrict__ par)
{
  int o = threadIdx.x;
  const float inv = 1.f / (float)ITEMS;
  if (o < 64) {
    float s = 0.f, s2 = 0.f;
    for (int j = 0; j < 64; ++j) { s += st1[j * 160 + o]; s2 += st1[j * 160 + 64 + o]; }
    float mu = s * inv, var = s2 * inv - mu * mu;
    float a = g1[o] * rsqrtf(var + EPSV);
    par[o] = a; par[64 + o] = b1[o] - mu * a;
  } else if (o < 80) {
    int v = o - 64;
    float s = 0.f, s2 = 0.f;
    for (int j = 0; j < 64; ++j) { s += st1[j * 160 + 128 + v]; s2 += st1[j * 160 + 144 + v]; }
    float mu = s * inv, var = s2 * inv - mu * mu;
    float a = gv[v] * rsqrtf(var + EPSV);
    par[128 + v] = a; par[144 + v] = bv[v] - mu * a;
  }
}

__global__ void k_red2(const float* __restrict__ st2, const float* __restrict__ g2,
                       const float* __restrict__ b2, float* __restrict__ par)
{
  int o = threadIdx.x; // 64
  float s = 0.f, s2 = 0.f;
  for (int j = 0; j < 64; ++j) { s += st2[j * 128 + o]; s2 += st2[j * 128 + 64 + o]; }
  const float inv = 1.f / (float)ITEMS;
  float mu = s * inv, var = s2 * inv - mu * mu;
  float a = g2[o] * rsqrtf(var + EPSV);
  par[160 + o] = a; par[224 + o] = b2[o] - mu * a;
}

// ---------- FAST PATH (needs ~200 MB ws) ----------

// fcat pass #1: t1 (64) + tv (16): stats + bf16 store
__global__ void __launch_bounds__(256, 3) k_s1f(
    const float4* __restrict__ xyz4, const float* __restrict__ feat,
    const int* __restrict__ idxb, const float* __restrict__ W1,
    const float* __restrict__ Wv, const float* __restrict__ Wh,
    float* __restrict__ st1,
    __hip_bfloat16* __restrict__ t1g, __hip_bfloat16* __restrict__ tvg)
{
  int t = blockIdx.x * 256 + threadIdx.x;
  int bn = t / KK, k = t - bn * KK, b = bn >> 12;
  int nb = idxb[(size_t)bn * KK + k];
  const float* fme = feat + (size_t)bn * CFEAT;
  const float* fnb = feat + ((size_t)b * NN + nb) * CFEAT;
  float4 pn = xyz4[(size_t)b * NN + nb];
  float4 pm = xyz4[bn];
  float rx = pn.x - pm.x, ry = pn.y - pm.y, rz = pn.z - pm.z;
  float a1[CHN], av[DVV];
#pragma unroll
  for (int o = 0; o < CHN; ++o) a1[o] = 0.f;
#pragma unroll
  for (int o = 0; o < DVV; ++o) av[o] = 0.f;
#pragma unroll 1
  for (int ch = 0; ch < 9; ++ch) {
    float fc[16];
    build_chunk(ch, fme, fnb, rx, ry, rz, Wh, fc);
    accum_chunk<CHN>(W1, ch, fc, a1);
    accum_chunk<DVV>(Wv, ch, fc, av);
  }
  __hip_bfloat162* t1p = (__hip_bfloat162*)(t1g + (size_t)t * CHN);
#pragma unroll
  for (int o = 0; o < CHN; o += 2) {
    float2 f2; f2.x = a1[o]; f2.y = a1[o + 1];
    t1p[o >> 1] = __float22bfloat162_rn(f2);
  }
  __hip_bfloat162* tvp = (__hip_bfloat162*)(tvg + (size_t)t * DVV);
#pragma unroll
  for (int o = 0; o < DVV; o += 2) {
    float2 f2; f2.x = av[o]; f2.y = av[o + 1];
    tvp[o >> 1] = __float22bfloat162_rn(f2);
  }
  float* slot = st1 + (blockIdx.x & 63) * 160;
  int lane = threadIdx.x & 63;
#pragma unroll
  for (int o = 0; o < CHN; ++o) {
    float s = wred(a1[o]), s2 = wred(a1[o] * a1[o]);
    if (lane == 0) { atomicAdd(&slot[o], s); atomicAdd(&slot[CHN + o], s2); }
  }
#pragma unroll
  for (int o = 0; o < DVV; ++o) {
    float s = wred(av[o]), s2 = wred(av[o] * av[o]);
    if (lane == 0) { atomicAdd(&slot[128 + o], s); atomicAdd(&slot[128 + DVV + o], s2); }
  }
}

// fcat pass #2: ak = Wk@fcat, bf16 store (no stats needed)
__global__ void __launch_bounds__(256, 4) k_skf(
    const float4* __restrict__ xyz4, const float* __restrict__ feat,
    const int* __restrict__ idxb, const float* __restrict__ Wk,
    const float* __restrict__ Wh, __hip_bfloat16* __restrict__ akg)
{
  int t = blockIdx.x * 256 + threadIdx.x;
  int bn = t / KK, k = t - bn * KK, b = bn >> 12;
  int nb = idxb[(size_t)bn * KK + k];
  const float* fme = feat + (size_t)bn * CFEAT;
  const float* fnb = feat + ((size_t)b * NN + nb) * CFEAT;
  float4 pn = xyz4[(size_t)b * NN + nb];
  float4 pm = xyz4[bn];
  float rx = pn.x - pm.x, ry = pn.y - pm.y, rz = pn.z - pm.z;
  float ak[DKK];
#pragma unroll
  for (int o = 0; o < DKK; ++o) ak[o] = 0.f;
#pragma unroll 1
  for (int ch = 0; ch < 9; ++ch) {
    float fc[16];
    build_chunk(ch, fme, fnb, rx, ry, rz, Wh, fc);
    accum_chunk<DKK>(Wk, ch, fc, ak);
  }
  __hip_bfloat162* akp = (__hip_bfloat162*)(akg + (size_t)t * DKK);
#pragma unroll
  for (int o = 0; o < DKK; o += 2) {
    float2 f2; f2.x = ak[o]; f2.y = ak[o + 1];
    akp[o >> 1] = __float22bfloat162_rn(f2);
  }
}

// t2 stats from cached t1
__global__ void __launch_bounds__(256, 4) k_s2f(
    const __hip_bfloat16* __restrict__ t1g, const float* __restrict__ W2,
    const float* __restrict__ par, float* __restrict__ st2)
{
  int t = blockIdx.x * 256 + threadIdx.x;
  const unsigned* tp = (const unsigned*)(t1g + (size_t)t * CHN);
  float h1[CHN];
#pragma unroll
  for (int i = 0; i < CHN / 2; ++i) {
    unsigned w = tp[i];
    float lo = __uint_as_float(w << 16);
    float hi = __uint_as_float(w & 0xffff0000u);
    h1[2 * i]     = fmaxf(fmaf(lo, par[2 * i],     par[64 + 2 * i]),     0.f);
    h1[2 * i + 1] = fmaxf(fmaf(hi, par[2 * i + 1], par[64 + 2 * i + 1]), 0.f);
  }
  float* slot = st2 + (blockIdx.x & 63) * 128;
  int lane = threadIdx.x & 63;
#pragma unroll 1
  for (int o = 0; o < CHN; ++o) {
    const float* w = W2 + o * CHN;
    float c0 = 0.f, c1 = 0.f, c2 = 0.f, c3 = 0.f;
#pragma unroll
    for (int c = 0; c < CHN; c += 4) {
      c0 = fmaf(w[c + 0], h1[c + 0], c0); c1 = fmaf(w[c + 1], h1[c + 1], c1);
      c2 = fmaf(w[c + 2], h1[c + 2], c2); c3 = fmaf(w[c + 3], h1[c + 3], c3);
    }
    float v = (c0 + c1) + (c2 + c3);
    float s = wred(v), s2 = wred(v * v);
    if (lane == 0) { atomicAdd(&slot[o], s); atomicAdd(&slot[64 + o], s2); }
  }
}

// main pass from cached t1/ak/tv: fq = max_k h2; softmax; kv
#define P3P 16
__global__ void __launch_bounds__(320, 2) k_p3f(
    const __hip_bfloat16* __restrict__ t1g, const __hip_bfloat16* __restrict__ akg,
    const __hip_bfloat16* __restrict__ tvg, const float* __restrict__ W2,
    const float* __restrict__ par, float* __restrict__ fqg,
    __hip_bfloat16* __restrict__ kvg)
{
  __shared__ float sl[P3P][KK][DKK + 1];
  __shared__ float sv[P3P][KK][DVV + 1];
  __shared__ unsigned sfq[P3P][CHN];
  __shared__ float sm[P3P][DKK], ssi[P3P][DKK];
  int tid = threadIdx.x;
  for (int i = tid; i < P3P * CHN; i += 320) ((unsigned*)sfq)[i] = 0u;
  __syncthreads();
  int p = tid / KK, k = tid - p * KK;
  size_t item = (size_t)(blockIdx.x * P3P + p) * KK + k;
  // ak -> logits LDS
  const unsigned* ap = (const unsigned*)(akg + item * DKK);
#pragma unroll
  for (int i = 0; i < DKK / 2; ++i) {
    unsigned w = ap[i];
    sl[p][k][2 * i]     = __uint_as_float(w << 16);
    sl[p][k][2 * i + 1] = __uint_as_float(w & 0xffff0000u);
  }
  // tv -> BNv -> LDS
  const unsigned* vp = (const unsigned*)(tvg + item * DVV);
#pragma unroll
  for (int i = 0; i < DVV / 2; ++i) {
    unsigned w = vp[i];
    float lo = __uint_as_float(w << 16);
    float hi = __uint_as_float(w & 0xffff0000u);
    sv[p][k][2 * i]     = fmaf(lo, par[128 + 2 * i],     par[144 + 2 * i]);
    sv[p][k][2 * i + 1] = fmaf(hi, par[128 + 2 * i + 1], par[144 + 2 * i + 1]);
  }
  // t1 -> h1
  const unsigned* tp = (const unsigned*)(t1g + item * CHN);
  float h1[CHN];
#pragma unroll
  for (int i = 0; i < CHN / 2; ++i) {
    unsigned w = tp[i];
    float lo = __uint_as_float(w << 16);
    float hi = __uint_as_float(w & 0xffff0000u);
    h1[2 * i]     = fmaxf(fmaf(lo, par[2 * i],     par[64 + 2 * i]),     0.f);
    h1[2 * i + 1] = fmaxf(fmaf(hi, par[2 * i + 1], par[64 + 2 * i + 1]), 0.f);
  }
#pragma unroll 1
  for (int o = 0; o < CHN; ++o) {
    const float* w = W2 + o * CHN;
    float c0 = 0.f, c1 = 0.f, c2 = 0.f, c3 = 0.f;
#pragma unroll
    for (int c = 0; c < CHN; c += 4) {
      c0 = fmaf(w[c + 0], h1[c + 0], c0); c1 = fmaf(w[c + 1], h1[c + 1], c1);
      c2 = fmaf(w[c + 2], h1[c + 2], c2); c3 = fmaf(w[c + 3], h1[c + 3], c3);
    }
    float v = (c0 + c1) + (c2 + c3);
    float h2 = fmaxf(fmaf(v, par[160 + o], par[224 + o]), 0.f);
    atomicMax(&sfq[p][o], __float_as_uint(h2));
  }
  __syncthreads();
  for (int i = tid; i < P3P * CHN; i += 320)
    fqg[(size_t)blockIdx.x * (P3P * CHN) + i] = __uint_as_float(sfq[i >> 6][i & 63]);
  for (int pd = tid; pd < P3P * DKK; pd += 320) {
    int pp = pd >> 5, d = pd & 31;
    float m = -1e30f;
#pragma unroll
    for (int q = 0; q < KK; ++q) m = fmaxf(m, sl[pp][q][d]);
    float S = 0.f;
#pragma unroll
    for (int q = 0; q < KK; ++q) S += __expf(sl[pp][q][d] - m);
    sm[pp][d] = m; ssi[pp][d] = 1.f / S;
  }
  __syncthreads();
  for (int pd = tid; pd < P3P * DKK; pd += 320) {
    int pp = pd >> 5, d = pd & 31;
    float m = sm[pp][d], Si = ssi[pp][d];
    float a[DVV];
#pragma unroll
    for (int v = 0; v < DVV; ++v) a[v] = 0.f;
#pragma unroll
    for (int q = 0; q < KK; ++q) {
      float wgt = __expf(sl[pp][q][d] - m) * Si;
#pragma unroll
      for (int v = 0; v < DVV; ++v) a[v] = fmaf(wgt, sv[pp][q][v], a[v]);
    }
    __hip_bfloat162* dst = (__hip_bfloat162*)
        (kvg + ((size_t)(blockIdx.x * P3P + pp) * DKK + d) * DVV);
#pragma unroll
    for (int v = 0; v < DVV; v += 2) {
      float2 f2; f2.x = a[v]; f2.y = a[v + 1];
      dst[v >> 1] = __float22bfloat162_rn(f2);
    }
  }
}

// ---------- FALLBACK PATH (round-3 kernels, used if ws too small) ----------

__global__ void __launch_bounds__(256, 3) k_s1(
    const float4* __restrict__ xyz4, const float* __restrict__ feat,
    const int* __restrict__ idxb, const float* __restrict__ W1,
    const float* __restrict__ Wv, const float* __restrict__ Wh,
    float* __restrict__ st1)
{
  int t = blockIdx.x * 256 + threadIdx.x;
  int bn = t / KK, k = t - bn * KK, b = bn >> 12;
  int nb = idxb[(size_t)bn * KK + k];
  const float* fme = feat + (size_t)bn * CFEAT;
  const float* fnb = feat + ((size_t)b * NN + nb) * CFEAT;
  float4 pn = xyz4[(size_t)b * NN + nb];
  float4 pm = xyz4[bn];
  float rx = pn.x - pm.x, ry = pn.y - pm.y, rz = pn.z - pm.z;
  float a1[CHN], av[DVV];
#pragma unroll
  for (int o = 0; o < CHN; ++o) a1[o] = 0.f;
#pragma unroll
  for (int o = 0; o < DVV; ++o) av[o] = 0.f;
#pragma unroll 1
  for (int ch = 0; ch < 9; ++ch) {
    float fc[16];
    build_chunk(ch, fme, fnb, rx, ry, rz, Wh, fc);
    accum_chunk<CHN>(W1, ch, fc, a1);
    accum_chunk<DVV>(Wv, ch, fc, av);
  }
  float* slot = st1 + (blockIdx.x & 63) * 160;
  int lane = threadIdx.x & 63;
#pragma unroll
  for (int o = 0; o < CHN; ++o) {
    float s = wred(a1[o]), s2 = wred(a1[o] * a1[o]);
    if (lane == 0) { atomicAdd(&slot[o], s); atomicAdd(&slot[CHN + o], s2); }
  }
#pragma unroll
  for (int o = 0; o < DVV; ++o) {
    float s = wred(av[o]), s2 = wred(av[o] * av[o]);
    if (lane == 0) { atomicAdd(&slot[128 + o], s); atomicAdd(&slot[128 + DVV + o], s2); }
  }
}

__global__ void __launch_bounds__(256, 3) k_s2(
    const float4* __restrict__ xyz4, const float* __restrict__ feat,
    const int* __restrict__ idxb, const float* __restrict__ W1,
    const float* __restrict__ W2, const float* __restrict__ Wh,
    const float* __restrict__ par, float* __restrict__ st2)
{
  int t = blockIdx.x * 256 + threadIdx.x;
  int bn = t / KK, k = t - bn * KK, b = bn >> 12;
  int nb = idxb[(size_t)bn * KK + k];
  const float* fme = feat + (size_t)bn * CFEAT;
  const float* fnb = feat + ((size_t)b * NN + nb) * CFEAT;
  float4 pn = xyz4[(size_t)b * NN + nb];
  float4 pm = xyz4[bn];
  float rx = pn.x - pm.x, ry = pn.y - pm.y, rz = pn.z - pm.z;
  float a1[CHN];
#pragma unroll
  for (int o = 0; o < CHN; ++o) a1[o] = 0.f;
#pragma unroll 1
  for (int ch = 0; ch < 9; ++ch) {
    float fc[16];
    build_chunk(ch, fme, fnb, rx, ry, rz, Wh, fc);
    accum_chunk<CHN>(W1, ch, fc, a1);
  }
#pragma unroll
  for (int c = 0; c < CHN; ++c) a1[c] = fmaxf(fmaf(a1[c], par[c], par[64 + c]), 0.f);
  float* slot = st2 + (blockIdx.x & 63) * 128;
  int lane = threadIdx.x & 63;
#pragma unroll 1
  for (int o = 0; o < CHN; ++o) {
    const float* w = W2 + o * CHN;
    float c0 = 0.f, c1 = 0.f, c2 = 0.f, c3 = 0.f;
#pragma unroll
    for (int c = 0; c < CHN; c += 4) {
      c0 = fmaf(w[c + 0], a1[c + 0], c0); c1 = fmaf(w[c + 1], a1[c + 1], c1);
      c2 = fmaf(w[c + 2], a1[c + 2], c2); c3 = fmaf(w[c + 3], a1[c + 3], c3);
    }
    float v = (c0 + c1) + (c2 + c3);
    float s = wred(v), s2 = wred(v * v);
    if (lane == 0) { atomicAdd(&slot[o], s); atomicAdd(&slot[64 + o], s2); }
  }
}

__global__ void __launch_bounds__(320, 2) k_p3(
    const float4* __restrict__ xyz4, const float* __restrict__ feat,
    const int* __restrict__ idxb, const float* __restrict__ W1,
    const float* __restrict__ W2, const float* __restrict__ Wk,
    const float* __restrict__ Wv, const float* __restrict__ Wh,
    const float* __restrict__ par, float* __restrict__ fqg,
    __hip_bfloat16* __restrict__ kvg)
{
  __shared__ float sl[P3P][KK][DKK + 1];
  __shared__ float sv[P3P][KK][DVV + 1];
  __shared__ unsigned sfq[P3P][CHN];
  __shared__ float sm[P3P][DKK], ssi[P3P][DKK];
  int tid = threadIdx.x;
  for (int i = tid; i < P3P * CHN; i += 320) ((unsigned*)sfq)[i] = 0u;
  __syncthreads();
  int p = tid / KK, k = tid - p * KK;
  int bn = blockIdx.x * P3P + p, b = bn >> 12;
  int nb = idxb[(size_t)bn * KK + k];
  const float* fme = feat + (size_t)bn * CFEAT;
  const float* fnb = feat + ((size_t)b * NN + nb) * CFEAT;
  float4 pn = xyz4[(size_t)b * NN + nb];
  float4 pm = xyz4[bn];
  float rx = pn.x - pm.x, ry = pn.y - pm.y, rz = pn.z - pm.z;
  float a1[CHN], ak[DKK], av[DVV];
#pragma unroll
  for (int o = 0; o < CHN; ++o) a1[o] = 0.f;
#pragma unroll
  for (int o = 0; o < DKK; ++o) ak[o] = 0.f;
#pragma unroll
  for (int o = 0; o < DVV; ++o) av[o] = 0.f;
#pragma unroll 1
  for (int ch = 0; ch < 9; ++ch) {
    float fc[16];
    build_chunk(ch, fme, fnb, rx, ry, rz, Wh, fc);
    accum_chunk<CHN>(W1, ch, fc, a1);
    accum_chunk<DKK>(Wk, ch, fc, ak);
    accum_chunk<DVV>(Wv, ch, fc, av);
  }
#pragma unroll
  for (int d = 0; d < DKK; ++d) sl[p][k][d] = ak[d];
#pragma unroll
  for (int v = 0; v < DVV; ++v)
    sv[p][k][v] = fmaf(av[v], par[128 + v], par[144 + v]);
#pragma unroll
  for (int c = 0; c < CHN; ++c) a1[c] = fmaxf(fmaf(a1[c], par[c], par[64 + c]), 0.f);
#pragma unroll 1
  for (int o = 0; o < CHN; ++o) {
    const float* w = W2 + o * CHN;
    float c0 = 0.f, c1 = 0.f, c2 = 0.f, c3 = 0.f;
#pragma unroll
    for (int c = 0; c < CHN; c += 4) {
      c0 = fmaf(w[c + 0], a1[c + 0], c0); c1 = fmaf(w[c + 1], a1[c + 1], c1);
      c2 = fmaf(w[c + 2], a1[c + 2], c2); c3 = fmaf(w[c + 3], a1[c + 3], c3);
    }
    float v = (c0 + c1) + (c2 + c3);
    float h2 = fmaxf(fmaf(v, par[160 + o], par[224 + o]), 0.f);
    atomicMax(&sfq[p][o], __float_as_uint(h2));
  }
  __syncthreads();
  for (int i = tid; i < P3P * CHN; i += 320)
    fqg[(size_t)blockIdx.x * (P3P * CHN) + i] = __uint_as_float(sfq[i >> 6][i & 63]);
  for (int pd = tid; pd < P3P * DKK; pd += 320) {
    int pp = pd >> 5, d = pd & 31;
    float m = -1e30f;
#pragma unroll
    for (int q = 0; q < KK; ++q) m = fmaxf(m, sl[pp][q][d]);
    float S = 0.f;
#pragma unroll
    for (int q = 0; q < KK; ++q) S += __expf(sl[pp][q][d] - m);
    sm[pp][d] = m; ssi[pp][d] = 1.f / S;
  }
  __syncthreads();
  for (int pd = tid; pd < P3P * DKK; pd += 320) {
    int pp = pd >> 5, d = pd & 31;
    float m = sm[pp][d], Si = ssi[pp][d];
    float a[DVV];
#pragma unroll
    for (int v = 0; v < DVV; ++v) a[v] = 0.f;
#pragma unroll
    for (int q = 0; q < KK; ++q) {
      float wgt = __expf(sl[pp][q][d] - m) * Si;
#pragma unroll
      for (int v = 0; v < DVV; ++v) a[v] = fmaf(wgt, sv[pp][q][v], a[v]);
    }
    __hip_bfloat162* dst = (__hip_bfloat162*)
        (kvg + ((size_t)(blockIdx.x * P3P + pp) * DKK + d) * DVV);
#pragma unroll
    for (int v = 0; v < DVV; v += 2) {
      float2 f2; f2.x = a[v]; f2.y = a[v + 1];
      dst[v >> 1] = __float22bfloat162_rn(f2);
    }
  }
}

// ---------- tail kernels (shared) ----------

__global__ void __launch_bounds__(128, 2) k_pq(const float* __restrict__ fqg,
                                               const float* __restrict__ Wq,
                                               float* __restrict__ stq,
                                               float* __restrict__ q2g)
{
  int bn = blockIdx.x * 128 + threadIdx.x;
  float fq[CHN];
#pragma unroll
  for (int c = 0; c < CHN; c += 4) {
    float4 v4 = *(const float4*)(fqg + (size_t)bn * CHN + c);
    fq[c] = v4.x; fq[c + 1] = v4.y; fq[c + 2] = v4.z; fq[c + 3] = v4.w;
  }
  float* slot = stq + (blockIdx.x & 63) * 512;
  int lane = threadIdx.x & 63;
#pragma unroll 1
  for (int o = 0; o < NQC; ++o) {
    const float* w = Wq + o * CHN;
    float a0 = 0.f, a1 = 0.f, a2 = 0.f, a3 = 0.f;
#pragma unroll
    for (int c = 0; c < CHN; c += 4) {
      a0 = fmaf(w[c], fq[c], a0); a1 = fmaf(w[c + 1], fq[c + 1], a1);
      a2 = fmaf(w[c + 2], fq[c + 2], a2); a3 = fmaf(w[c + 3], fq[c + 3], a3);
    }
    float v = (a0 + a1) + (a2 + a3);
    q2g[(size_t)bn * NQC + o] = v;
    float s = wred(v), s2 = wred(v * v);
    if (lane == 0) { atomicAdd(&slot[o], s); atomicAdd(&slot[256 + o], s2); }
  }
}

__global__ void k_redq(const float* __restrict__ stq, const float* __restrict__ gq,
                       const float* __restrict__ bq, float* __restrict__ par)
{
  int o = threadIdx.x; // 256
  float s = 0.f, s2 = 0.f;
  for (int j = 0; j < 64; ++j) { s += stq[j * 512 + o]; s2 += stq[j * 512 + 256 + o]; }
  const float inv = 1.f / (float)BNTOT;
  float mu = s * inv, var = s2 * inv - mu * mu;
  float a = gq[o] * rsqrtf(var + EPSV);
  par[288 + o] = a; par[544 + o] = bq[o] - mu * a;
}

__global__ void __launch_bounds__(64) k_p4(const float* __restrict__ q2g,
                                           const __hip_bfloat16* __restrict__ kvg,
                                           const float* __restrict__ par,
                                           float* __restrict__ outp)
{
  __shared__ float sq2[NQC], skv[DKK * DVV];
  int t = threadIdx.x;
  int b = blockIdx.x & 7, n = blockIdx.x >> 3;
  int bn = (b << 12) | n;
#pragma unroll
  for (int j = 0; j < 8; ++j)
    skv[t + 64 * j] = __bfloat162float(kvg[(size_t)bn * 512 + t + 64 * j]);
#pragma unroll
  for (int j = 0; j < 4; ++j) {
    int o = t + 64 * j;
    float v = q2g[(size_t)bn * NQC + o];
    sq2[o] = fmaxf(fmaf(v, par[288 + o], par[544 + o]), 0.f);
  }
  __syncthreads();
#pragma unroll
  for (int j = 0; j < 2; ++j) {
    int ch = t + 64 * j, h = ch >> 4, vv = ch & 15;
    float a = 0.f;
#pragma unroll
    for (int d = 0; d < DKK; ++d) a = fmaf(sq2[h * DKK + d], skv[d * DVV + vv], a);
    outp[(size_t)BNTOT * 3 + ((size_t)(b * 128 + ch)) * NN + n] = a;
  }
}

// ---------- launch ----------

extern "C" void kernel_launch(void* const* d_in, const int* in_sizes, int n_in,
                              void* d_out, int out_size, void* d_ws, size_t ws_size,
                              hipStream_t stream)
{
  const float* x  = (const float*)d_in[0];
  const float* W1 = (const float*)d_in[1];
  const float* g1 = (const float*)d_in[2];
  const float* b1 = (const float*)d_in[3];
  const float* W2 = (const float*)d_in[4];
  const float* g2 = (const float*)d_in[5];
  const float* b2 = (const float*)d_in[6];
  const float* Wv = (const float*)d_in[7];
  const float* gv = (const float*)d_in[8];
  const float* bv = (const float*)d_in[9];
  const float* Wk = (const float*)d_in[10];
  const float* Wq = (const float*)d_in[11];
  const float* gq = (const float*)d_in[12];
  const float* bq = (const float*)d_in[13];
  const float* Wh = (const float*)d_in[14];

  float* ws = (float*)d_ws;
  // common prefix (float-word offsets)
  float4* xyz4 = (float4*)ws;                      // 131072
  float*  feat = ws + 131072;                      // 2097152
  int*    idxb = (int*)(ws + 2228224);             // 655360
  float*  st1  = ws + 2883584;                     // 10240
  float*  st2  = ws + 2893824;                     // 8192
  float*  stq  = ws + 2902016;                     // 32768
  float*  par  = ws + 2934784;                     // 800
  float*  fqg  = ws + 2935584;                     // 2097152
  __hip_bfloat16* kvg = (__hip_bfloat16*)(ws + 5032736);  // 8388608 fw
  float*  outp = (float*)d_out;

  const size_t FAST_NEED = (size_t)50121504 * 4;   // ~200.5 MB

  hipMemsetAsync(st1, 0, (size_t)(10240 + 8192 + 32768) * sizeof(float), stream);
  k_prep<<<128, 256, 0, stream>>>(x, xyz4, feat, outp);
  k_knn <<<256, 256, 0, stream>>>(xyz4, idxb);

  if (ws_size >= FAST_NEED) {
    __hip_bfloat16* t1g = (__hip_bfloat16*)(ws + 13421344); // 20971520 fw
    __hip_bfloat16* akg = (__hip_bfloat16*)(ws + 34392864); // 10485760 fw
    __hip_bfloat16* tvg = (__hip_bfloat16*)(ws + 44878624); //  5242880 fw
    float* q2g = ws + 34392864;                             // alias akg (dead by then)
    k_s1f <<<2560, 256, 0, stream>>>(xyz4, feat, idxb, W1, Wv, Wh, st1, t1g, tvg);
    k_skf <<<2560, 256, 0, stream>>>(xyz4, feat, idxb, Wk, Wh, akg);
    k_red1<<<1, 128, 0, stream>>>(st1, g1, b1, gv, bv, par);
    k_s2f <<<2560, 256, 0, stream>>>(t1g, W2, par, st2);
    k_red2<<<1, 64, 0, stream>>>(st2, g2, b2, par);
    k_p3f <<<2048, 320, 0, stream>>>(t1g, akg, tvg, W2, par, fqg, kvg);
    k_pq  <<<256, 128, 0, stream>>>(fqg, Wq, stq, q2g);
    k_redq<<<1, 256, 0, stream>>>(stq, gq, bq, par);
    k_p4  <<<32768, 64, 0, stream>>>(q2g, kvg, par, outp);
  } else {
    float* q2g = ws + 5032736 + 8388608;            // round-3 layout
    k_s1  <<<2560, 256, 0, stream>>>(xyz4, feat, idxb, W1, Wv, Wh, st1);
    k_red1<<<1, 128, 0, stream>>>(st1, g1, b1, gv, bv, par);
    k_s2  <<<2560, 256, 0, stream>>>(xyz4, feat, idxb, W1, W2, Wh, par, st2);
    k_red2<<<1, 64, 0, stream>>>(st2, g2, b2, par);
    k_p3  <<<2048, 320, 0, stream>>>(xyz4, feat, idxb, W1, W2, Wk, Wv, Wh, par, fqg, kvg);
    k_pq  <<<256, 128, 0, stream>>>(fqg, Wq, stq, q2g);
    k_redq<<<1, 256, 0, stream>>>(stq, gq, bq, par);
    k_p4  <<<32768, 64, 0, stream>>>(q2g, kvg, par, outp);
  }
}

// Round 5
// 1461.778 us; speedup vs baseline: 3.7994x; 1.1739x over previous
//
#include <hip/hip_runtime.h>
#include <hip/hip_bf16.h>

#define NB 8
#define NN 4096
#define KK 20
#define CFEAT 64
#define CCAT 144
#define CHN 64
#define NHEAD 8
#define DKK 32
#define DVV 16
#define NQC 256
#define EPSV 1e-5f
#define BNTOT (NB*NN)      /* 32768 */
#define ITEMS (BNTOT*KK)   /* 655360 */

// ---------- helpers ----------

__device__ __forceinline__ float wred(float v) {
#pragma unroll
  for (int off = 32; off > 0; off >>= 1) v += __shfl_down(v, off);
  return v;
}

// build 16 channels of fcat: ch 0..3 = gpn, 4..7 = feat(center), 8 = pos
__device__ __forceinline__ void build_chunk(int ch,
    const float* __restrict__ fme, const float* __restrict__ fnb,
    float rx, float ry, float rz, const float* __restrict__ Wh, float* fc)
{
  if (ch < 4) {
    int c0 = ch * 16;
#pragma unroll
    for (int j = 0; j < 16; j += 4) {
      float4 a = *(const float4*)(fnb + c0 + j);
      float4 m = *(const float4*)(fme + c0 + j);
      fc[j + 0] = a.x - m.x; fc[j + 1] = a.y - m.y;
      fc[j + 2] = a.z - m.z; fc[j + 3] = a.w - m.w;
    }
  } else if (ch < 8) {
    int c0 = (ch - 4) * 16;
#pragma unroll
    for (int j = 0; j < 16; j += 4) {
      float4 m = *(const float4*)(fme + c0 + j);
      fc[j + 0] = m.x; fc[j + 1] = m.y; fc[j + 2] = m.z; fc[j + 3] = m.w;
    }
  } else {
#pragma unroll
    for (int v = 0; v < 16; ++v)
      fc[v] = fmaf(Wh[v * 3], rx, fmaf(Wh[v * 3 + 1], ry, Wh[v * 3 + 2] * rz));
  }
}

template<int NO>
__device__ __forceinline__ void accum_chunk(const float* __restrict__ W, int ch,
                                            const float* fc, float* acc)
{
  const float* wb = W + ch * 16;
#pragma unroll
  for (int o = 0; o < NO; ++o) {
    const float* w = wb + o * CCAT;   // wave-uniform -> s_load
#pragma unroll
    for (int j = 0; j < 16; ++j) acc[o] = fmaf(w[j], fc[j], acc[o]);
  }
}

// identical in phase1/phase2 so d is bit-identical
__device__ __forceinline__ float pdist(float4 me, float4 p) {
  float dot = fmaf(me.x, p.x, fmaf(me.y, p.y, me.z * p.z));
  return fmaf(-2.f, dot, me.w + p.w);
}

// ---------- shared kernels ----------

__global__ void __launch_bounds__(256) k_prep(const float* __restrict__ x,
                                              float4* __restrict__ xyz4,
                                              float* __restrict__ feat,
                                              float* __restrict__ outp)
{
  int i = blockIdx.x * 256 + threadIdx.x;
  const float* xr = x + (size_t)i * 67;
  float a = xr[0], b = xr[1], c = xr[2];
  xyz4[i] = make_float4(a, b, c, a * a + b * b + c * c);
  outp[i * 3 + 0] = a; outp[i * 3 + 1] = b; outp[i * 3 + 2] = c;
  float* fd = feat + (size_t)i * CFEAT;
#pragma unroll
  for (int cc = 0; cc < CFEAT; ++cc) fd[cc] = xr[3 + cc];
}

// exact K=20 NN. Block = 64 queries x 8 segments (512 pts each, wave-uniform seg).
// Phase1: branchless med3 top-20 dists per (query,segment), x2 batched.
// Merge: 8-way merge -> tau = 20th smallest (multiset-exact).
// Phase2: rescan, scatter d<tau; ties d==tau -> lowest index first.
#define KNQ 64
#define KNS 8
__global__ void __launch_bounds__(512) k_knn(const float4* __restrict__ xyz4,
                                             int* __restrict__ idxb)
{
  __shared__ float sbd[KNS][KNQ][21];   // pad 21: conflict-free, +sentinel slot
  __shared__ float stau[KNQ];
  __shared__ int   scnt[KNQ];
  __shared__ int   stcnt[KNQ];
  __shared__ int   sties[KNQ * 16];
  int t = threadIdx.x;
  int q = t & 63, s = t >> 6;           // s wave-uniform
  int b = blockIdx.x >> 6;
  int n = ((blockIdx.x & 63) << 6) + q;
  const float4* pts = xyz4 + (size_t)b * NN;
  float4 me = pts[n];
  if (t < KNQ) { scnt[t] = 0; stcnt[t] = 0; }
  int m0 = s << 9;                      // *512
  float bd[KK];
#pragma unroll
  for (int j = 0; j < KK; ++j) bd[j] = 3.4e38f;
#pragma unroll 1
  for (int m = m0; m < m0 + 512; m += 2) {
    float4 p0 = pts[m];                 // wave-uniform -> s_load_dwordx4
    float4 p1 = pts[m + 1];
    float d0 = pdist(me, p0);
    float d1 = pdist(me, p1);
#pragma unroll
    for (int j = KK - 1; j >= 1; --j)
      bd[j] = __builtin_amdgcn_fmed3f(d0, bd[j - 1], bd[j]);
    bd[0] = fminf(bd[0], d0);
#pragma unroll
    for (int j = KK - 1; j >= 1; --j)
      bd[j] = __builtin_amdgcn_fmed3f(d1, bd[j - 1], bd[j]);
    bd[0] = fminf(bd[0], d1);
  }
#pragma unroll
  for (int j = 0; j < KK; ++j) sbd[s][q][j] = bd[j];
  sbd[s][q][KK] = 3.4e38f;              // sentinel for merge overrun
  __syncthreads();
  if (t < KNQ) {
    int ia[KNS];
#pragma unroll
    for (int ss = 0; ss < KNS; ++ss) ia[ss] = 0;
    float tau = 0.f;
#pragma unroll 1
    for (int r = 0; r < KK; ++r) {
      float best = 3.5e38f; int bs = 0;
#pragma unroll
      for (int ss = 0; ss < KNS; ++ss) {
        float v = sbd[ss][t][ia[ss]];
        if (v < best) { best = v; bs = ss; }
      }
      ia[bs]++;
      tau = best;
    }
    stau[t] = tau;
  }
  __syncthreads();
  float tau = stau[q];
  size_t obase = ((size_t)b * NN + n) * KK;
#pragma unroll 2
  for (int m = m0; m < m0 + 512; ++m) {
    float4 p = pts[m];
    float d = pdist(me, p);
    if (d < tau) {
      int slot = atomicAdd(&scnt[q], 1);
      idxb[obase + slot] = m;
    } else if (d == tau) {
      int ts_ = atomicAdd(&stcnt[q], 1);
      if (ts_ < 16) sties[q * 16 + ts_] = m;
    }
  }
  __syncthreads();
  if (t < KNQ) {
    int c1 = scnt[t];                   // <= 19
    int tc = min(stcnt[t], 16);
    int need = KK - c1;
    size_t ob = ((size_t)b * NN + (((blockIdx.x & 63) << 6) + t)) * KK;
    int last = -1;
#pragma unroll 1
    for (int r = 0; r < need; ++r) {
      int best = 0x7fffffff;
      for (int u = 0; u < tc; ++u) {
        int mv = sties[t * 16 + u];
        if (mv > last && mv < best) best = mv;
      }
      if (best == 0x7fffffff) best = 0;
      idxb[ob + c1 + r] = best;
      last = best;
    }
  }
}

__global__ void k_red1(const float* __restrict__ st1, const float* __restrict__ g1,
                       const float* __restrict__ b1, const float* __restrict__ gv,
                       const float* __restrict__ bv, float* __restrict__ par)
{
  int o = threadIdx.x;
  const float inv = 1.f / (float)ITEMS;
  if (o < 64) {
    float s = 0.f, s2 = 0.f;
    for (int j = 0; j < 64; ++j) { s += st1[j * 160 + o]; s2 += st1[j * 160 + 64 + o]; }
    float mu = s * inv, var = s2 * inv - mu * mu;
    float a = g1[o] * rsqrtf(var + EPSV);
    par[o] = a; par[64 + o] = b1[o] - mu * a;
  } else if (o < 80) {
    int v = o - 64;
    float s = 0.f, s2 = 0.f;
    for (int j = 0; j < 64; ++j) { s += st1[j * 160 + 128 + v]; s2 += st1[j * 160 + 144 + v]; }
    float mu = s * inv, var = s2 * inv - mu * mu;
    float a = gv[v] * rsqrtf(var + EPSV);
    par[128 + v] = a; par[144 + v] = bv[v] - mu * a;
  }
}

__global__ void k_red2(const float* __restrict__ st2, const float* __restrict__ g2,
                       const float* __restrict__ b2, float* __restrict__ par)
{
  int o = threadIdx.x; // 64
  float s = 0.f, s2 = 0.f;
  for (int j = 0; j < 64; ++j) { s += st2[j * 128 + o]; s2 += st2[j * 128 + 64 + o]; }
  const float inv = 1.f / (float)ITEMS;
  float mu = s * inv, var = s2 * inv - mu * mu;
  float a = g2[o] * rsqrtf(var + EPSV);
  par[160 + o] = a; par[224 + o] = b2[o] - mu * a;
}

// ---------- FAST PATH (needs ~200 MB ws) ----------

// fcat pass #1: t1 (64) + tv (16): stats + bf16 store
__global__ void __launch_bounds__(256, 3) k_s1f(
    const float4* __restrict__ xyz4, const float* __restrict__ feat,
    const int* __restrict__ idxb, const float* __restrict__ W1,
    const float* __restrict__ Wv, const float* __restrict__ Wh,
    float* __restrict__ st1,
    __hip_bfloat16* __restrict__ t1g, __hip_bfloat16* __restrict__ tvg)
{
  int t = blockIdx.x * 256 + threadIdx.x;
  int bn = t / KK, k = t - bn * KK, b = bn >> 12;
  int nb = idxb[(size_t)bn * KK + k];
  const float* fme = feat + (size_t)bn * CFEAT;
  const float* fnb = feat + ((size_t)b * NN + nb) * CFEAT;
  float4 pn = xyz4[(size_t)b * NN + nb];
  float4 pm = xyz4[bn];
  float rx = pn.x - pm.x, ry = pn.y - pm.y, rz = pn.z - pm.z;
  float a1[CHN], av[DVV];
#pragma unroll
  for (int o = 0; o < CHN; ++o) a1[o] = 0.f;
#pragma unroll
  for (int o = 0; o < DVV; ++o) av[o] = 0.f;
#pragma unroll 1
  for (int ch = 0; ch < 9; ++ch) {
    float fc[16];
    build_chunk(ch, fme, fnb, rx, ry, rz, Wh, fc);
    accum_chunk<CHN>(W1, ch, fc, a1);
    accum_chunk<DVV>(Wv, ch, fc, av);
  }
  __hip_bfloat162* t1p = (__hip_bfloat162*)(t1g + (size_t)t * CHN);
#pragma unroll
  for (int o = 0; o < CHN; o += 2) {
    float2 f2; f2.x = a1[o]; f2.y = a1[o + 1];
    t1p[o >> 1] = __float22bfloat162_rn(f2);
  }
  __hip_bfloat162* tvp = (__hip_bfloat162*)(tvg + (size_t)t * DVV);
#pragma unroll
  for (int o = 0; o < DVV; o += 2) {
    float2 f2; f2.x = av[o]; f2.y = av[o + 1];
    tvp[o >> 1] = __float22bfloat162_rn(f2);
  }
  float* slot = st1 + (blockIdx.x & 63) * 160;
  int lane = threadIdx.x & 63;
#pragma unroll
  for (int o = 0; o < CHN; ++o) {
    float s = wred(a1[o]), s2 = wred(a1[o] * a1[o]);
    if (lane == 0) { atomicAdd(&slot[o], s); atomicAdd(&slot[CHN + o], s2); }
  }
#pragma unroll
  for (int o = 0; o < DVV; ++o) {
    float s = wred(av[o]), s2 = wred(av[o] * av[o]);
    if (lane == 0) { atomicAdd(&slot[128 + o], s); atomicAdd(&slot[128 + DVV + o], s2); }
  }
}

// fcat pass #2: ak = Wk@fcat, bf16 store
__global__ void __launch_bounds__(256, 4) k_skf(
    const float4* __restrict__ xyz4, const float* __restrict__ feat,
    const int* __restrict__ idxb, const float* __restrict__ Wk,
    const float* __restrict__ Wh, __hip_bfloat16* __restrict__ akg)
{
  int t = blockIdx.x * 256 + threadIdx.x;
  int bn = t / KK, k = t - bn * KK, b = bn >> 12;
  int nb = idxb[(size_t)bn * KK + k];
  const float* fme = feat + (size_t)bn * CFEAT;
  const float* fnb = feat + ((size_t)b * NN + nb) * CFEAT;
  float4 pn = xyz4[(size_t)b * NN + nb];
  float4 pm = xyz4[bn];
  float rx = pn.x - pm.x, ry = pn.y - pm.y, rz = pn.z - pm.z;
  float ak[DKK];
#pragma unroll
  for (int o = 0; o < DKK; ++o) ak[o] = 0.f;
#pragma unroll 1
  for (int ch = 0; ch < 9; ++ch) {
    float fc[16];
    build_chunk(ch, fme, fnb, rx, ry, rz, Wh, fc);
    accum_chunk<DKK>(Wk, ch, fc, ak);
  }
  __hip_bfloat162* akp = (__hip_bfloat162*)(akg + (size_t)t * DKK);
#pragma unroll
  for (int o = 0; o < DKK; o += 2) {
    float2 f2; f2.x = ak[o]; f2.y = ak[o + 1];
    akp[o >> 1] = __float22bfloat162_rn(f2);
  }
}

// t2 stats from cached t1
__global__ void __launch_bounds__(256, 4) k_s2f(
    const __hip_bfloat16* __restrict__ t1g, const float* __restrict__ W2,
    const float* __restrict__ par, float* __restrict__ st2)
{
  int t = blockIdx.x * 256 + threadIdx.x;
  const unsigned* tp = (const unsigned*)(t1g + (size_t)t * CHN);
  float h1[CHN];
#pragma unroll
  for (int i = 0; i < CHN / 2; ++i) {
    unsigned w = tp[i];
    float lo = __uint_as_float(w << 16);
    float hi = __uint_as_float(w & 0xffff0000u);
    h1[2 * i]     = fmaxf(fmaf(lo, par[2 * i],     par[64 + 2 * i]),     0.f);
    h1[2 * i + 1] = fmaxf(fmaf(hi, par[2 * i + 1], par[64 + 2 * i + 1]), 0.f);
  }
  float* slot = st2 + (blockIdx.x & 63) * 128;
  int lane = threadIdx.x & 63;
#pragma unroll 1
  for (int o = 0; o < CHN; ++o) {
    const float* w = W2 + o * CHN;
    float c0 = 0.f, c1 = 0.f, c2 = 0.f, c3 = 0.f;
#pragma unroll
    for (int c = 0; c < CHN; c += 4) {
      c0 = fmaf(w[c + 0], h1[c + 0], c0); c1 = fmaf(w[c + 1], h1[c + 1], c1);
      c2 = fmaf(w[c + 2], h1[c + 2], c2); c3 = fmaf(w[c + 3], h1[c + 3], c3);
    }
    float v = (c0 + c1) + (c2 + c3);
    float s = wred(v), s2 = wred(v * v);
    if (lane == 0) { atomicAdd(&slot[o], s); atomicAdd(&slot[64 + o], s2); }
  }
}

// main pass from cached t1/ak/tv: fq = max_k h2; softmax; kv
#define P3P 16
__global__ void __launch_bounds__(320, 2) k_p3f(
    const __hip_bfloat16* __restrict__ t1g, const __hip_bfloat16* __restrict__ akg,
    const __hip_bfloat16* __restrict__ tvg, const float* __restrict__ W2,
    const float* __restrict__ par, float* __restrict__ fqg,
    __hip_bfloat16* __restrict__ kvg)
{
  __shared__ float sl[P3P][KK][DKK + 1];
  __shared__ float sv[P3P][KK][DVV + 1];
  __shared__ unsigned sfq[P3P][CHN];
  __shared__ float sm[P3P][DKK], ssi[P3P][DKK];
  int tid = threadIdx.x;
  for (int i = tid; i < P3P * CHN; i += 320) ((unsigned*)sfq)[i] = 0u;
  __syncthreads();
  int p = tid / KK, k = tid - p * KK;
  size_t item = (size_t)(blockIdx.x * P3P + p) * KK + k;
  const unsigned* ap = (const unsigned*)(akg + item * DKK);
#pragma unroll
  for (int i = 0; i < DKK / 2; ++i) {
    unsigned w = ap[i];
    sl[p][k][2 * i]     = __uint_as_float(w << 16);
    sl[p][k][2 * i + 1] = __uint_as_float(w & 0xffff0000u);
  }
  const unsigned* vp = (const unsigned*)(tvg + item * DVV);
#pragma unroll
  for (int i = 0; i < DVV / 2; ++i) {
    unsigned w = vp[i];
    float lo = __uint_as_float(w << 16);
    float hi = __uint_as_float(w & 0xffff0000u);
    sv[p][k][2 * i]     = fmaf(lo, par[128 + 2 * i],     par[144 + 2 * i]);
    sv[p][k][2 * i + 1] = fmaf(hi, par[128 + 2 * i + 1], par[144 + 2 * i + 1]);
  }
  const unsigned* tp = (const unsigned*)(t1g + item * CHN);
  float h1[CHN];
#pragma unroll
  for (int i = 0; i < CHN / 2; ++i) {
    unsigned w = tp[i];
    float lo = __uint_as_float(w << 16);
    float hi = __uint_as_float(w & 0xffff0000u);
    h1[2 * i]     = fmaxf(fmaf(lo, par[2 * i],     par[64 + 2 * i]),     0.f);
    h1[2 * i + 1] = fmaxf(fmaf(hi, par[2 * i + 1], par[64 + 2 * i + 1]), 0.f);
  }
#pragma unroll 1
  for (int o = 0; o < CHN; ++o) {
    const float* w = W2 + o * CHN;
    float c0 = 0.f, c1 = 0.f, c2 = 0.f, c3 = 0.f;
#pragma unroll
    for (int c = 0; c < CHN; c += 4) {
      c0 = fmaf(w[c + 0], h1[c + 0], c0); c1 = fmaf(w[c + 1], h1[c + 1], c1);
      c2 = fmaf(w[c + 2], h1[c + 2], c2); c3 = fmaf(w[c + 3], h1[c + 3], c3);
    }
    float v = (c0 + c1) + (c2 + c3);
    float h2 = fmaxf(fmaf(v, par[160 + o], par[224 + o]), 0.f);
    atomicMax(&sfq[p][o], __float_as_uint(h2));
  }
  __syncthreads();
  for (int i = tid; i < P3P * CHN; i += 320)
    fqg[(size_t)blockIdx.x * (P3P * CHN) + i] = __uint_as_float(sfq[i >> 6][i & 63]);
  for (int pd = tid; pd < P3P * DKK; pd += 320) {
    int pp = pd >> 5, d = pd & 31;
    float m = -1e30f;
#pragma unroll
    for (int q = 0; q < KK; ++q) m = fmaxf(m, sl[pp][q][d]);
    float S = 0.f;
#pragma unroll
    for (int q = 0; q < KK; ++q) S += __expf(sl[pp][q][d] - m);
    sm[pp][d] = m; ssi[pp][d] = 1.f / S;
  }
  __syncthreads();
  for (int pd = tid; pd < P3P * DKK; pd += 320) {
    int pp = pd >> 5, d = pd & 31;
    float m = sm[pp][d], Si = ssi[pp][d];
    float a[DVV];
#pragma unroll
    for (int v = 0; v < DVV; ++v) a[v] = 0.f;
#pragma unroll
    for (int q = 0; q < KK; ++q) {
      float wgt = __expf(sl[pp][q][d] - m) * Si;
#pragma unroll
      for (int v = 0; v < DVV; ++v) a[v] = fmaf(wgt, sv[pp][q][v], a[v]);
    }
    __hip_bfloat162* dst = (__hip_bfloat162*)
        (kvg + ((size_t)(blockIdx.x * P3P + pp) * DKK + d) * DVV);
#pragma unroll
    for (int v = 0; v < DVV; v += 2) {
      float2 f2; f2.x = a[v]; f2.y = a[v + 1];
      dst[v >> 1] = __float22bfloat162_rn(f2);
    }
  }
}

// ---------- FALLBACK PATH (used if ws too small) ----------

__global__ void __launch_bounds__(256, 3) k_s1(
    const float4* __restrict__ xyz4, const float* __restrict__ feat,
    const int* __restrict__ idxb, const float* __restrict__ W1,
    const float* __restrict__ Wv, const float* __restrict__ Wh,
    float* __restrict__ st1)
{
  int t = blockIdx.x * 256 + threadIdx.x;
  int bn = t / KK, k = t - bn * KK, b = bn >> 12;
  int nb = idxb[(size_t)bn * KK + k];
  const float* fme = feat + (size_t)bn * CFEAT;
  const float* fnb = feat + ((size_t)b * NN + nb) * CFEAT;
  float4 pn = xyz4[(size_t)b * NN + nb];
  float4 pm = xyz4[bn];
  float rx = pn.x - pm.x, ry = pn.y - pm.y, rz = pn.z - pm.z;
  float a1[CHN], av[DVV];
#pragma unroll
  for (int o = 0; o < CHN; ++o) a1[o] = 0.f;
#pragma unroll
  for (int o = 0; o < DVV; ++o) av[o] = 0.f;
#pragma unroll 1
  for (int ch = 0; ch < 9; ++ch) {
    float fc[16];
    build_chunk(ch, fme, fnb, rx, ry, rz, Wh, fc);
    accum_chunk<CHN>(W1, ch, fc, a1);
    accum_chunk<DVV>(Wv, ch, fc, av);
  }
  float* slot = st1 + (blockIdx.x & 63) * 160;
  int lane = threadIdx.x & 63;
#pragma unroll
  for (int o = 0; o < CHN; ++o) {
    float s = wred(a1[o]), s2 = wred(a1[o] * a1[o]);
    if (lane == 0) { atomicAdd(&slot[o], s); atomicAdd(&slot[CHN + o], s2); }
  }
#pragma unroll
  for (int o = 0; o < DVV; ++o) {
    float s = wred(av[o]), s2 = wred(av[o] * av[o]);
    if (lane == 0) { atomicAdd(&slot[128 + o], s); atomicAdd(&slot[128 + DVV + o], s2); }
  }
}

__global__ void __launch_bounds__(256, 3) k_s2(
    const float4* __restrict__ xyz4, const float* __restrict__ feat,
    const int* __restrict__ idxb, const float* __restrict__ W1,
    const float* __restrict__ W2, const float* __restrict__ Wh,
    const float* __restrict__ par, float* __restrict__ st2)
{
  int t = blockIdx.x * 256 + threadIdx.x;
  int bn = t / KK, k = t - bn * KK, b = bn >> 12;
  int nb = idxb[(size_t)bn * KK + k];
  const float* fme = feat + (size_t)bn * CFEAT;
  const float* fnb = feat + ((size_t)b * NN + nb) * CFEAT;
  float4 pn = xyz4[(size_t)b * NN + nb];
  float4 pm = xyz4[bn];
  float rx = pn.x - pm.x, ry = pn.y - pm.y, rz = pn.z - pm.z;
  float a1[CHN];
#pragma unroll
  for (int o = 0; o < CHN; ++o) a1[o] = 0.f;
#pragma unroll 1
  for (int ch = 0; ch < 9; ++ch) {
    float fc[16];
    build_chunk(ch, fme, fnb, rx, ry, rz, Wh, fc);
    accum_chunk<CHN>(W1, ch, fc, a1);
  }
#pragma unroll
  for (int c = 0; c < CHN; ++c) a1[c] = fmaxf(fmaf(a1[c], par[c], par[64 + c]), 0.f);
  float* slot = st2 + (blockIdx.x & 63) * 128;
  int lane = threadIdx.x & 63;
#pragma unroll 1
  for (int o = 0; o < CHN; ++o) {
    const float* w = W2 + o * CHN;
    float c0 = 0.f, c1 = 0.f, c2 = 0.f, c3 = 0.f;
#pragma unroll
    for (int c = 0; c < CHN; c += 4) {
      c0 = fmaf(w[c + 0], a1[c + 0], c0); c1 = fmaf(w[c + 1], a1[c + 1], c1);
      c2 = fmaf(w[c + 2], a1[c + 2], c2); c3 = fmaf(w[c + 3], a1[c + 3], c3);
    }
    float v = (c0 + c1) + (c2 + c3);
    float s = wred(v), s2 = wred(v * v);
    if (lane == 0) { atomicAdd(&slot[o], s); atomicAdd(&slot[64 + o], s2); }
  }
}

__global__ void __launch_bounds__(320, 2) k_p3(
    const float4* __restrict__ xyz4, const float* __restrict__ feat,
    const int* __restrict__ idxb, const float* __restrict__ W1,
    const float* __restrict__ W2, const float* __restrict__ Wk,
    const float* __restrict__ Wv, const float* __restrict__ Wh,
    const float* __restrict__ par, float* __restrict__ fqg,
    __hip_bfloat16* __restrict__ kvg)
{
  __shared__ float sl[P3P][KK][DKK + 1];
  __shared__ float sv[P3P][KK][DVV + 1];
  __shared__ unsigned sfq[P3P][CHN];
  __shared__ float sm[P3P][DKK], ssi[P3P][DKK];
  int tid = threadIdx.x;
  for (int i = tid; i < P3P * CHN; i += 320) ((unsigned*)sfq)[i] = 0u;
  __syncthreads();
  int p = tid / KK, k = tid - p * KK;
  int bn = blockIdx.x * P3P + p, b = bn >> 12;
  int nb = idxb[(size_t)bn * KK + k];
  const float* fme = feat + (size_t)bn * CFEAT;
  const float* fnb = feat + ((size_t)b * NN + nb) * CFEAT;
  float4 pn = xyz4[(size_t)b * NN + nb];
  float4 pm = xyz4[bn];
  float rx = pn.x - pm.x, ry = pn.y - pm.y, rz = pn.z - pm.z;
  float a1[CHN], ak[DKK], av[DVV];
#pragma unroll
  for (int o = 0; o < CHN; ++o) a1[o] = 0.f;
#pragma unroll
  for (int o = 0; o < DKK; ++o) ak[o] = 0.f;
#pragma unroll
  for (int o = 0; o < DVV; ++o) av[o] = 0.f;
#pragma unroll 1
  for (int ch = 0; ch < 9; ++ch) {
    float fc[16];
    build_chunk(ch, fme, fnb, rx, ry, rz, Wh, fc);
    accum_chunk<CHN>(W1, ch, fc, a1);
    accum_chunk<DKK>(Wk, ch, fc, ak);
    accum_chunk<DVV>(Wv, ch, fc, av);
  }
#pragma unroll
  for (int d = 0; d < DKK; ++d) sl[p][k][d] = ak[d];
#pragma unroll
  for (int v = 0; v < DVV; ++v)
    sv[p][k][v] = fmaf(av[v], par[128 + v], par[144 + v]);
#pragma unroll
  for (int c = 0; c < CHN; ++c) a1[c] = fmaxf(fmaf(a1[c], par[c], par[64 + c]), 0.f);
#pragma unroll 1
  for (int o = 0; o < CHN; ++o) {
    const float* w = W2 + o * CHN;
    float c0 = 0.f, c1 = 0.f, c2 = 0.f, c3 = 0.f;
#pragma unroll
    for (int c = 0; c < CHN; c += 4) {
      c0 = fmaf(w[c + 0], a1[c + 0], c0); c1 = fmaf(w[c + 1], a1[c + 1], c1);
      c2 = fmaf(w[c + 2], a1[c + 2], c2); c3 = fmaf(w[c + 3], a1[c + 3], c3);
    }
    float v = (c0 + c1) + (c2 + c3);
    float h2 = fmaxf(fmaf(v, par[160 + o], par[224 + o]), 0.f);
    atomicMax(&sfq[p][o], __float_as_uint(h2));
  }
  __syncthreads();
  for (int i = tid; i < P3P * CHN; i += 320)
    fqg[(size_t)blockIdx.x * (P3P * CHN) + i] = __uint_as_float(sfq[i >> 6][i & 63]);
  for (int pd = tid; pd < P3P * DKK; pd += 320) {
    int pp = pd >> 5, d = pd & 31;
    float m = -1e30f;
#pragma unroll
    for (int q = 0; q < KK; ++q) m = fmaxf(m, sl[pp][q][d]);
    float S = 0.f;
#pragma unroll
    for (int q = 0; q < KK; ++q) S += __expf(sl[pp][q][d] - m);
    sm[pp][d] = m; ssi[pp][d] = 1.f / S;
  }
  __syncthreads();
  for (int pd = tid; pd < P3P * DKK; pd += 320) {
    int pp = pd >> 5, d = pd & 31;
    float m = sm[pp][d], Si = ssi[pp][d];
    float a[DVV];
#pragma unroll
    for (int v = 0; v < DVV; ++v) a[v] = 0.f;
#pragma unroll
    for (int q = 0; q < KK; ++q) {
      float wgt = __expf(sl[pp][q][d] - m) * Si;
#pragma unroll
      for (int v = 0; v < DVV; ++v) a[v] = fmaf(wgt, sv[pp][q][v], a[v]);
    }
    __hip_bfloat162* dst = (__hip_bfloat162*)
        (kvg + ((size_t)(blockIdx.x * P3P + pp) * DKK + d) * DVV);
#pragma unroll
    for (int v = 0; v < DVV; v += 2) {
      float2 f2; f2.x = a[v]; f2.y = a[v + 1];
      dst[v >> 1] = __float22bfloat162_rn(f2);
    }
  }
}

// ---------- tail kernels (shared) ----------

__global__ void __launch_bounds__(128, 2) k_pq(const float* __restrict__ fqg,
                                               const float* __restrict__ Wq,
                                               float* __restrict__ stq,
                                               float* __restrict__ q2g)
{
  int bn = blockIdx.x * 128 + threadIdx.x;
  float fq[CHN];
#pragma unroll
  for (int c = 0; c < CHN; c += 4) {
    float4 v4 = *(const float4*)(fqg + (size_t)bn * CHN + c);
    fq[c] = v4.x; fq[c + 1] = v4.y; fq[c + 2] = v4.z; fq[c + 3] = v4.w;
  }
  float* slot = stq + (blockIdx.x & 63) * 512;
  int lane = threadIdx.x & 63;
#pragma unroll 1
  for (int o = 0; o < NQC; ++o) {
    const float* w = Wq + o * CHN;
    float a0 = 0.f, a1 = 0.f, a2 = 0.f, a3 = 0.f;
#pragma unroll
    for (int c = 0; c < CHN; c += 4) {
      a0 = fmaf(w[c], fq[c], a0); a1 = fmaf(w[c + 1], fq[c + 1], a1);
      a2 = fmaf(w[c + 2], fq[c + 2], a2); a3 = fmaf(w[c + 3], fq[c + 3], a3);
    }
    float v = (a0 + a1) + (a2 + a3);
    q2g[(size_t)bn * NQC + o] = v;
    float s = wred(v), s2 = wred(v * v);
    if (lane == 0) { atomicAdd(&slot[o], s); atomicAdd(&slot[256 + o], s2); }
  }
}

__global__ void k_redq(const float* __restrict__ stq, const float* __restrict__ gq,
                       const float* __restrict__ bq, float* __restrict__ par)
{
  int o = threadIdx.x; // 256
  float s = 0.f, s2 = 0.f;
  for (int j = 0; j < 64; ++j) { s += stq[j * 512 + o]; s2 += stq[j * 512 + 256 + o]; }
  const float inv = 1.f / (float)BNTOT;
  float mu = s * inv, var = s2 * inv - mu * mu;
  float a = gq[o] * rsqrtf(var + EPSV);
  par[288 + o] = a; par[544 + o] = bq[o] - mu * a;
}

__global__ void __launch_bounds__(64) k_p4(const float* __restrict__ q2g,
                                           const __hip_bfloat16* __restrict__ kvg,
                                           const float* __restrict__ par,
                                           float* __restrict__ outp)
{
  __shared__ float sq2[NQC], skv[DKK * DVV];
  int t = threadIdx.x;
  int b = blockIdx.x & 7, n = blockIdx.x >> 3;
  int bn = (b << 12) | n;
#pragma unroll
  for (int j = 0; j < 8; ++j)
    skv[t + 64 * j] = __bfloat162float(kvg[(size_t)bn * 512 + t + 64 * j]);
#pragma unroll
  for (int j = 0; j < 4; ++j) {
    int o = t + 64 * j;
    float v = q2g[(size_t)bn * NQC + o];
    sq2[o] = fmaxf(fmaf(v, par[288 + o], par[544 + o]), 0.f);
  }
  __syncthreads();
#pragma unroll
  for (int j = 0; j < 2; ++j) {
    int ch = t + 64 * j, h = ch >> 4, vv = ch & 15;
    float a = 0.f;
#pragma unroll
    for (int d = 0; d < DKK; ++d) a = fmaf(sq2[h * DKK + d], skv[d * DVV + vv], a);
    outp[(size_t)BNTOT * 3 + ((size_t)(b * 128 + ch)) * NN + n] = a;
  }
}

// ---------- launch ----------

extern "C" void kernel_launch(void* const* d_in, const int* in_sizes, int n_in,
                              void* d_out, int out_size, void* d_ws, size_t ws_size,
                              hipStream_t stream)
{
  const float* x  = (const float*)d_in[0];
  const float* W1 = (const float*)d_in[1];
  const float* g1 = (const float*)d_in[2];
  const float* b1 = (const float*)d_in[3];
  const float* W2 = (const float*)d_in[4];
  const float* g2 = (const float*)d_in[5];
  const float* b2 = (const float*)d_in[6];
  const float* Wv = (const float*)d_in[7];
  const float* gv = (const float*)d_in[8];
  const float* bv = (const float*)d_in[9];
  const float* Wk = (const float*)d_in[10];
  const float* Wq = (const float*)d_in[11];
  const float* gq = (const float*)d_in[12];
  const float* bq = (const float*)d_in[13];
  const float* Wh = (const float*)d_in[14];

  float* ws = (float*)d_ws;
  float4* xyz4 = (float4*)ws;                      // 131072
  float*  feat = ws + 131072;                      // 2097152
  int*    idxb = (int*)(ws + 2228224);             // 655360
  float*  st1  = ws + 2883584;                     // 10240
  float*  st2  = ws + 2893824;                     // 8192
  float*  stq  = ws + 2902016;                     // 32768
  float*  par  = ws + 2934784;                     // 800
  float*  fqg  = ws + 2935584;                     // 2097152
  __hip_bfloat16* kvg = (__hip_bfloat16*)(ws + 5032736);  // 8388608 fw
  float*  outp = (float*)d_out;

  const size_t FAST_NEED = (size_t)50121504 * 4;   // ~200.5 MB

  hipMemsetAsync(st1, 0, (size_t)(10240 + 8192 + 32768) * sizeof(float), stream);
  k_prep<<<128, 256, 0, stream>>>(x, xyz4, feat, outp);
  k_knn <<<512, 512, 0, stream>>>(xyz4, idxb);

  if (ws_size >= FAST_NEED) {
    __hip_bfloat16* t1g = (__hip_bfloat16*)(ws + 13421344); // 20971520 fw
    __hip_bfloat16* akg = (__hip_bfloat16*)(ws + 34392864); // 10485760 fw
    __hip_bfloat16* tvg = (__hip_bfloat16*)(ws + 44878624); //  5242880 fw
    float* q2g = ws + 34392864;                             // alias akg (dead by then)
    k_s1f <<<2560, 256, 0, stream>>>(xyz4, feat, idxb, W1, Wv, Wh, st1, t1g, tvg);
    k_skf <<<2560, 256, 0, stream>>>(xyz4, feat, idxb, Wk, Wh, akg);
    k_red1<<<1, 128, 0, stream>>>(st1, g1, b1, gv, bv, par);
    k_s2f <<<2560, 256, 0, stream>>>(t1g, W2, par, st2);
    k_red2<<<1, 64, 0, stream>>>(st2, g2, b2, par);
    k_p3f <<<2048, 320, 0, stream>>>(t1g, akg, tvg, W2, par, fqg, kvg);
    k_pq  <<<256, 128, 0, stream>>>(fqg, Wq, stq, q2g);
    k_redq<<<1, 256, 0, stream>>>(stq, gq, bq, par);
    k_p4  <<<32768, 64, 0, stream>>>(q2g, kvg, par, outp);
  } else {
    float* q2g = ws + 5032736 + 8388608;            // round-3 layout
    k_s1  <<<2560, 256, 0, stream>>>(xyz4, feat, idxb, W1, Wv, Wh, st1);
    k_red1<<<1, 128, 0, stream>>>(st1, g1, b1, gv, bv, par);
    k_s2  <<<2560, 256, 0, stream>>>(xyz4, feat, idxb, W1, W2, Wh, par, st2);
    k_red2<<<1, 64, 0, stream>>>(st2, g2, b2, par);
    k_p3  <<<2048, 320, 0, stream>>>(xyz4, feat, idxb, W1, W2, Wk, Wv, Wh, par, fqg, kvg);
    k_pq  <<<256, 128, 0, stream>>>(fqg, Wq, stq, q2g);
    k_redq<<<1, 256, 0, stream>>>(stq, gq, bq, par);
    k_p4  <<<32768, 64, 0, stream>>>(q2g, kvg, par, outp);
  }
}

// Round 6
// 921.140 us; speedup vs baseline: 6.0294x; 1.5869x over previous
//
#include <hip/hip_runtime.h>
#include <hip/hip_bf16.h>

#define NB 8
#define NN 4096
#define KK 20
#define CFEAT 64
#define CCAT 144
#define CHN 64
#define NHEAD 8
#define DKK 32
#define DVV 16
#define NQC 256
#define EPSV 1e-5f
#define BNTOT (NB*NN)      /* 32768 */
#define ITEMS (BNTOT*KK)   /* 655360 */

typedef unsigned short ushort_t;
typedef __attribute__((ext_vector_type(8))) short bf16x8;
typedef __attribute__((ext_vector_type(4))) float f32x4;

// ---------- helpers ----------

__device__ __forceinline__ float wred(float v) {
#pragma unroll
  for (int off = 32; off > 0; off >>= 1) v += __shfl_down(v, off);
  return v;
}

__device__ __forceinline__ ushort_t f2bf(float f) {
  unsigned u = __float_as_uint(f);
  return (ushort_t)((u + 0x7fffu + ((u >> 16) & 1u)) >> 16);
}
__device__ __forceinline__ float bf2f(ushort_t h) {
  return __uint_as_float(((unsigned)h) << 16);
}

// identical in phase1/phase2 so d is bit-identical
__device__ __forceinline__ float pdist(float4 me, float4 p) {
  float dot = fmaf(me.x, p.x, fmaf(me.y, p.y, me.z * p.z));
  return fmaf(-2.f, dot, me.w + p.w);
}

// build 16 channels of fcat (fallback path)
__device__ __forceinline__ void build_chunk(int ch,
    const float* __restrict__ fme, const float* __restrict__ fnb,
    float rx, float ry, float rz, const float* __restrict__ Wh, float* fc)
{
  if (ch < 4) {
    int c0 = ch * 16;
#pragma unroll
    for (int j = 0; j < 16; j += 4) {
      float4 a = *(const float4*)(fnb + c0 + j);
      float4 m = *(const float4*)(fme + c0 + j);
      fc[j + 0] = a.x - m.x; fc[j + 1] = a.y - m.y;
      fc[j + 2] = a.z - m.z; fc[j + 3] = a.w - m.w;
    }
  } else if (ch < 8) {
    int c0 = (ch - 4) * 16;
#pragma unroll
    for (int j = 0; j < 16; j += 4) {
      float4 m = *(const float4*)(fme + c0 + j);
      fc[j + 0] = m.x; fc[j + 1] = m.y; fc[j + 2] = m.z; fc[j + 3] = m.w;
    }
  } else {
#pragma unroll
    for (int v = 0; v < 16; ++v)
      fc[v] = fmaf(Wh[v * 3], rx, fmaf(Wh[v * 3 + 1], ry, Wh[v * 3 + 2] * rz));
  }
}

template<int NO>
__device__ __forceinline__ void accum_chunk(const float* __restrict__ W, int ch,
                                            const float* fc, float* acc)
{
  const float* wb = W + ch * 16;
#pragma unroll
  for (int o = 0; o < NO; ++o) {
    const float* w = wb + o * CCAT;
#pragma unroll
    for (int j = 0; j < 16; ++j) acc[o] = fmaf(w[j], fc[j], acc[o]);
  }
}

// ---------- shared kernels ----------

__global__ void __launch_bounds__(256) k_prep(const float* __restrict__ x,
                                              float4* __restrict__ xyz4,
                                              float* __restrict__ feat,
                                              float* __restrict__ outp)
{
  int i = blockIdx.x * 256 + threadIdx.x;
  const float* xr = x + (size_t)i * 67;
  float a = xr[0], b = xr[1], c = xr[2];
  xyz4[i] = make_float4(a, b, c, a * a + b * b + c * c);
  outp[i * 3 + 0] = a; outp[i * 3 + 1] = b; outp[i * 3 + 2] = c;
  float* fd = feat + (size_t)i * CFEAT;
#pragma unroll
  for (int cc = 0; cc < CFEAT; ++cc) fd[cc] = xr[3 + cc];
}

#define KNQ 64
#define KNS 8
__global__ void __launch_bounds__(512) k_knn(const float4* __restrict__ xyz4,
                                             int* __restrict__ idxb)
{
  __shared__ float sbd[KNS][KNQ][21];
  __shared__ float stau[KNQ];
  __shared__ int   scnt[KNQ];
  __shared__ int   stcnt[KNQ];
  __shared__ int   sties[KNQ * 16];
  int t = threadIdx.x;
  int q = t & 63, s = t >> 6;
  int b = blockIdx.x >> 6;
  int n = ((blockIdx.x & 63) << 6) + q;
  const float4* pts = xyz4 + (size_t)b * NN;
  float4 me = pts[n];
  if (t < KNQ) { scnt[t] = 0; stcnt[t] = 0; }
  int m0 = s << 9;
  float bd[KK];
#pragma unroll
  for (int j = 0; j < KK; ++j) bd[j] = 3.4e38f;
#pragma unroll 1
  for (int m = m0; m < m0 + 512; m += 2) {
    float4 p0 = pts[m];
    float4 p1 = pts[m + 1];
    float d0 = pdist(me, p0);
    float d1 = pdist(me, p1);
#pragma unroll
    for (int j = KK - 1; j >= 1; --j)
      bd[j] = __builtin_amdgcn_fmed3f(d0, bd[j - 1], bd[j]);
    bd[0] = fminf(bd[0], d0);
#pragma unroll
    for (int j = KK - 1; j >= 1; --j)
      bd[j] = __builtin_amdgcn_fmed3f(d1, bd[j - 1], bd[j]);
    bd[0] = fminf(bd[0], d1);
  }
#pragma unroll
  for (int j = 0; j < KK; ++j) sbd[s][q][j] = bd[j];
  sbd[s][q][KK] = 3.4e38f;
  __syncthreads();
  if (t < KNQ) {
    int ia[KNS];
#pragma unroll
    for (int ss = 0; ss < KNS; ++ss) ia[ss] = 0;
    float tau = 0.f;
#pragma unroll 1
    for (int r = 0; r < KK; ++r) {
      float best = 3.5e38f; int bs = 0;
#pragma unroll
      for (int ss = 0; ss < KNS; ++ss) {
        float v = sbd[ss][t][ia[ss]];
        if (v < best) { best = v; bs = ss; }
      }
      ia[bs]++;
      tau = best;
    }
    stau[t] = tau;
  }
  __syncthreads();
  float tau = stau[q];
  size_t obase = ((size_t)b * NN + n) * KK;
#pragma unroll 2
  for (int m = m0; m < m0 + 512; ++m) {
    float4 p = pts[m];
    float d = pdist(me, p);
    if (d < tau) {
      int slot = atomicAdd(&scnt[q], 1);
      idxb[obase + slot] = m;
    } else if (d == tau) {
      int ts_ = atomicAdd(&stcnt[q], 1);
      if (ts_ < 16) sties[q * 16 + ts_] = m;
    }
  }
  __syncthreads();
  if (t < KNQ) {
    int c1 = scnt[t];
    int tc = min(stcnt[t], 16);
    int need = KK - c1;
    size_t ob = ((size_t)b * NN + (((blockIdx.x & 63) << 6) + t)) * KK;
    int last = -1;
#pragma unroll 1
    for (int r = 0; r < need; ++r) {
      int best = 0x7fffffff;
      for (int u = 0; u < tc; ++u) {
        int mv = sties[t * 16 + u];
        if (mv > last && mv < best) best = mv;
      }
      if (best == 0x7fffffff) best = 0;
      idxb[ob + c1 + r] = best;
      last = best;
    }
  }
}

__global__ void k_red1(const float* __restrict__ st1, const float* __restrict__ g1,
                       const float* __restrict__ b1, const float* __restrict__ gv,
                       const float* __restrict__ bv, float* __restrict__ par)
{
  int o = threadIdx.x;
  const float inv = 1.f / (float)ITEMS;
  if (o < 64) {
    float s = 0.f, s2 = 0.f;
    for (int j = 0; j < 64; ++j) { s += st1[j * 160 + o]; s2 += st1[j * 160 + 64 + o]; }
    float mu = s * inv, var = s2 * inv - mu * mu;
    float a = g1[o] * rsqrtf(var + EPSV);
    par[o] = a; par[64 + o] = b1[o] - mu * a;
  } else if (o < 80) {
    int v = o - 64;
    float s = 0.f, s2 = 0.f;
    for (int j = 0; j < 64; ++j) { s += st1[j * 160 + 128 + v]; s2 += st1[j * 160 + 144 + v]; }
    float mu = s * inv, var = s2 * inv - mu * mu;
    float a = gv[v] * rsqrtf(var + EPSV);
    par[128 + v] = a; par[144 + v] = bv[v] - mu * a;
  }
}

__global__ void k_red2(const float* __restrict__ st2, const float* __restrict__ g2,
                       const float* __restrict__ b2, float* __restrict__ par)
{
  int o = threadIdx.x; // 64
  float s = 0.f, s2 = 0.f;
  for (int j = 0; j < 64; ++j) { s += st2[j * 128 + o]; s2 += st2[j * 128 + 64 + o]; }
  const float inv = 1.f / (float)ITEMS;
  float mu = s * inv, var = s2 * inv - mu * mu;
  float a = g2[o] * rsqrtf(var + EPSV);
  par[160 + o] = a; par[224 + o] = b2[o] - mu * a;
}

// ---------- NEW MFMA PATH ----------

// GEMM1: fcat[M=ITEMS x K=160(144)] @ W^T -> [t1:64 | tv:16 | ak:32], bf16 out,
// + BN1 stats for t1/tv. One wave = 16-item M-tile, 4 tiles/wave.
__global__ void __launch_bounds__(256, 2) k_g1(
    const float4* __restrict__ xyz4, const float* __restrict__ feat,
    const int* __restrict__ idxb, const float* __restrict__ W1,
    const float* __restrict__ Wv, const float* __restrict__ Wk,
    const float* __restrict__ Wh, float* __restrict__ st1,
    ushort_t* __restrict__ t1g, ushort_t* __restrict__ akg,
    ushort_t* __restrict__ tvg)
{
  __shared__ ushort_t lds[4][16][120];
  int tid = threadIdx.x;
  int w = tid >> 6, lane = tid & 63;
  int m = lane & 15, quad = lane >> 4;

  // B fragments: B[k][n] -> lane n=lane&15, k=quad*8+j. W rows are outputs.
  bf16x8 Bf[7][5];
#pragma unroll
  for (int nt = 0; nt < 7; ++nt) {
    const float* wrow = (nt < 4) ? (W1 + (nt * 16 + m) * CCAT)
                      : (nt == 4) ? (Wv + m * CCAT)
                      : (Wk + ((nt - 5) * 16 + m) * CCAT);
#pragma unroll
    for (int ks = 0; ks < 5; ++ks) {
      int c0 = ks * 32 + quad * 8;
      bf16x8 f;
      if (c0 < 144) {
        float4 u = *(const float4*)(wrow + c0);
        float4 v = *(const float4*)(wrow + c0 + 4);
        f[0] = (short)f2bf(u.x); f[1] = (short)f2bf(u.y);
        f[2] = (short)f2bf(u.z); f[3] = (short)f2bf(u.w);
        f[4] = (short)f2bf(v.x); f[5] = (short)f2bf(v.y);
        f[6] = (short)f2bf(v.z); f[7] = (short)f2bf(v.w);
      } else {
#pragma unroll
        for (int j = 0; j < 8; ++j) f[j] = 0;
      }
      Bf[nt][ks] = f;
    }
  }

  float ss[5], sq[5];
#pragma unroll
  for (int i = 0; i < 5; ++i) { ss[i] = 0.f; sq[i] = 0.f; }

#pragma unroll 1
  for (int t = 0; t < 4; ++t) {
    int tile = blockIdx.x * 16 + w * 4 + t;
    int item = tile * 16 + m;
    int bn = item / 20;
    int b = bn >> 12;
    int nb = idxb[item];
    const float* fme = feat + (size_t)bn * CFEAT;
    const float* fnb = feat + ((size_t)b * NN + nb) * CFEAT;
    float4 pm = xyz4[bn];
    float4 pn = xyz4[(size_t)b * NN + nb];
    float rx = pn.x - pm.x, ry = pn.y - pm.y, rz = pn.z - pm.z;

    f32x4 acc[7];
#pragma unroll
    for (int nt = 0; nt < 7; ++nt)
#pragma unroll
      for (int r = 0; r < 4; ++r) acc[nt][r] = 0.f;

#pragma unroll
    for (int ks = 0; ks < 5; ++ks) {
      int c0 = ks * 32 + quad * 8;
      bf16x8 A;
      if (c0 < 64) {
        float4 a0 = *(const float4*)(fnb + c0);
        float4 a1 = *(const float4*)(fnb + c0 + 4);
        float4 m0 = *(const float4*)(fme + c0);
        float4 m1 = *(const float4*)(fme + c0 + 4);
        A[0] = (short)f2bf(a0.x - m0.x); A[1] = (short)f2bf(a0.y - m0.y);
        A[2] = (short)f2bf(a0.z - m0.z); A[3] = (short)f2bf(a0.w - m0.w);
        A[4] = (short)f2bf(a1.x - m1.x); A[5] = (short)f2bf(a1.y - m1.y);
        A[6] = (short)f2bf(a1.z - m1.z); A[7] = (short)f2bf(a1.w - m1.w);
      } else if (c0 < 128) {
        int c = c0 - 64;
        float4 m0 = *(const float4*)(fme + c);
        float4 m1 = *(const float4*)(fme + c + 4);
        A[0] = (short)f2bf(m0.x); A[1] = (short)f2bf(m0.y);
        A[2] = (short)f2bf(m0.z); A[3] = (short)f2bf(m0.w);
        A[4] = (short)f2bf(m1.x); A[5] = (short)f2bf(m1.y);
        A[6] = (short)f2bf(m1.z); A[7] = (short)f2bf(m1.w);
      } else if (c0 < 144) {
        int v0 = c0 - 128;
#pragma unroll
        for (int j = 0; j < 8; ++j) {
          float pv = fmaf(Wh[(v0 + j) * 3], rx,
                     fmaf(Wh[(v0 + j) * 3 + 1], ry, Wh[(v0 + j) * 3 + 2] * rz));
          A[j] = (short)f2bf(pv);
        }
      } else {
#pragma unroll
        for (int j = 0; j < 8; ++j) A[j] = 0;
      }
#pragma unroll
      for (int nt = 0; nt < 7; ++nt)
        acc[nt] = __builtin_amdgcn_mfma_f32_16x16x32_bf16(A, Bf[nt][ks], acc[nt], 0, 0, 0);
    }

    // stats (t1: nt 0-3, tv: nt 4); each reg = one item's value
#pragma unroll
    for (int nt = 0; nt < 5; ++nt)
#pragma unroll
      for (int r = 0; r < 4; ++r) {
        float v = acc[nt][r];
        ss[nt] += v; sq[nt] += v * v;
      }

    // C layout: row(item)=quad*4+r, col(ch)=m  -> LDS transpose to item-major
#pragma unroll
    for (int nt = 0; nt < 7; ++nt)
#pragma unroll
      for (int r = 0; r < 4; ++r)
        lds[w][quad * 4 + r][nt * 16 + m] = f2bf(acc[nt][r]);
    __syncthreads();

    // coalesced stores
    {
      int it = lane >> 2, sg = lane & 3;
      const uint4* sp = (const uint4*)&lds[w][it][sg * 16];
      uint4 d0 = sp[0], d1 = sp[1];
      *(uint4*)(t1g + (size_t)tile * 1024 + lane * 16) = d0;
      *(uint4*)(t1g + (size_t)tile * 1024 + lane * 16 + 8) = d1;
      const uint4* spk = (const uint4*)&lds[w][it][80 + sg * 8];
      *(uint4*)(akg + (size_t)tile * 512 + lane * 8) = spk[0];
      if (lane < 32) {
        const uint4* spv = (const uint4*)&lds[w][lane >> 1][64 + (lane & 1) * 8];
        *(uint4*)(tvg + (size_t)tile * 256 + lane * 8) = spv[0];
      }
    }
    __syncthreads();
  }

  // reduce stats across quads (lanes n, n+16, n+32, n+48 share channel n)
  float* slot = st1 + (blockIdx.x & 63) * 160;
#pragma unroll
  for (int nt = 0; nt < 5; ++nt) {
    float s = ss[nt];
    s += __shfl_xor(s, 16); s += __shfl_xor(s, 32);
    float q = sq[nt];
    q += __shfl_xor(q, 16); q += __shfl_xor(q, 32);
    if (lane < 16) {
      if (nt < 4) {
        atomicAdd(&slot[nt * 16 + lane], s);
        atomicAdd(&slot[64 + nt * 16 + lane], q);
      } else {
        atomicAdd(&slot[128 + lane], s);
        atomicAdd(&slot[144 + lane], q);
      }
    }
  }
}

// GEMM2: t2 = W2 @ relu(bn1(t1)), M=ITEMS, K=64, N=64. One wave = 80 items =
// 4 whole bn groups (5 tiles). Outputs: BN2 stats + per-bn max/min of raw t2.
__global__ void __launch_bounds__(256) k_g2(
    const ushort_t* __restrict__ t1g, const float* __restrict__ W2,
    const float* __restrict__ par, float* __restrict__ st2,
    float* __restrict__ fqpre)
{
  __shared__ ushort_t lds[4][80][68];
  int tid = threadIdx.x;
  int w = tid >> 6, lane = tid & 63;
  int m = lane & 15, quad = lane >> 4;
  int gw = blockIdx.x * 4 + w;          // 0..8191, owns bns [gw*4, gw*4+4)

  bf16x8 Bf[4][2];
#pragma unroll
  for (int nt = 0; nt < 4; ++nt) {
    const float* wrow = W2 + (nt * 16 + m) * CHN;
#pragma unroll
    for (int ks = 0; ks < 2; ++ks) {
      int c0 = ks * 32 + quad * 8;
      float4 u = *(const float4*)(wrow + c0);
      float4 v = *(const float4*)(wrow + c0 + 4);
      bf16x8 f;
      f[0] = (short)f2bf(u.x); f[1] = (short)f2bf(u.y);
      f[2] = (short)f2bf(u.z); f[3] = (short)f2bf(u.w);
      f[4] = (short)f2bf(v.x); f[5] = (short)f2bf(v.y);
      f[6] = (short)f2bf(v.z); f[7] = (short)f2bf(v.w);
      Bf[nt][ks] = f;
    }
  }
  // bn1 params for this lane's channels
  float pa[2][8], pb[2][8];
#pragma unroll
  for (int ks = 0; ks < 2; ++ks) {
    int c0 = ks * 32 + quad * 8;
    float4 a0 = *(const float4*)(par + c0);
    float4 a1 = *(const float4*)(par + c0 + 4);
    float4 b0 = *(const float4*)(par + 64 + c0);
    float4 b1 = *(const float4*)(par + 64 + c0 + 4);
    pa[ks][0] = a0.x; pa[ks][1] = a0.y; pa[ks][2] = a0.z; pa[ks][3] = a0.w;
    pa[ks][4] = a1.x; pa[ks][5] = a1.y; pa[ks][6] = a1.z; pa[ks][7] = a1.w;
    pb[ks][0] = b0.x; pb[ks][1] = b0.y; pb[ks][2] = b0.z; pb[ks][3] = b0.w;
    pb[ks][4] = b1.x; pb[ks][5] = b1.y; pb[ks][6] = b1.z; pb[ks][7] = b1.w;
  }

  float ss[4] = {0.f, 0.f, 0.f, 0.f}, sq[4] = {0.f, 0.f, 0.f, 0.f};

#pragma unroll 1
  for (int t5 = 0; t5 < 5; ++t5) {
    int tile = gw * 5 + t5;
    int item = tile * 16 + m;
    f32x4 acc[4];
#pragma unroll
    for (int nt = 0; nt < 4; ++nt)
#pragma unroll
      for (int r = 0; r < 4; ++r) acc[nt][r] = 0.f;
#pragma unroll
    for (int ks = 0; ks < 2; ++ks) {
      const ushort_t* tp = t1g + (size_t)item * 64 + ks * 32 + quad * 8;
      uint4 raw = *(const uint4*)tp;
      unsigned rw[4] = {raw.x, raw.y, raw.z, raw.w};
      bf16x8 A;
#pragma unroll
      for (int i = 0; i < 4; ++i) {
        float lo = bf2f((ushort_t)(rw[i] & 0xffffu));
        float hi = bf2f((ushort_t)(rw[i] >> 16));
        float h0 = fmaxf(fmaf(lo, pa[ks][2 * i], pb[ks][2 * i]), 0.f);
        float h1 = fmaxf(fmaf(hi, pa[ks][2 * i + 1], pb[ks][2 * i + 1]), 0.f);
        A[2 * i] = (short)f2bf(h0);
        A[2 * i + 1] = (short)f2bf(h1);
      }
#pragma unroll
      for (int nt = 0; nt < 4; ++nt)
        acc[nt] = __builtin_amdgcn_mfma_f32_16x16x32_bf16(A, Bf[nt][ks], acc[nt], 0, 0, 0);
    }
#pragma unroll
    for (int nt = 0; nt < 4; ++nt)
#pragma unroll
      for (int r = 0; r < 4; ++r) {
        float v = acc[nt][r];
        ss[nt] += v; sq[nt] += v * v;
        lds[w][t5 * 16 + quad * 4 + r][nt * 16 + m] = f2bf(v);
      }
  }
  __syncthreads();

  // fq: per-bn max/min of raw t2 over the 20 k-items (wave owns whole bns)
  {
    int bnl = lane >> 4;                // 0..3
    int chb = (lane & 15) * 4;          // 4 channels per lane
    float mx0 = -3.4e38f, mx1 = -3.4e38f, mx2 = -3.4e38f, mx3 = -3.4e38f;
    float mn0 = 3.4e38f, mn1 = 3.4e38f, mn2 = 3.4e38f, mn3 = 3.4e38f;
#pragma unroll
    for (int j = 0; j < KK; ++j) {
      const uint2 rv = *(const uint2*)&lds[w][bnl * 20 + j][chb];
      float v0 = bf2f((ushort_t)(rv.x & 0xffffu));
      float v1 = bf2f((ushort_t)(rv.x >> 16));
      float v2 = bf2f((ushort_t)(rv.y & 0xffffu));
      float v3 = bf2f((ushort_t)(rv.y >> 16));
      mx0 = fmaxf(mx0, v0); mn0 = fminf(mn0, v0);
      mx1 = fmaxf(mx1, v1); mn1 = fminf(mn1, v1);
      mx2 = fmaxf(mx2, v2); mn2 = fminf(mn2, v2);
      mx3 = fmaxf(mx3, v3); mn3 = fminf(mn3, v3);
    }
    int bn = gw * 4 + bnl;
    *(float4*)(fqpre + (size_t)bn * 128 + chb) = make_float4(mx0, mx1, mx2, mx3);
    *(float4*)(fqpre + (size_t)bn * 128 + 64 + chb) = make_float4(mn0, mn1, mn2, mn3);
  }

  float* slot = st2 + (blockIdx.x & 63) * 128;
#pragma unroll
  for (int nt = 0; nt < 4; ++nt) {
    float s = ss[nt];
    s += __shfl_xor(s, 16); s += __shfl_xor(s, 32);
    float q = sq[nt];
    q += __shfl_xor(q, 16); q += __shfl_xor(q, 32);
    if (lane < 16) {
      atomicAdd(&slot[nt * 16 + lane], s);
      atomicAdd(&slot[64 + nt * 16 + lane], q);
    }
  }
}

// softmax over k + kv from cached ak/tv
#define P3P 16
__global__ void __launch_bounds__(320, 2) k_p3s(
    const ushort_t* __restrict__ akg, const ushort_t* __restrict__ tvg,
    const float* __restrict__ par, __hip_bfloat16* __restrict__ kvg)
{
  __shared__ float sl[P3P][KK][DKK + 1];
  __shared__ float sv[P3P][KK][DVV + 1];
  __shared__ float sm[P3P][DKK], ssi[P3P][DKK];
  int tid = threadIdx.x;
  int p = tid / KK, k = tid - p * KK;
  size_t item = (size_t)(blockIdx.x * P3P + p) * KK + k;
  const unsigned* ap = (const unsigned*)(akg + item * DKK);
#pragma unroll
  for (int i = 0; i < DKK / 2; ++i) {
    unsigned wv = ap[i];
    sl[p][k][2 * i]     = __uint_as_float(wv << 16);
    sl[p][k][2 * i + 1] = __uint_as_float(wv & 0xffff0000u);
  }
  const unsigned* vp = (const unsigned*)(tvg + item * DVV);
#pragma unroll
  for (int i = 0; i < DVV / 2; ++i) {
    unsigned wv = vp[i];
    float lo = __uint_as_float(wv << 16);
    float hi = __uint_as_float(wv & 0xffff0000u);
    sv[p][k][2 * i]     = fmaf(lo, par[128 + 2 * i],     par[144 + 2 * i]);
    sv[p][k][2 * i + 1] = fmaf(hi, par[128 + 2 * i + 1], par[144 + 2 * i + 1]);
  }
  __syncthreads();
  for (int pd = tid; pd < P3P * DKK; pd += 320) {
    int pp = pd >> 5, d = pd & 31;
    float m = -1e30f;
#pragma unroll
    for (int q = 0; q < KK; ++q) m = fmaxf(m, sl[pp][q][d]);
    float S = 0.f;
#pragma unroll
    for (int q = 0; q < KK; ++q) S += __expf(sl[pp][q][d] - m);
    sm[pp][d] = m; ssi[pp][d] = 1.f / S;
  }
  __syncthreads();
  for (int pd = tid; pd < P3P * DKK; pd += 320) {
    int pp = pd >> 5, d = pd & 31;
    float m = sm[pp][d], Si = ssi[pp][d];
    float a[DVV];
#pragma unroll
    for (int v = 0; v < DVV; ++v) a[v] = 0.f;
#pragma unroll
    for (int q = 0; q < KK; ++q) {
      float wgt = __expf(sl[pp][q][d] - m) * Si;
#pragma unroll
      for (int v = 0; v < DVV; ++v) a[v] = fmaf(wgt, sv[pp][q][v], a[v]);
    }
    __hip_bfloat162* dst = (__hip_bfloat162*)
        (kvg + ((size_t)(blockIdx.x * P3P + pp) * DKK + d) * DVV);
#pragma unroll
    for (int v = 0; v < DVV; v += 2) {
      float2 f2; f2.x = a[v]; f2.y = a[v + 1];
      dst[v >> 1] = __float22bfloat162_rn(f2);
    }
  }
}

// fq from fqpre (sign-aware, exact under monotone bn+relu) -> q2 = Wq@fq + stats
__global__ void __launch_bounds__(128, 2) k_pq(const float* __restrict__ fqpre,
                                               const float* __restrict__ Wq,
                                               const float* __restrict__ par,
                                               float* __restrict__ stq,
                                               float* __restrict__ q2g)
{
  int bn = blockIdx.x * 128 + threadIdx.x;
  float fq[CHN];
  const float4* fp = (const float4*)(fqpre + (size_t)bn * 128);
#pragma unroll
  for (int c4 = 0; c4 < 16; ++c4) {
    float4 mx = fp[c4], mn = fp[16 + c4];
#pragma unroll
    for (int j = 0; j < 4; ++j) {
      int c = c4 * 4 + j;
      float a = par[160 + c], b = par[224 + c];
      float pick = (j == 0) ? (a >= 0.f ? mx.x : mn.x)
                 : (j == 1) ? (a >= 0.f ? mx.y : mn.y)
                 : (j == 2) ? (a >= 0.f ? mx.z : mn.z)
                            : (a >= 0.f ? mx.w : mn.w);
      fq[c] = fmaxf(fmaf(a, pick, b), 0.f);
    }
  }
  float* slot = stq + (blockIdx.x & 63) * 512;
  int lane = threadIdx.x & 63;
#pragma unroll 1
  for (int o = 0; o < NQC; ++o) {
    const float* w = Wq + o * CHN;
    float a0 = 0.f, a1 = 0.f, a2 = 0.f, a3 = 0.f;
#pragma unroll
    for (int c = 0; c < CHN; c += 4) {
      a0 = fmaf(w[c], fq[c], a0); a1 = fmaf(w[c + 1], fq[c + 1], a1);
      a2 = fmaf(w[c + 2], fq[c + 2], a2); a3 = fmaf(w[c + 3], fq[c + 3], a3);
    }
    float v = (a0 + a1) + (a2 + a3);
    q2g[(size_t)bn * NQC + o] = v;
    float s = wred(v), s2 = wred(v * v);
    if (lane == 0) { atomicAdd(&slot[o], s); atomicAdd(&slot[256 + o], s2); }
  }
}

__global__ void k_redq(const float* __restrict__ stq, const float* __restrict__ gq,
                       const float* __restrict__ bq, float* __restrict__ par)
{
  int o = threadIdx.x; // 256
  float s = 0.f, s2 = 0.f;
  for (int j = 0; j < 64; ++j) { s += stq[j * 512 + o]; s2 += stq[j * 512 + 256 + o]; }
  const float inv = 1.f / (float)BNTOT;
  float mu = s * inv, var = s2 * inv - mu * mu;
  float a = gq[o] * rsqrtf(var + EPSV);
  par[288 + o] = a; par[544 + o] = bq[o] - mu * a;
}

__global__ void __launch_bounds__(64) k_p4(const float* __restrict__ q2g,
                                           const __hip_bfloat16* __restrict__ kvg,
                                           const float* __restrict__ par,
                                           float* __restrict__ outp)
{
  __shared__ float sq2[NQC], skv[DKK * DVV];
  int t = threadIdx.x;
  int b = blockIdx.x & 7, n = blockIdx.x >> 3;
  int bn = (b << 12) | n;
#pragma unroll
  for (int j = 0; j < 8; ++j)
    skv[t + 64 * j] = __bfloat162float(kvg[(size_t)bn * 512 + t + 64 * j]);
#pragma unroll
  for (int j = 0; j < 4; ++j) {
    int o = t + 64 * j;
    float v = q2g[(size_t)bn * NQC + o];
    sq2[o] = fmaxf(fmaf(v, par[288 + o], par[544 + o]), 0.f);
  }
  __syncthreads();
#pragma unroll
  for (int j = 0; j < 2; ++j) {
    int ch = t + 64 * j, h = ch >> 4, vv = ch & 15;
    float a = 0.f;
#pragma unroll
    for (int d = 0; d < DKK; ++d) a = fmaf(sq2[h * DKK + d], skv[d * DVV + vv], a);
    outp[(size_t)BNTOT * 3 + ((size_t)(b * 128 + ch)) * NN + n] = a;
  }
}

// ---------- FALLBACK (round-5 proven path) ----------

__global__ void __launch_bounds__(256, 3) k_s1f(
    const float4* __restrict__ xyz4, const float* __restrict__ feat,
    const int* __restrict__ idxb, const float* __restrict__ W1,
    const float* __restrict__ Wv, const float* __restrict__ Wh,
    float* __restrict__ st1,
    __hip_bfloat16* __restrict__ t1g, __hip_bfloat16* __restrict__ tvg)
{
  int t = blockIdx.x * 256 + threadIdx.x;
  int bn = t / KK, k = t - bn * KK, b = bn >> 12;
  int nb = idxb[(size_t)bn * KK + k];
  const float* fme = feat + (size_t)bn * CFEAT;
  const float* fnb = feat + ((size_t)b * NN + nb) * CFEAT;
  float4 pn = xyz4[(size_t)b * NN + nb];
  float4 pm = xyz4[bn];
  float rx = pn.x - pm.x, ry = pn.y - pm.y, rz = pn.z - pm.z;
  float a1[CHN], av[DVV];
#pragma unroll
  for (int o = 0; o < CHN; ++o) a1[o] = 0.f;
#pragma unroll
  for (int o = 0; o < DVV; ++o) av[o] = 0.f;
#pragma unroll 1
  for (int ch = 0; ch < 9; ++ch) {
    float fc[16];
    build_chunk(ch, fme, fnb, rx, ry, rz, Wh, fc);
    accum_chunk<CHN>(W1, ch, fc, a1);
    accum_chunk<DVV>(Wv, ch, fc, av);
  }
  __hip_bfloat162* t1p = (__hip_bfloat162*)(t1g + (size_t)t * CHN);
#pragma unroll
  for (int o = 0; o < CHN; o += 2) {
    float2 f2; f2.x = a1[o]; f2.y = a1[o + 1];
    t1p[o >> 1] = __float22bfloat162_rn(f2);
  }
  __hip_bfloat162* tvp = (__hip_bfloat162*)(tvg + (size_t)t * DVV);
#pragma unroll
  for (int o = 0; o < DVV; o += 2) {
    float2 f2; f2.x = av[o]; f2.y = av[o + 1];
    tvp[o >> 1] = __float22bfloat162_rn(f2);
  }
  float* slot = st1 + (blockIdx.x & 63) * 160;
  int lane = threadIdx.x & 63;
#pragma unroll
  for (int o = 0; o < CHN; ++o) {
    float s = wred(a1[o]), s2 = wred(a1[o] * a1[o]);
    if (lane == 0) { atomicAdd(&slot[o], s); atomicAdd(&slot[CHN + o], s2); }
  }
#pragma unroll
  for (int o = 0; o < DVV; ++o) {
    float s = wred(av[o]), s2 = wred(av[o] * av[o]);
    if (lane == 0) { atomicAdd(&slot[128 + o], s); atomicAdd(&slot[128 + DVV + o], s2); }
  }
}

__global__ void __launch_bounds__(256, 4) k_skf(
    const float4* __restrict__ xyz4, const float* __restrict__ feat,
    const int* __restrict__ idxb, const float* __restrict__ Wk,
    const float* __restrict__ Wh, __hip_bfloat16* __restrict__ akg)
{
  int t = blockIdx.x * 256 + threadIdx.x;
  int bn = t / KK, k = t - bn * KK, b = bn >> 12;
  int nb = idxb[(size_t)bn * KK + k];
  const float* fme = feat + (size_t)bn * CFEAT;
  const float* fnb = feat + ((size_t)b * NN + nb) * CFEAT;
  float4 pn = xyz4[(size_t)b * NN + nb];
  float4 pm = xyz4[bn];
  float rx = pn.x - pm.x, ry = pn.y - pm.y, rz = pn.z - pm.z;
  float ak[DKK];
#pragma unroll
  for (int o = 0; o < DKK; ++o) ak[o] = 0.f;
#pragma unroll 1
  for (int ch = 0; ch < 9; ++ch) {
    float fc[16];
    build_chunk(ch, fme, fnb, rx, ry, rz, Wh, fc);
    accum_chunk<DKK>(Wk, ch, fc, ak);
  }
  __hip_bfloat162* akp = (__hip_bfloat162*)(akg + (size_t)t * DKK);
#pragma unroll
  for (int o = 0; o < DKK; o += 2) {
    float2 f2; f2.x = ak[o]; f2.y = ak[o + 1];
    akp[o >> 1] = __float22bfloat162_rn(f2);
  }
}

__global__ void __launch_bounds__(256, 4) k_s2f(
    const __hip_bfloat16* __restrict__ t1g, const float* __restrict__ W2,
    const float* __restrict__ par, float* __restrict__ st2)
{
  int t = blockIdx.x * 256 + threadIdx.x;
  const unsigned* tp = (const unsigned*)(t1g + (size_t)t * CHN);
  float h1[CHN];
#pragma unroll
  for (int i = 0; i < CHN / 2; ++i) {
    unsigned w = tp[i];
    float lo = __uint_as_float(w << 16);
    float hi = __uint_as_float(w & 0xffff0000u);
    h1[2 * i]     = fmaxf(fmaf(lo, par[2 * i],     par[64 + 2 * i]),     0.f);
    h1[2 * i + 1] = fmaxf(fmaf(hi, par[2 * i + 1], par[64 + 2 * i + 1]), 0.f);
  }
  float* slot = st2 + (blockIdx.x & 63) * 128;
  int lane = threadIdx.x & 63;
#pragma unroll 1
  for (int o = 0; o < CHN; ++o) {
    const float* w = W2 + o * CHN;
    float c0 = 0.f, c1 = 0.f, c2 = 0.f, c3 = 0.f;
#pragma unroll
    for (int c = 0; c < CHN; c += 4) {
      c0 = fmaf(w[c + 0], h1[c + 0], c0); c1 = fmaf(w[c + 1], h1[c + 1], c1);
      c2 = fmaf(w[c + 2], h1[c + 2], c2); c3 = fmaf(w[c + 3], h1[c + 3], c3);
    }
    float v = (c0 + c1) + (c2 + c3);
    float s = wred(v), s2 = wred(v * v);
    if (lane == 0) { atomicAdd(&slot[o], s); atomicAdd(&slot[64 + o], s2); }
  }
}

__global__ void __launch_bounds__(320, 2) k_p3f(
    const __hip_bfloat16* __restrict__ t1g, const __hip_bfloat16* __restrict__ akg,
    const __hip_bfloat16* __restrict__ tvg, const float* __restrict__ W2,
    const float* __restrict__ par, float* __restrict__ fqg,
    __hip_bfloat16* __restrict__ kvg)
{
  __shared__ float sl[P3P][KK][DKK + 1];
  __shared__ float sv[P3P][KK][DVV + 1];
  __shared__ unsigned sfq[P3P][CHN];
  __shared__ float sm[P3P][DKK], ssi[P3P][DKK];
  int tid = threadIdx.x;
  for (int i = tid; i < P3P * CHN; i += 320) ((unsigned*)sfq)[i] = 0u;
  __syncthreads();
  int p = tid / KK, k = tid - p * KK;
  size_t item = (size_t)(blockIdx.x * P3P + p) * KK + k;
  const unsigned* ap = (const unsigned*)(akg + item * DKK);
#pragma unroll
  for (int i = 0; i < DKK / 2; ++i) {
    unsigned w = ap[i];
    sl[p][k][2 * i]     = __uint_as_float(w << 16);
    sl[p][k][2 * i + 1] = __uint_as_float(w & 0xffff0000u);
  }
  const unsigned* vp = (const unsigned*)(tvg + item * DVV);
#pragma unroll
  for (int i = 0; i < DVV / 2; ++i) {
    unsigned w = vp[i];
    float lo = __uint_as_float(w << 16);
    float hi = __uint_as_float(w & 0xffff0000u);
    sv[p][k][2 * i]     = fmaf(lo, par[128 + 2 * i],     par[144 + 2 * i]);
    sv[p][k][2 * i + 1] = fmaf(hi, par[128 + 2 * i + 1], par[144 + 2 * i + 1]);
  }
  const unsigned* tp = (const unsigned*)(t1g + item * CHN);
  float h1[CHN];
#pragma unroll
  for (int i = 0; i < CHN / 2; ++i) {
    unsigned w = tp[i];
    float lo = __uint_as_float(w << 16);
    float hi = __uint_as_float(w & 0xffff0000u);
    h1[2 * i]     = fmaxf(fmaf(lo, par[2 * i],     par[64 + 2 * i]),     0.f);
    h1[2 * i + 1] = fmaxf(fmaf(hi, par[2 * i + 1], par[64 + 2 * i + 1]), 0.f);
  }
#pragma unroll 1
  for (int o = 0; o < CHN; ++o) {
    const float* w = W2 + o * CHN;
    float c0 = 0.f, c1 = 0.f, c2 = 0.f, c3 = 0.f;
#pragma unroll
    for (int c = 0; c < CHN; c += 4) {
      c0 = fmaf(w[c + 0], h1[c + 0], c0); c1 = fmaf(w[c + 1], h1[c + 1], c1);
      c2 = fmaf(w[c + 2], h1[c + 2], c2); c3 = fmaf(w[c + 3], h1[c + 3], c3);
    }
    float v = (c0 + c1) + (c2 + c3);
    float h2 = fmaxf(fmaf(v, par[160 + o], par[224 + o]), 0.f);
    atomicMax(&sfq[p][o], __float_as_uint(h2));
  }
  __syncthreads();
  for (int i = tid; i < P3P * CHN; i += 320)
    fqg[(size_t)blockIdx.x * (P3P * CHN) + i] = __uint_as_float(sfq[i >> 6][i & 63]);
  for (int pd = tid; pd < P3P * DKK; pd += 320) {
    int pp = pd >> 5, d = pd & 31;
    float m = -1e30f;
#pragma unroll
    for (int q = 0; q < KK; ++q) m = fmaxf(m, sl[pp][q][d]);
    float S = 0.f;
#pragma unroll
    for (int q = 0; q < KK; ++q) S += __expf(sl[pp][q][d] - m);
    sm[pp][d] = m; ssi[pp][d] = 1.f / S;
  }
  __syncthreads();
  for (int pd = tid; pd < P3P * DKK; pd += 320) {
    int pp = pd >> 5, d = pd & 31;
    float m = sm[pp][d], Si = ssi[pp][d];
    float a[DVV];
#pragma unroll
    for (int v = 0; v < DVV; ++v) a[v] = 0.f;
#pragma unroll
    for (int q = 0; q < KK; ++q) {
      float wgt = __expf(sl[pp][q][d] - m) * Si;
#pragma unroll
      for (int v = 0; v < DVV; ++v) a[v] = fmaf(wgt, sv[pp][q][v], a[v]);
    }
    __hip_bfloat162* dst = (__hip_bfloat162*)
        (kvg + ((size_t)(blockIdx.x * P3P + pp) * DKK + d) * DVV);
#pragma unroll
    for (int v = 0; v < DVV; v += 2) {
      float2 f2; f2.x = a[v]; f2.y = a[v + 1];
      dst[v >> 1] = __float22bfloat162_rn(f2);
    }
  }
}

__global__ void __launch_bounds__(128, 2) k_pqf(const float* __restrict__ fqg,
                                                const float* __restrict__ Wq,
                                                float* __restrict__ stq,
                                                float* __restrict__ q2g)
{
  int bn = blockIdx.x * 128 + threadIdx.x;
  float fq[CHN];
#pragma unroll
  for (int c = 0; c < CHN; c += 4) {
    float4 v4 = *(const float4*)(fqg + (size_t)bn * CHN + c);
    fq[c] = v4.x; fq[c + 1] = v4.y; fq[c + 2] = v4.z; fq[c + 3] = v4.w;
  }
  float* slot = stq + (blockIdx.x & 63) * 512;
  int lane = threadIdx.x & 63;
#pragma unroll 1
  for (int o = 0; o < NQC; ++o) {
    const float* w = Wq + o * CHN;
    float a0 = 0.f, a1 = 0.f, a2 = 0.f, a3 = 0.f;
#pragma unroll
    for (int c = 0; c < CHN; c += 4) {
      a0 = fmaf(w[c], fq[c], a0); a1 = fmaf(w[c + 1], fq[c + 1], a1);
      a2 = fmaf(w[c + 2], fq[c + 2], a2); a3 = fmaf(w[c + 3], fq[c + 3], a3);
    }
    float v = (a0 + a1) + (a2 + a3);
    q2g[(size_t)bn * NQC + o] = v;
    float s = wred(v), s2 = wred(v * v);
    if (lane == 0) { atomicAdd(&slot[o], s); atomicAdd(&slot[256 + o], s2); }
  }
}

// ---------- launch ----------

extern "C" void kernel_launch(void* const* d_in, const int* in_sizes, int n_in,
                              void* d_out, int out_size, void* d_ws, size_t ws_size,
                              hipStream_t stream)
{
  const float* x  = (const float*)d_in[0];
  const float* W1 = (const float*)d_in[1];
  const float* g1 = (const float*)d_in[2];
  const float* b1 = (const float*)d_in[3];
  const float* W2 = (const float*)d_in[4];
  const float* g2 = (const float*)d_in[5];
  const float* b2 = (const float*)d_in[6];
  const float* Wv = (const float*)d_in[7];
  const float* gv = (const float*)d_in[8];
  const float* bv = (const float*)d_in[9];
  const float* Wk = (const float*)d_in[10];
  const float* Wq = (const float*)d_in[11];
  const float* gq = (const float*)d_in[12];
  const float* bq = (const float*)d_in[13];
  const float* Wh = (const float*)d_in[14];

  float* ws = (float*)d_ws;
  float4* xyz4 = (float4*)ws;                      // 131072
  float*  feat = ws + 131072;                      // 2097152
  int*    idxb = (int*)(ws + 2228224);             // 655360
  float*  st1  = ws + 2883584;                     // 10240
  float*  st2  = ws + 2893824;                     // 8192
  float*  stq  = ws + 2902016;                     // 32768
  float*  par  = ws + 2934784;                     // 800
  float*  fqg  = ws + 2935584;                     // 2097152
  __hip_bfloat16* kvg = (__hip_bfloat16*)(ws + 5032736);  // 8388608 fw
  float*  outp = (float*)d_out;

  ushort_t* t1g = (ushort_t*)(ws + 13421344);      // 20971520 fw
  ushort_t* akg = (ushort_t*)(ws + 34392864);      // 10485760 fw
  ushort_t* tvg = (ushort_t*)(ws + 44878624);      //  5242880 fw
  float*    fqpre = ws + 50121504;                 //  4194304 fw
  float*    q2g = ws + 13421344;                   // alias t1g (dead after k_g2)

  const size_t FAST_NEED = (size_t)50121504 * 4;   // ~200.5 MB (round-5 path)
  const size_t NEW_NEED  = (size_t)54315808 * 4;   // ~217.3 MB (MFMA path)

  hipMemsetAsync(st1, 0, (size_t)(10240 + 8192 + 32768) * sizeof(float), stream);
  k_prep<<<128, 256, 0, stream>>>(x, xyz4, feat, outp);
  k_knn <<<512, 512, 0, stream>>>(xyz4, idxb);

  if (ws_size >= NEW_NEED) {
    k_g1  <<<2560, 256, 0, stream>>>(xyz4, feat, idxb, W1, Wv, Wk, Wh, st1, t1g, akg, tvg);
    k_red1<<<1, 128, 0, stream>>>(st1, g1, b1, gv, bv, par);
    k_g2  <<<2048, 256, 0, stream>>>(t1g, W2, par, st2, fqpre);
    k_red2<<<1, 64, 0, stream>>>(st2, g2, b2, par);
    k_p3s <<<2048, 320, 0, stream>>>(akg, tvg, par, kvg);
    k_pq  <<<256, 128, 0, stream>>>(fqpre, Wq, par, stq, q2g);
    k_redq<<<1, 256, 0, stream>>>(stq, gq, bq, par);
    k_p4  <<<32768, 64, 0, stream>>>(q2g, kvg, par, outp);
  } else {
    __hip_bfloat16* t1b = (__hip_bfloat16*)t1g;
    __hip_bfloat16* akb = (__hip_bfloat16*)akg;
    __hip_bfloat16* tvb = (__hip_bfloat16*)tvg;
    float* q2f = ws + 34392864;                    // alias akg region
    k_s1f <<<2560, 256, 0, stream>>>(xyz4, feat, idxb, W1, Wv, Wh, st1, t1b, tvb);
    k_skf <<<2560, 256, 0, stream>>>(xyz4, feat, idxb, Wk, Wh, akb);
    k_red1<<<1, 128, 0, stream>>>(st1, g1, b1, gv, bv, par);
    k_s2f <<<2560, 256, 0, stream>>>(t1b, W2, par, st2);
    k_red2<<<1, 64, 0, stream>>>(st2, g2, b2, par);
    k_p3f <<<2048, 320, 0, stream>>>(t1b, akb, tvb, W2, par, fqg, kvg);
    k_pqf <<<256, 128, 0, stream>>>(fqg, Wq, stq, q2f);
    k_redq<<<1, 256, 0, stream>>>(stq, gq, bq, par);
    k_p4  <<<32768, 64, 0, stream>>>(q2f, kvg, par, outp);
  }
}

// Round 7
// 615.310 us; speedup vs baseline: 9.0261x; 1.4970x over previous
//
#include <hip/hip_runtime.h>
#include <hip/hip_bf16.h>

#define NB 8
#define NN 4096
#define KK 20
#define CFEAT 64
#define CCAT 144
#define CHN 64
#define NHEAD 8
#define DKK 32
#define DVV 16
#define NQC 256
#define EPSV 1e-5f
#define BNTOT (NB*NN)      /* 32768 */
#define ITEMS (BNTOT*KK)   /* 655360 */

typedef unsigned short ushort_t;
typedef __attribute__((ext_vector_type(8))) short bf16x8;
typedef __attribute__((ext_vector_type(4))) float f32x4;

// ---------- helpers ----------

__device__ __forceinline__ float wred(float v) {
#pragma unroll
  for (int off = 32; off > 0; off >>= 1) v += __shfl_down(v, off);
  return v;
}

__device__ __forceinline__ ushort_t f2bf(float f) {
  unsigned u = __float_as_uint(f);
  return (ushort_t)((u + 0x7fffu + ((u >> 16) & 1u)) >> 16);
}
__device__ __forceinline__ float bf2f(ushort_t h) {
  return __uint_as_float(((unsigned)h) << 16);
}

// identical in phase1/phase2 so d is bit-identical
__device__ __forceinline__ float pdist(float4 me, float4 p) {
  float dot = fmaf(me.x, p.x, fmaf(me.y, p.y, me.z * p.z));
  return fmaf(-2.f, dot, me.w + p.w);
}

// build 16 channels of fcat (fallback path)
__device__ __forceinline__ void build_chunk(int ch,
    const float* __restrict__ fme, const float* __restrict__ fnb,
    float rx, float ry, float rz, const float* __restrict__ Wh, float* fc)
{
  if (ch < 4) {
    int c0 = ch * 16;
#pragma unroll
    for (int j = 0; j < 16; j += 4) {
      float4 a = *(const float4*)(fnb + c0 + j);
      float4 m = *(const float4*)(fme + c0 + j);
      fc[j + 0] = a.x - m.x; fc[j + 1] = a.y - m.y;
      fc[j + 2] = a.z - m.z; fc[j + 3] = a.w - m.w;
    }
  } else if (ch < 8) {
    int c0 = (ch - 4) * 16;
#pragma unroll
    for (int j = 0; j < 16; j += 4) {
      float4 m = *(const float4*)(fme + c0 + j);
      fc[j + 0] = m.x; fc[j + 1] = m.y; fc[j + 2] = m.z; fc[j + 3] = m.w;
    }
  } else {
#pragma unroll
    for (int v = 0; v < 16; ++v)
      fc[v] = fmaf(Wh[v * 3], rx, fmaf(Wh[v * 3 + 1], ry, Wh[v * 3 + 2] * rz));
  }
}

template<int NO>
__device__ __forceinline__ void accum_chunk(const float* __restrict__ W, int ch,
                                            const float* fc, float* acc)
{
  const float* wb = W + ch * 16;
#pragma unroll
  for (int o = 0; o < NO; ++o) {
    const float* w = wb + o * CCAT;
#pragma unroll
    for (int j = 0; j < 16; ++j) acc[o] = fmaf(w[j], fc[j], acc[o]);
  }
}

// ---------- shared kernels ----------

__global__ void __launch_bounds__(256) k_prep(const float* __restrict__ x,
                                              float4* __restrict__ xyz4,
                                              float* __restrict__ feat,
                                              float* __restrict__ outp)
{
  int i = blockIdx.x * 256 + threadIdx.x;
  const float* xr = x + (size_t)i * 67;
  float a = xr[0], b = xr[1], c = xr[2];
  xyz4[i] = make_float4(a, b, c, a * a + b * b + c * c);
  outp[i * 3 + 0] = a; outp[i * 3 + 1] = b; outp[i * 3 + 2] = c;
  float* fd = feat + (size_t)i * CFEAT;
#pragma unroll
  for (int cc = 0; cc < CFEAT; ++cc) fd[cc] = xr[3 + cc];
}

#define KNQ 64
#define KNS 8
__global__ void __launch_bounds__(512) k_knn(const float4* __restrict__ xyz4,
                                             int* __restrict__ idxb)
{
  __shared__ float sbd[KNS][KNQ][21];
  __shared__ float stau[KNQ];
  __shared__ int   scnt[KNQ];
  __shared__ int   stcnt[KNQ];
  __shared__ int   sties[KNQ * 16];
  int t = threadIdx.x;
  int q = t & 63, s = t >> 6;
  int b = blockIdx.x >> 6;
  int n = ((blockIdx.x & 63) << 6) + q;
  const float4* pts = xyz4 + (size_t)b * NN;
  float4 me = pts[n];
  if (t < KNQ) { scnt[t] = 0; stcnt[t] = 0; }
  int m0 = s << 9;
  float bd[KK];
#pragma unroll
  for (int j = 0; j < KK; ++j) bd[j] = 3.4e38f;
#pragma unroll 1
  for (int m = m0; m < m0 + 512; m += 2) {
    float4 p0 = pts[m];
    float4 p1 = pts[m + 1];
    float d0 = pdist(me, p0);
    float d1 = pdist(me, p1);
#pragma unroll
    for (int j = KK - 1; j >= 1; --j)
      bd[j] = __builtin_amdgcn_fmed3f(d0, bd[j - 1], bd[j]);
    bd[0] = fminf(bd[0], d0);
#pragma unroll
    for (int j = KK - 1; j >= 1; --j)
      bd[j] = __builtin_amdgcn_fmed3f(d1, bd[j - 1], bd[j]);
    bd[0] = fminf(bd[0], d1);
  }
#pragma unroll
  for (int j = 0; j < KK; ++j) sbd[s][q][j] = bd[j];
  sbd[s][q][KK] = 3.4e38f;
  __syncthreads();
  if (t < KNQ) {
    int ia[KNS];
#pragma unroll
    for (int ss = 0; ss < KNS; ++ss) ia[ss] = 0;
    float tau = 0.f;
#pragma unroll 1
    for (int r = 0; r < KK; ++r) {
      float best = 3.5e38f; int bs = 0;
#pragma unroll
      for (int ss = 0; ss < KNS; ++ss) {
        float v = sbd[ss][t][ia[ss]];
        if (v < best) { best = v; bs = ss; }
      }
      ia[bs]++;
      tau = best;
    }
    stau[t] = tau;
  }
  __syncthreads();
  float tau = stau[q];
  size_t obase = ((size_t)b * NN + n) * KK;
#pragma unroll 2
  for (int m = m0; m < m0 + 512; ++m) {
    float4 p = pts[m];
    float d = pdist(me, p);
    if (d < tau) {
      int slot = atomicAdd(&scnt[q], 1);
      idxb[obase + slot] = m;
    } else if (d == tau) {
      int ts_ = atomicAdd(&stcnt[q], 1);
      if (ts_ < 16) sties[q * 16 + ts_] = m;
    }
  }
  __syncthreads();
  if (t < KNQ) {
    int c1 = scnt[t];
    int tc = min(stcnt[t], 16);
    int need = KK - c1;
    size_t ob = ((size_t)b * NN + (((blockIdx.x & 63) << 6) + t)) * KK;
    int last = -1;
#pragma unroll 1
    for (int r = 0; r < need; ++r) {
      int best = 0x7fffffff;
      for (int u = 0; u < tc; ++u) {
        int mv = sties[t * 16 + u];
        if (mv > last && mv < best) best = mv;
      }
      if (best == 0x7fffffff) best = 0;
      idxb[ob + c1 + r] = best;
      last = best;
    }
  }
}

__global__ void k_red1(const float* __restrict__ st1, const float* __restrict__ g1,
                       const float* __restrict__ b1, const float* __restrict__ gv,
                       const float* __restrict__ bv, float* __restrict__ par)
{
  int o = threadIdx.x;
  const float inv = 1.f / (float)ITEMS;
  if (o < 64) {
    float s = 0.f, s2 = 0.f;
    for (int j = 0; j < 64; ++j) { s += st1[j * 160 + o]; s2 += st1[j * 160 + 64 + o]; }
    float mu = s * inv, var = s2 * inv - mu * mu;
    float a = g1[o] * rsqrtf(var + EPSV);
    par[o] = a; par[64 + o] = b1[o] - mu * a;
  } else if (o < 80) {
    int v = o - 64;
    float s = 0.f, s2 = 0.f;
    for (int j = 0; j < 64; ++j) { s += st1[j * 160 + 128 + v]; s2 += st1[j * 160 + 144 + v]; }
    float mu = s * inv, var = s2 * inv - mu * mu;
    float a = gv[v] * rsqrtf(var + EPSV);
    par[128 + v] = a; par[144 + v] = bv[v] - mu * a;
  }
}

__global__ void k_red2(const float* __restrict__ st2, const float* __restrict__ g2,
                       const float* __restrict__ b2, float* __restrict__ par)
{
  int o = threadIdx.x; // 64
  float s = 0.f, s2 = 0.f;
  for (int j = 0; j < 64; ++j) { s += st2[j * 128 + o]; s2 += st2[j * 128 + 64 + o]; }
  const float inv = 1.f / (float)ITEMS;
  float mu = s * inv, var = s2 * inv - mu * mu;
  float a = g2[o] * rsqrtf(var + EPSV);
  par[160 + o] = a; par[224 + o] = b2[o] - mu * a;
}

// ---------- MFMA PATH ----------

// GEMM1: fcat[M=ITEMS x K=160(144)] @ W^T -> [t1:64 | tv:16 | ak:32], bf16 out,
// + BN1 stats for t1/tv. One wave = 16-item M-tile, 4 tiles/wave.
__global__ void __launch_bounds__(256, 2) k_g1(
    const float4* __restrict__ xyz4, const float* __restrict__ feat,
    const int* __restrict__ idxb, const float* __restrict__ W1,
    const float* __restrict__ Wv, const float* __restrict__ Wk,
    const float* __restrict__ Wh, float* __restrict__ st1,
    ushort_t* __restrict__ t1g, ushort_t* __restrict__ akg,
    ushort_t* __restrict__ tvg)
{
  __shared__ ushort_t lds[4][16][120];
  int tid = threadIdx.x;
  int w = tid >> 6, lane = tid & 63;
  int m = lane & 15, quad = lane >> 4;

  bf16x8 Bf[7][5];
#pragma unroll
  for (int nt = 0; nt < 7; ++nt) {
    const float* wrow = (nt < 4) ? (W1 + (nt * 16 + m) * CCAT)
                      : (nt == 4) ? (Wv + m * CCAT)
                      : (Wk + ((nt - 5) * 16 + m) * CCAT);
#pragma unroll
    for (int ks = 0; ks < 5; ++ks) {
      int c0 = ks * 32 + quad * 8;
      bf16x8 f;
      if (c0 < 144) {
        float4 u = *(const float4*)(wrow + c0);
        float4 v = *(const float4*)(wrow + c0 + 4);
        f[0] = (short)f2bf(u.x); f[1] = (short)f2bf(u.y);
        f[2] = (short)f2bf(u.z); f[3] = (short)f2bf(u.w);
        f[4] = (short)f2bf(v.x); f[5] = (short)f2bf(v.y);
        f[6] = (short)f2bf(v.z); f[7] = (short)f2bf(v.w);
      } else {
#pragma unroll
        for (int j = 0; j < 8; ++j) f[j] = 0;
      }
      Bf[nt][ks] = f;
    }
  }

  float ss[5], sq[5];
#pragma unroll
  for (int i = 0; i < 5; ++i) { ss[i] = 0.f; sq[i] = 0.f; }

#pragma unroll 1
  for (int t = 0; t < 4; ++t) {
    int tile = blockIdx.x * 16 + w * 4 + t;
    int item = tile * 16 + m;
    int bn = item / 20;
    int b = bn >> 12;
    int nb = idxb[item];
    const float* fme = feat + (size_t)bn * CFEAT;
    const float* fnb = feat + ((size_t)b * NN + nb) * CFEAT;
    float4 pm = xyz4[bn];
    float4 pn = xyz4[(size_t)b * NN + nb];
    float rx = pn.x - pm.x, ry = pn.y - pm.y, rz = pn.z - pm.z;

    f32x4 acc[7];
#pragma unroll
    for (int nt = 0; nt < 7; ++nt)
#pragma unroll
      for (int r = 0; r < 4; ++r) acc[nt][r] = 0.f;

#pragma unroll
    for (int ks = 0; ks < 5; ++ks) {
      int c0 = ks * 32 + quad * 8;
      bf16x8 A;
      if (c0 < 64) {
        float4 a0 = *(const float4*)(fnb + c0);
        float4 a1 = *(const float4*)(fnb + c0 + 4);
        float4 m0 = *(const float4*)(fme + c0);
        float4 m1 = *(const float4*)(fme + c0 + 4);
        A[0] = (short)f2bf(a0.x - m0.x); A[1] = (short)f2bf(a0.y - m0.y);
        A[2] = (short)f2bf(a0.z - m0.z); A[3] = (short)f2bf(a0.w - m0.w);
        A[4] = (short)f2bf(a1.x - m1.x); A[5] = (short)f2bf(a1.y - m1.y);
        A[6] = (short)f2bf(a1.z - m1.z); A[7] = (short)f2bf(a1.w - m1.w);
      } else if (c0 < 128) {
        int c = c0 - 64;
        float4 m0 = *(const float4*)(fme + c);
        float4 m1 = *(const float4*)(fme + c + 4);
        A[0] = (short)f2bf(m0.x); A[1] = (short)f2bf(m0.y);
        A[2] = (short)f2bf(m0.z); A[3] = (short)f2bf(m0.w);
        A[4] = (short)f2bf(m1.x); A[5] = (short)f2bf(m1.y);
        A[6] = (short)f2bf(m1.z); A[7] = (short)f2bf(m1.w);
      } else if (c0 < 144) {
        int v0 = c0 - 128;
#pragma unroll
        for (int j = 0; j < 8; ++j) {
          float pv = fmaf(Wh[(v0 + j) * 3], rx,
                     fmaf(Wh[(v0 + j) * 3 + 1], ry, Wh[(v0 + j) * 3 + 2] * rz));
          A[j] = (short)f2bf(pv);
        }
      } else {
#pragma unroll
        for (int j = 0; j < 8; ++j) A[j] = 0;
      }
#pragma unroll
      for (int nt = 0; nt < 7; ++nt)
        acc[nt] = __builtin_amdgcn_mfma_f32_16x16x32_bf16(A, Bf[nt][ks], acc[nt], 0, 0, 0);
    }

#pragma unroll
    for (int nt = 0; nt < 5; ++nt)
#pragma unroll
      for (int r = 0; r < 4; ++r) {
        float v = acc[nt][r];
        ss[nt] += v; sq[nt] += v * v;
      }

#pragma unroll
    for (int nt = 0; nt < 7; ++nt)
#pragma unroll
      for (int r = 0; r < 4; ++r)
        lds[w][quad * 4 + r][nt * 16 + m] = f2bf(acc[nt][r]);
    __syncthreads();

    {
      int it = lane >> 2, sg = lane & 3;
      const uint4* sp = (const uint4*)&lds[w][it][sg * 16];
      uint4 d0 = sp[0], d1 = sp[1];
      *(uint4*)(t1g + (size_t)tile * 1024 + lane * 16) = d0;
      *(uint4*)(t1g + (size_t)tile * 1024 + lane * 16 + 8) = d1;
      const uint4* spk = (const uint4*)&lds[w][it][80 + sg * 8];
      *(uint4*)(akg + (size_t)tile * 512 + lane * 8) = spk[0];
      if (lane < 32) {
        const uint4* spv = (const uint4*)&lds[w][lane >> 1][64 + (lane & 1) * 8];
        *(uint4*)(tvg + (size_t)tile * 256 + lane * 8) = spv[0];
      }
    }
    __syncthreads();
  }

  float* slot = st1 + (blockIdx.x & 63) * 160;
#pragma unroll
  for (int nt = 0; nt < 5; ++nt) {
    float s = ss[nt];
    s += __shfl_xor(s, 16); s += __shfl_xor(s, 32);
    float q = sq[nt];
    q += __shfl_xor(q, 16); q += __shfl_xor(q, 32);
    if (lane < 16) {
      if (nt < 4) {
        atomicAdd(&slot[nt * 16 + lane], s);
        atomicAdd(&slot[64 + nt * 16 + lane], q);
      } else {
        atomicAdd(&slot[128 + lane], s);
        atomicAdd(&slot[144 + lane], q);
      }
    }
  }
}

// GEMM2: t2 = W2 @ relu(bn1(t1)); per-bn max/min of t2 -> fqpre; BN2 stats
__global__ void __launch_bounds__(256) k_g2(
    const ushort_t* __restrict__ t1g, const float* __restrict__ W2,
    const float* __restrict__ par, float* __restrict__ st2,
    float* __restrict__ fqpre)
{
  __shared__ ushort_t lds[4][80][68];
  int tid = threadIdx.x;
  int w = tid >> 6, lane = tid & 63;
  int m = lane & 15, quad = lane >> 4;
  int gw = blockIdx.x * 4 + w;

  bf16x8 Bf[4][2];
#pragma unroll
  for (int nt = 0; nt < 4; ++nt) {
    const float* wrow = W2 + (nt * 16 + m) * CHN;
#pragma unroll
    for (int ks = 0; ks < 2; ++ks) {
      int c0 = ks * 32 + quad * 8;
      float4 u = *(const float4*)(wrow + c0);
      float4 v = *(const float4*)(wrow + c0 + 4);
      bf16x8 f;
      f[0] = (short)f2bf(u.x); f[1] = (short)f2bf(u.y);
      f[2] = (short)f2bf(u.z); f[3] = (short)f2bf(u.w);
      f[4] = (short)f2bf(v.x); f[5] = (short)f2bf(v.y);
      f[6] = (short)f2bf(v.z); f[7] = (short)f2bf(v.w);
      Bf[nt][ks] = f;
    }
  }
  float pa[2][8], pb[2][8];
#pragma unroll
  for (int ks = 0; ks < 2; ++ks) {
    int c0 = ks * 32 + quad * 8;
    float4 a0 = *(const float4*)(par + c0);
    float4 a1 = *(const float4*)(par + c0 + 4);
    float4 b0 = *(const float4*)(par + 64 + c0);
    float4 b1 = *(const float4*)(par + 64 + c0 + 4);
    pa[ks][0] = a0.x; pa[ks][1] = a0.y; pa[ks][2] = a0.z; pa[ks][3] = a0.w;
    pa[ks][4] = a1.x; pa[ks][5] = a1.y; pa[ks][6] = a1.z; pa[ks][7] = a1.w;
    pb[ks][0] = b0.x; pb[ks][1] = b0.y; pb[ks][2] = b0.z; pb[ks][3] = b0.w;
    pb[ks][4] = b1.x; pb[ks][5] = b1.y; pb[ks][6] = b1.z; pb[ks][7] = b1.w;
  }

  float ss[4] = {0.f, 0.f, 0.f, 0.f}, sq[4] = {0.f, 0.f, 0.f, 0.f};

#pragma unroll 1
  for (int t5 = 0; t5 < 5; ++t5) {
    int tile = gw * 5 + t5;
    int item = tile * 16 + m;
    f32x4 acc[4];
#pragma unroll
    for (int nt = 0; nt < 4; ++nt)
#pragma unroll
      for (int r = 0; r < 4; ++r) acc[nt][r] = 0.f;
#pragma unroll
    for (int ks = 0; ks < 2; ++ks) {
      const ushort_t* tp = t1g + (size_t)item * 64 + ks * 32 + quad * 8;
      uint4 raw = *(const uint4*)tp;
      unsigned rw[4] = {raw.x, raw.y, raw.z, raw.w};
      bf16x8 A;
#pragma unroll
      for (int i = 0; i < 4; ++i) {
        float lo = bf2f((ushort_t)(rw[i] & 0xffffu));
        float hi = bf2f((ushort_t)(rw[i] >> 16));
        float h0 = fmaxf(fmaf(lo, pa[ks][2 * i], pb[ks][2 * i]), 0.f);
        float h1 = fmaxf(fmaf(hi, pa[ks][2 * i + 1], pb[ks][2 * i + 1]), 0.f);
        A[2 * i] = (short)f2bf(h0);
        A[2 * i + 1] = (short)f2bf(h1);
      }
#pragma unroll
      for (int nt = 0; nt < 4; ++nt)
        acc[nt] = __builtin_amdgcn_mfma_f32_16x16x32_bf16(A, Bf[nt][ks], acc[nt], 0, 0, 0);
    }
#pragma unroll
    for (int nt = 0; nt < 4; ++nt)
#pragma unroll
      for (int r = 0; r < 4; ++r) {
        float v = acc[nt][r];
        ss[nt] += v; sq[nt] += v * v;
        lds[w][t5 * 16 + quad * 4 + r][nt * 16 + m] = f2bf(v);
      }
  }
  __syncthreads();

  {
    int bnl = lane >> 4;
    int chb = (lane & 15) * 4;
    float mx0 = -3.4e38f, mx1 = -3.4e38f, mx2 = -3.4e38f, mx3 = -3.4e38f;
    float mn0 = 3.4e38f, mn1 = 3.4e38f, mn2 = 3.4e38f, mn3 = 3.4e38f;
#pragma unroll
    for (int j = 0; j < KK; ++j) {
      const uint2 rv = *(const uint2*)&lds[w][bnl * 20 + j][chb];
      float v0 = bf2f((ushort_t)(rv.x & 0xffffu));
      float v1 = bf2f((ushort_t)(rv.x >> 16));
      float v2 = bf2f((ushort_t)(rv.y & 0xffffu));
      float v3 = bf2f((ushort_t)(rv.y >> 16));
      mx0 = fmaxf(mx0, v0); mn0 = fminf(mn0, v0);
      mx1 = fmaxf(mx1, v1); mn1 = fminf(mn1, v1);
      mx2 = fmaxf(mx2, v2); mn2 = fminf(mn2, v2);
      mx3 = fmaxf(mx3, v3); mn3 = fminf(mn3, v3);
    }
    int bn = gw * 4 + bnl;
    *(float4*)(fqpre + (size_t)bn * 128 + chb) = make_float4(mx0, mx1, mx2, mx3);
    *(float4*)(fqpre + (size_t)bn * 128 + 64 + chb) = make_float4(mn0, mn1, mn2, mn3);
  }

  float* slot = st2 + (blockIdx.x & 63) * 128;
#pragma unroll
  for (int nt = 0; nt < 4; ++nt) {
    float s = ss[nt];
    s += __shfl_xor(s, 16); s += __shfl_xor(s, 32);
    float q = sq[nt];
    q += __shfl_xor(q, 16); q += __shfl_xor(q, 32);
    if (lane < 16) {
      atomicAdd(&slot[nt * 16 + lane], s);
      atomicAdd(&slot[64 + nt * 16 + lane], q);
    }
  }
}

// softmax over k + kv from cached ak/tv
#define P3P 16
__global__ void __launch_bounds__(320, 2) k_p3s(
    const ushort_t* __restrict__ akg, const ushort_t* __restrict__ tvg,
    const float* __restrict__ par, __hip_bfloat16* __restrict__ kvg)
{
  __shared__ float sl[P3P][KK][DKK + 1];
  __shared__ float sv[P3P][KK][DVV + 1];
  __shared__ float sm[P3P][DKK], ssi[P3P][DKK];
  int tid = threadIdx.x;
  int p = tid / KK, k = tid - p * KK;
  size_t item = (size_t)(blockIdx.x * P3P + p) * KK + k;
  const unsigned* ap = (const unsigned*)(akg + item * DKK);
#pragma unroll
  for (int i = 0; i < DKK / 2; ++i) {
    unsigned wv = ap[i];
    sl[p][k][2 * i]     = __uint_as_float(wv << 16);
    sl[p][k][2 * i + 1] = __uint_as_float(wv & 0xffff0000u);
  }
  const unsigned* vp = (const unsigned*)(tvg + item * DVV);
#pragma unroll
  for (int i = 0; i < DVV / 2; ++i) {
    unsigned wv = vp[i];
    float lo = __uint_as_float(wv << 16);
    float hi = __uint_as_float(wv & 0xffff0000u);
    sv[p][k][2 * i]     = fmaf(lo, par[128 + 2 * i],     par[144 + 2 * i]);
    sv[p][k][2 * i + 1] = fmaf(hi, par[128 + 2 * i + 1], par[144 + 2 * i + 1]);
  }
  __syncthreads();
  for (int pd = tid; pd < P3P * DKK; pd += 320) {
    int pp = pd >> 5, d = pd & 31;
    float m = -1e30f;
#pragma unroll
    for (int q = 0; q < KK; ++q) m = fmaxf(m, sl[pp][q][d]);
    float S = 0.f;
#pragma unroll
    for (int q = 0; q < KK; ++q) S += __expf(sl[pp][q][d] - m);
    sm[pp][d] = m; ssi[pp][d] = 1.f / S;
  }
  __syncthreads();
  for (int pd = tid; pd < P3P * DKK; pd += 320) {
    int pp = pd >> 5, d = pd & 31;
    float m = sm[pp][d], Si = ssi[pp][d];
    float a[DVV];
#pragma unroll
    for (int v = 0; v < DVV; ++v) a[v] = 0.f;
#pragma unroll
    for (int q = 0; q < KK; ++q) {
      float wgt = __expf(sl[pp][q][d] - m) * Si;
#pragma unroll
      for (int v = 0; v < DVV; ++v) a[v] = fmaf(wgt, sv[pp][q][v], a[v]);
    }
    __hip_bfloat162* dst = (__hip_bfloat162*)
        (kvg + ((size_t)(blockIdx.x * P3P + pp) * DKK + d) * DVV);
#pragma unroll
    for (int v = 0; v < DVV; v += 2) {
      float2 f2; f2.x = a[v]; f2.y = a[v + 1];
      dst[v >> 1] = __float22bfloat162_rn(f2);
    }
  }
}

// MFMA GEMM: q2 = Wq @ fq, fq reconstructed inline from fqpre (sign-aware).
// Wave = one 16-item M-tile x half of N (8 N-tiles = 128 ch). + BNq stats.
__global__ void __launch_bounds__(256) k_gq(
    const float* __restrict__ fqpre, const float* __restrict__ Wq,
    const float* __restrict__ par, float* __restrict__ stq,
    float* __restrict__ q2g)
{
  int tid = threadIdx.x;
  int w = tid >> 6, lane = tid & 63;
  int m = lane & 15, quad = lane >> 4;
  int nt0 = (w & 1) * 8;
  int mt = blockIdx.x * 2 + (w >> 1);   // grid 1024 -> 2048 M-tiles

  bf16x8 Bf[8][2];
#pragma unroll
  for (int nt = 0; nt < 8; ++nt) {
    const float* wrow = Wq + ((nt0 + nt) * 16 + m) * CHN;
#pragma unroll
    for (int ks = 0; ks < 2; ++ks) {
      int c0 = ks * 32 + quad * 8;
      float4 u = *(const float4*)(wrow + c0);
      float4 v = *(const float4*)(wrow + c0 + 4);
      bf16x8 f;
      f[0] = (short)f2bf(u.x); f[1] = (short)f2bf(u.y);
      f[2] = (short)f2bf(u.z); f[3] = (short)f2bf(u.w);
      f[4] = (short)f2bf(v.x); f[5] = (short)f2bf(v.y);
      f[6] = (short)f2bf(v.z); f[7] = (short)f2bf(v.w);
      Bf[nt][ks] = f;
    }
  }

  f32x4 acc[8];
#pragma unroll
  for (int nt = 0; nt < 8; ++nt)
#pragma unroll
    for (int r = 0; r < 4; ++r) acc[nt][r] = 0.f;

  int item = mt * 16 + m;
  const float* fp = fqpre + (size_t)item * 128;
#pragma unroll
  for (int ks = 0; ks < 2; ++ks) {
    int c0 = ks * 32 + quad * 8;
    float mxv[8], mnv[8], av[8], bv[8];
    *(float4*)&mxv[0] = *(const float4*)(fp + c0);
    *(float4*)&mxv[4] = *(const float4*)(fp + c0 + 4);
    *(float4*)&mnv[0] = *(const float4*)(fp + 64 + c0);
    *(float4*)&mnv[4] = *(const float4*)(fp + 64 + c0 + 4);
    *(float4*)&av[0] = *(const float4*)(par + 160 + c0);
    *(float4*)&av[4] = *(const float4*)(par + 160 + c0 + 4);
    *(float4*)&bv[0] = *(const float4*)(par + 224 + c0);
    *(float4*)&bv[4] = *(const float4*)(par + 224 + c0 + 4);
    bf16x8 A;
#pragma unroll
    for (int j = 0; j < 8; ++j) {
      float pick = (av[j] >= 0.f) ? mxv[j] : mnv[j];
      float fq = fmaxf(fmaf(av[j], pick, bv[j]), 0.f);
      A[j] = (short)f2bf(fq);
    }
#pragma unroll
    for (int nt = 0; nt < 8; ++nt)
      acc[nt] = __builtin_amdgcn_mfma_f32_16x16x32_bf16(A, Bf[nt][ks], acc[nt], 0, 0, 0);
  }

  // store q2 (C layout: row=item=quad*4+r, col=o=(nt0+nt)*16+m) + stats
  float* slot = stq + (blockIdx.x & 63) * 512;
#pragma unroll
  for (int nt = 0; nt < 8; ++nt) {
    int o = (nt0 + nt) * 16 + m;
    float s = 0.f, q = 0.f;
#pragma unroll
    for (int r = 0; r < 4; ++r) {
      float v = acc[nt][r];
      q2g[(size_t)(mt * 16 + quad * 4 + r) * NQC + o] = v;
      s += v; q += v * v;
    }
    s += __shfl_xor(s, 16); s += __shfl_xor(s, 32);
    q += __shfl_xor(q, 16); q += __shfl_xor(q, 32);
    if (lane < 16) {
      atomicAdd(&slot[(nt0 + nt) * 16 + lane], s);
      atomicAdd(&slot[256 + (nt0 + nt) * 16 + lane], q);
    }
  }
}

__global__ void k_redq(const float* __restrict__ stq, const float* __restrict__ gq,
                       const float* __restrict__ bq, float* __restrict__ par)
{
  int o = threadIdx.x; // 256
  float s = 0.f, s2 = 0.f;
  for (int j = 0; j < 64; ++j) { s += stq[j * 512 + o]; s2 += stq[j * 512 + 256 + o]; }
  const float inv = 1.f / (float)BNTOT;
  float mu = s * inv, var = s2 * inv - mu * mu;
  float a = gq[o] * rsqrtf(var + EPSV);
  par[288 + o] = a; par[544 + o] = bq[o] - mu * a;
}

// out[h*16+v] = sum_d relu(bnq(q2))[h*32+d] * kv[d][v] ; 4 bn per block
__global__ void __launch_bounds__(256) k_p4(const float* __restrict__ q2g,
                                            const __hip_bfloat16* __restrict__ kvg,
                                            const float* __restrict__ par,
                                            float* __restrict__ outp)
{
  __shared__ float sq2[4][NQC];
  __shared__ float skv[4][DKK * DVV];
  int t = threadIdx.x & 63, sub = threadIdx.x >> 6;
  int v = blockIdx.x * 4 + sub;
  int b = v & 7, n = v >> 3;
  int bn = (b << 12) | n;
#pragma unroll
  for (int j = 0; j < 8; ++j)
    skv[sub][t + 64 * j] = __bfloat162float(kvg[(size_t)bn * 512 + t + 64 * j]);
#pragma unroll
  for (int j = 0; j < 4; ++j) {
    int o = t + 64 * j;
    float q = q2g[(size_t)bn * NQC + o];
    sq2[sub][o] = fmaxf(fmaf(q, par[288 + o], par[544 + o]), 0.f);
  }
  __syncthreads();
#pragma unroll
  for (int j = 0; j < 2; ++j) {
    int ch = t + 64 * j, h = ch >> 4, vv = ch & 15;
    float a = 0.f;
#pragma unroll
    for (int d = 0; d < DKK; ++d) a = fmaf(sq2[sub][h * DKK + d], skv[sub][d * DVV + vv], a);
    outp[(size_t)BNTOT * 3 + ((size_t)(b * 128 + ch)) * NN + n] = a;
  }
}

// ---------- FALLBACK (round-5 proven path) ----------

__global__ void __launch_bounds__(256, 3) k_s1f(
    const float4* __restrict__ xyz4, const float* __restrict__ feat,
    const int* __restrict__ idxb, const float* __restrict__ W1,
    const float* __restrict__ Wv, const float* __restrict__ Wh,
    float* __restrict__ st1,
    __hip_bfloat16* __restrict__ t1g, __hip_bfloat16* __restrict__ tvg)
{
  int t = blockIdx.x * 256 + threadIdx.x;
  int bn = t / KK, k = t - bn * KK, b = bn >> 12;
  int nb = idxb[(size_t)bn * KK + k];
  const float* fme = feat + (size_t)bn * CFEAT;
  const float* fnb = feat + ((size_t)b * NN + nb) * CFEAT;
  float4 pn = xyz4[(size_t)b * NN + nb];
  float4 pm = xyz4[bn];
  float rx = pn.x - pm.x, ry = pn.y - pm.y, rz = pn.z - pm.z;
  float a1[CHN], av[DVV];
#pragma unroll
  for (int o = 0; o < CHN; ++o) a1[o] = 0.f;
#pragma unroll
  for (int o = 0; o < DVV; ++o) av[o] = 0.f;
#pragma unroll 1
  for (int ch = 0; ch < 9; ++ch) {
    float fc[16];
    build_chunk(ch, fme, fnb, rx, ry, rz, Wh, fc);
    accum_chunk<CHN>(W1, ch, fc, a1);
    accum_chunk<DVV>(Wv, ch, fc, av);
  }
  __hip_bfloat162* t1p = (__hip_bfloat162*)(t1g + (size_t)t * CHN);
#pragma unroll
  for (int o = 0; o < CHN; o += 2) {
    float2 f2; f2.x = a1[o]; f2.y = a1[o + 1];
    t1p[o >> 1] = __float22bfloat162_rn(f2);
  }
  __hip_bfloat162* tvp = (__hip_bfloat162*)(tvg + (size_t)t * DVV);
#pragma unroll
  for (int o = 0; o < DVV; o += 2) {
    float2 f2; f2.x = av[o]; f2.y = av[o + 1];
    tvp[o >> 1] = __float22bfloat162_rn(f2);
  }
  float* slot = st1 + (blockIdx.x & 63) * 160;
  int lane = threadIdx.x & 63;
#pragma unroll
  for (int o = 0; o < CHN; ++o) {
    float s = wred(a1[o]), s2 = wred(a1[o] * a1[o]);
    if (lane == 0) { atomicAdd(&slot[o], s); atomicAdd(&slot[CHN + o], s2); }
  }
#pragma unroll
  for (int o = 0; o < DVV; ++o) {
    float s = wred(av[o]), s2 = wred(av[o] * av[o]);
    if (lane == 0) { atomicAdd(&slot[128 + o], s); atomicAdd(&slot[128 + DVV + o], s2); }
  }
}

__global__ void __launch_bounds__(256, 4) k_skf(
    const float4* __restrict__ xyz4, const float* __restrict__ feat,
    const int* __restrict__ idxb, const float* __restrict__ Wk,
    const float* __restrict__ Wh, __hip_bfloat16* __restrict__ akg)
{
  int t = blockIdx.x * 256 + threadIdx.x;
  int bn = t / KK, k = t - bn * KK, b = bn >> 12;
  int nb = idxb[(size_t)bn * KK + k];
  const float* fme = feat + (size_t)bn * CFEAT;
  const float* fnb = feat + ((size_t)b * NN + nb) * CFEAT;
  float4 pn = xyz4[(size_t)b * NN + nb];
  float4 pm = xyz4[bn];
  float rx = pn.x - pm.x, ry = pn.y - pm.y, rz = pn.z - pm.z;
  float ak[DKK];
#pragma unroll
  for (int o = 0; o < DKK; ++o) ak[o] = 0.f;
#pragma unroll 1
  for (int ch = 0; ch < 9; ++ch) {
    float fc[16];
    build_chunk(ch, fme, fnb, rx, ry, rz, Wh, fc);
    accum_chunk<DKK>(Wk, ch, fc, ak);
  }
  __hip_bfloat162* akp = (__hip_bfloat162*)(akg + (size_t)t * DKK);
#pragma unroll
  for (int o = 0; o < DKK; o += 2) {
    float2 f2; f2.x = ak[o]; f2.y = ak[o + 1];
    akp[o >> 1] = __float22bfloat162_rn(f2);
  }
}

__global__ void __launch_bounds__(256, 4) k_s2f(
    const __hip_bfloat16* __restrict__ t1g, const float* __restrict__ W2,
    const float* __restrict__ par, float* __restrict__ st2)
{
  int t = blockIdx.x * 256 + threadIdx.x;
  const unsigned* tp = (const unsigned*)(t1g + (size_t)t * CHN);
  float h1[CHN];
#pragma unroll
  for (int i = 0; i < CHN / 2; ++i) {
    unsigned w = tp[i];
    float lo = __uint_as_float(w << 16);
    float hi = __uint_as_float(w & 0xffff0000u);
    h1[2 * i]     = fmaxf(fmaf(lo, par[2 * i],     par[64 + 2 * i]),     0.f);
    h1[2 * i + 1] = fmaxf(fmaf(hi, par[2 * i + 1], par[64 + 2 * i + 1]), 0.f);
  }
  float* slot = st2 + (blockIdx.x & 63) * 128;
  int lane = threadIdx.x & 63;
#pragma unroll 1
  for (int o = 0; o < CHN; ++o) {
    const float* w = W2 + o * CHN;
    float c0 = 0.f, c1 = 0.f, c2 = 0.f, c3 = 0.f;
#pragma unroll
    for (int c = 0; c < CHN; c += 4) {
      c0 = fmaf(w[c + 0], h1[c + 0], c0); c1 = fmaf(w[c + 1], h1[c + 1], c1);
      c2 = fmaf(w[c + 2], h1[c + 2], c2); c3 = fmaf(w[c + 3], h1[c + 3], c3);
    }
    float v = (c0 + c1) + (c2 + c3);
    float s = wred(v), s2 = wred(v * v);
    if (lane == 0) { atomicAdd(&slot[o], s); atomicAdd(&slot[64 + o], s2); }
  }
}

__global__ void __launch_bounds__(320, 2) k_p3f(
    const __hip_bfloat16* __restrict__ t1g, const __hip_bfloat16* __restrict__ akg,
    const __hip_bfloat16* __restrict__ tvg, const float* __restrict__ W2,
    const float* __restrict__ par, float* __restrict__ fqg,
    __hip_bfloat16* __restrict__ kvg)
{
  __shared__ float sl[P3P][KK][DKK + 1];
  __shared__ float sv[P3P][KK][DVV + 1];
  __shared__ unsigned sfq[P3P][CHN];
  __shared__ float sm[P3P][DKK], ssi[P3P][DKK];
  int tid = threadIdx.x;
  for (int i = tid; i < P3P * CHN; i += 320) ((unsigned*)sfq)[i] = 0u;
  __syncthreads();
  int p = tid / KK, k = tid - p * KK;
  size_t item = (size_t)(blockIdx.x * P3P + p) * KK + k;
  const unsigned* ap = (const unsigned*)(akg + item * DKK);
#pragma unroll
  for (int i = 0; i < DKK / 2; ++i) {
    unsigned w = ap[i];
    sl[p][k][2 * i]     = __uint_as_float(w << 16);
    sl[p][k][2 * i + 1] = __uint_as_float(w & 0xffff0000u);
  }
  const unsigned* vp = (const unsigned*)(tvg + item * DVV);
#pragma unroll
  for (int i = 0; i < DVV / 2; ++i) {
    unsigned w = vp[i];
    float lo = __uint_as_float(w << 16);
    float hi = __uint_as_float(w & 0xffff0000u);
    sv[p][k][2 * i]     = fmaf(lo, par[128 + 2 * i],     par[144 + 2 * i]);
    sv[p][k][2 * i + 1] = fmaf(hi, par[128 + 2 * i + 1], par[144 + 2 * i + 1]);
  }
  const unsigned* tp = (const unsigned*)(t1g + item * CHN);
  float h1[CHN];
#pragma unroll
  for (int i = 0; i < CHN / 2; ++i) {
    unsigned w = tp[i];
    float lo = __uint_as_float(w << 16);
    float hi = __uint_as_float(w & 0xffff0000u);
    h1[2 * i]     = fmaxf(fmaf(lo, par[2 * i],     par[64 + 2 * i]),     0.f);
    h1[2 * i + 1] = fmaxf(fmaf(hi, par[2 * i + 1], par[64 + 2 * i + 1]), 0.f);
  }
#pragma unroll 1
  for (int o = 0; o < CHN; ++o) {
    const float* w = W2 + o * CHN;
    float c0 = 0.f, c1 = 0.f, c2 = 0.f, c3 = 0.f;
#pragma unroll
    for (int c = 0; c < CHN; c += 4) {
      c0 = fmaf(w[c + 0], h1[c + 0], c0); c1 = fmaf(w[c + 1], h1[c + 1], c1);
      c2 = fmaf(w[c + 2], h1[c + 2], c2); c3 = fmaf(w[c + 3], h1[c + 3], c3);
    }
    float v = (c0 + c1) + (c2 + c3);
    float h2 = fmaxf(fmaf(v, par[160 + o], par[224 + o]), 0.f);
    atomicMax(&sfq[p][o], __float_as_uint(h2));
  }
  __syncthreads();
  for (int i = tid; i < P3P * CHN; i += 320)
    fqg[(size_t)blockIdx.x * (P3P * CHN) + i] = __uint_as_float(sfq[i >> 6][i & 63]);
  for (int pd = tid; pd < P3P * DKK; pd += 320) {
    int pp = pd >> 5, d = pd & 31;
    float m = -1e30f;
#pragma unroll
    for (int q = 0; q < KK; ++q) m = fmaxf(m, sl[pp][q][d]);
    float S = 0.f;
#pragma unroll
    for (int q = 0; q < KK; ++q) S += __expf(sl[pp][q][d] - m);
    sm[pp][d] = m; ssi[pp][d] = 1.f / S;
  }
  __syncthreads();
  for (int pd = tid; pd < P3P * DKK; pd += 320) {
    int pp = pd >> 5, d = pd & 31;
    float m = sm[pp][d], Si = ssi[pp][d];
    float a[DVV];
#pragma unroll
    for (int v = 0; v < DVV; ++v) a[v] = 0.f;
#pragma unroll
    for (int q = 0; q < KK; ++q) {
      float wgt = __expf(sl[pp][q][d] - m) * Si;
#pragma unroll
      for (int v = 0; v < DVV; ++v) a[v] = fmaf(wgt, sv[pp][q][v], a[v]);
    }
    __hip_bfloat162* dst = (__hip_bfloat162*)
        (kvg + ((size_t)(blockIdx.x * P3P + pp) * DKK + d) * DVV);
#pragma unroll
    for (int v = 0; v < DVV; v += 2) {
      float2 f2; f2.x = a[v]; f2.y = a[v + 1];
      dst[v >> 1] = __float22bfloat162_rn(f2);
    }
  }
}

__global__ void __launch_bounds__(128, 2) k_pqf(const float* __restrict__ fqg,
                                                const float* __restrict__ Wq,
                                                float* __restrict__ stq,
                                                float* __restrict__ q2g)
{
  int bn = blockIdx.x * 128 + threadIdx.x;
  float fq[CHN];
#pragma unroll
  for (int c = 0; c < CHN; c += 4) {
    float4 v4 = *(const float4*)(fqg + (size_t)bn * CHN + c);
    fq[c] = v4.x; fq[c + 1] = v4.y; fq[c + 2] = v4.z; fq[c + 3] = v4.w;
  }
  float* slot = stq + (blockIdx.x & 63) * 512;
  int lane = threadIdx.x & 63;
#pragma unroll 1
  for (int o = 0; o < NQC; ++o) {
    const float* w = Wq + o * CHN;
    float a0 = 0.f, a1 = 0.f, a2 = 0.f, a3 = 0.f;
#pragma unroll
    for (int c = 0; c < CHN; c += 4) {
      a0 = fmaf(w[c], fq[c], a0); a1 = fmaf(w[c + 1], fq[c + 1], a1);
      a2 = fmaf(w[c + 2], fq[c + 2], a2); a3 = fmaf(w[c + 3], fq[c + 3], a3);
    }
    float v = (a0 + a1) + (a2 + a3);
    q2g[(size_t)bn * NQC + o] = v;
    float s = wred(v), s2 = wred(v * v);
    if (lane == 0) { atomicAdd(&slot[o], s); atomicAdd(&slot[256 + o], s2); }
  }
}

__global__ void __launch_bounds__(64) k_p4f(const float* __restrict__ q2g,
                                            const __hip_bfloat16* __restrict__ kvg,
                                            const float* __restrict__ par,
                                            float* __restrict__ outp)
{
  __shared__ float sq2[NQC], skv[DKK * DVV];
  int t = threadIdx.x;
  int b = blockIdx.x & 7, n = blockIdx.x >> 3;
  int bn = (b << 12) | n;
#pragma unroll
  for (int j = 0; j < 8; ++j)
    skv[t + 64 * j] = __bfloat162float(kvg[(size_t)bn * 512 + t + 64 * j]);
#pragma unroll
  for (int j = 0; j < 4; ++j) {
    int o = t + 64 * j;
    float v = q2g[(size_t)bn * NQC + o];
    sq2[o] = fmaxf(fmaf(v, par[288 + o], par[544 + o]), 0.f);
  }
  __syncthreads();
#pragma unroll
  for (int j = 0; j < 2; ++j) {
    int ch = t + 64 * j, h = ch >> 4, vv = ch & 15;
    float a = 0.f;
#pragma unroll
    for (int d = 0; d < DKK; ++d) a = fmaf(sq2[h * DKK + d], skv[d * DVV + vv], a);
    outp[(size_t)BNTOT * 3 + ((size_t)(b * 128 + ch)) * NN + n] = a;
  }
}

// ---------- launch ----------

extern "C" void kernel_launch(void* const* d_in, const int* in_sizes, int n_in,
                              void* d_out, int out_size, void* d_ws, size_t ws_size,
                              hipStream_t stream)
{
  const float* x  = (const float*)d_in[0];
  const float* W1 = (const float*)d_in[1];
  const float* g1 = (const float*)d_in[2];
  const float* b1 = (const float*)d_in[3];
  const float* W2 = (const float*)d_in[4];
  const float* g2 = (const float*)d_in[5];
  const float* b2 = (const float*)d_in[6];
  const float* Wv = (const float*)d_in[7];
  const float* gv = (const float*)d_in[8];
  const float* bv = (const float*)d_in[9];
  const float* Wk = (const float*)d_in[10];
  const float* Wq = (const float*)d_in[11];
  const float* gq = (const float*)d_in[12];
  const float* bq = (const float*)d_in[13];
  const float* Wh = (const float*)d_in[14];

  float* ws = (float*)d_ws;
  float4* xyz4 = (float4*)ws;                      // 131072
  float*  feat = ws + 131072;                      // 2097152
  int*    idxb = (int*)(ws + 2228224);             // 655360
  float*  st1  = ws + 2883584;                     // 10240
  float*  st2  = ws + 2893824;                     // 8192
  float*  stq  = ws + 2902016;                     // 32768
  float*  par  = ws + 2934784;                     // 800
  float*  fqg  = ws + 2935584;                     // 2097152
  __hip_bfloat16* kvg = (__hip_bfloat16*)(ws + 5032736);  // 8388608 fw
  float*  outp = (float*)d_out;

  ushort_t* t1g = (ushort_t*)(ws + 13421344);      // 20971520 fw
  ushort_t* akg = (ushort_t*)(ws + 34392864);      // 10485760 fw
  ushort_t* tvg = (ushort_t*)(ws + 44878624);      //  5242880 fw
  float*    fqpre = ws + 50121504;                 //  4194304 fw
  float*    q2g = ws + 13421344;                   // alias t1g (dead after k_g2)

  const size_t NEW_NEED  = (size_t)54315808 * 4;   // ~217.3 MB (MFMA path)

  hipMemsetAsync(st1, 0, (size_t)(10240 + 8192 + 32768) * sizeof(float), stream);
  k_prep<<<128, 256, 0, stream>>>(x, xyz4, feat, outp);
  k_knn <<<512, 512, 0, stream>>>(xyz4, idxb);

  if (ws_size >= NEW_NEED) {
    k_g1  <<<2560, 256, 0, stream>>>(xyz4, feat, idxb, W1, Wv, Wk, Wh, st1, t1g, akg, tvg);
    k_red1<<<1, 128, 0, stream>>>(st1, g1, b1, gv, bv, par);
    k_g2  <<<2048, 256, 0, stream>>>(t1g, W2, par, st2, fqpre);
    k_red2<<<1, 64, 0, stream>>>(st2, g2, b2, par);
    k_p3s <<<2048, 320, 0, stream>>>(akg, tvg, par, kvg);
    k_gq  <<<1024, 256, 0, stream>>>(fqpre, Wq, par, stq, q2g);
    k_redq<<<1, 256, 0, stream>>>(stq, gq, bq, par);
    k_p4  <<<8192, 256, 0, stream>>>(q2g, kvg, par, outp);
  } else {
    __hip_bfloat16* t1b = (__hip_bfloat16*)t1g;
    __hip_bfloat16* akb = (__hip_bfloat16*)akg;
    __hip_bfloat16* tvb = (__hip_bfloat16*)tvg;
    float* q2f = ws + 34392864;                    // alias akg region
    k_s1f <<<2560, 256, 0, stream>>>(xyz4, feat, idxb, W1, Wv, Wh, st1, t1b, tvb);
    k_skf <<<2560, 256, 0, stream>>>(xyz4, feat, idxb, Wk, Wh, akb);
    k_red1<<<1, 128, 0, stream>>>(st1, g1, b1, gv, bv, par);
    k_s2f <<<2560, 256, 0, stream>>>(t1b, W2, par, st2);
    k_red2<<<1, 64, 0, stream>>>(st2, g2, b2, par);
    k_p3f <<<2048, 320, 0, stream>>>(t1b, akb, tvb, W2, par, fqg, kvg);
    k_pqf <<<256, 128, 0, stream>>>(fqg, Wq, stq, q2f);
    k_redq<<<1, 256, 0, stream>>>(stq, gq, bq, par);
    k_p4f <<<32768, 64, 0, stream>>>(q2f, kvg, par, outp);
  }
}

// Round 8
// 603.240 us; speedup vs baseline: 9.2067x; 1.0200x over previous
//
#include <hip/hip_runtime.h>
#include <hip/hip_bf16.h>

#define NB 8
#define NN 4096
#define KK 20
#define CFEAT 64
#define CCAT 144
#define CHN 64
#define NHEAD 8
#define DKK 32
#define DVV 16
#define NQC 256
#define EPSV 1e-5f
#define BNTOT (NB*NN)      /* 32768 */
#define ITEMS (BNTOT*KK)   /* 655360 */

typedef unsigned short ushort_t;
typedef __attribute__((ext_vector_type(8))) short bf16x8;
typedef __attribute__((ext_vector_type(4))) float f32x4;

// ---------- helpers ----------

__device__ __forceinline__ float wred(float v) {
#pragma unroll
  for (int off = 32; off > 0; off >>= 1) v += __shfl_down(v, off);
  return v;
}

__device__ __forceinline__ ushort_t f2bf(float f) {
  unsigned u = __float_as_uint(f);
  return (ushort_t)((u + 0x7fffu + ((u >> 16) & 1u)) >> 16);
}
__device__ __forceinline__ float bf2f(ushort_t h) {
  return __uint_as_float(((unsigned)h) << 16);
}

// identical in phase1/phase2 so d is bit-identical
__device__ __forceinline__ float pdist(float4 me, float4 p) {
  float dot = fmaf(me.x, p.x, fmaf(me.y, p.y, me.z * p.z));
  return fmaf(-2.f, dot, me.w + p.w);
}

// build 16 channels of fcat (fallback path)
__device__ __forceinline__ void build_chunk(int ch,
    const float* __restrict__ fme, const float* __restrict__ fnb,
    float rx, float ry, float rz, const float* __restrict__ Wh, float* fc)
{
  if (ch < 4) {
    int c0 = ch * 16;
#pragma unroll
    for (int j = 0; j < 16; j += 4) {
      float4 a = *(const float4*)(fnb + c0 + j);
      float4 m = *(const float4*)(fme + c0 + j);
      fc[j + 0] = a.x - m.x; fc[j + 1] = a.y - m.y;
      fc[j + 2] = a.z - m.z; fc[j + 3] = a.w - m.w;
    }
  } else if (ch < 8) {
    int c0 = (ch - 4) * 16;
#pragma unroll
    for (int j = 0; j < 16; j += 4) {
      float4 m = *(const float4*)(fme + c0 + j);
      fc[j + 0] = m.x; fc[j + 1] = m.y; fc[j + 2] = m.z; fc[j + 3] = m.w;
    }
  } else {
#pragma unroll
    for (int v = 0; v < 16; ++v)
      fc[v] = fmaf(Wh[v * 3], rx, fmaf(Wh[v * 3 + 1], ry, Wh[v * 3 + 2] * rz));
  }
}

template<int NO>
__device__ __forceinline__ void accum_chunk(const float* __restrict__ W, int ch,
                                            const float* fc, float* acc)
{
  const float* wb = W + ch * 16;
#pragma unroll
  for (int o = 0; o < NO; ++o) {
    const float* w = wb + o * CCAT;
#pragma unroll
    for (int j = 0; j < 16; ++j) acc[o] = fmaf(w[j], fc[j], acc[o]);
  }
}

// ---------- shared kernels ----------

// fully-coalesced prep via LDS staging: block = 256 points
__global__ void __launch_bounds__(256) k_prep(const float* __restrict__ x,
                                              float4* __restrict__ xyz4,
                                              float* __restrict__ feat,
                                              float* __restrict__ outp)
{
  __shared__ float lx[256 * 67];        // 68608 B
  int t = threadIdx.x;
  size_t base = (size_t)blockIdx.x * 256;
  const float* xb = x + base * 67;
#pragma unroll 4
  for (int j = t; j < 256 * 67; j += 256) lx[j] = xb[j];
  __syncthreads();
  {
    float a = lx[t * 67], b = lx[t * 67 + 1], c = lx[t * 67 + 2];
    xyz4[base + t] = make_float4(a, b, c, a * a + b * b + c * c);
  }
#pragma unroll
  for (int r = 0; r < 3; ++r) {
    int j = r * 256 + t;                // 0..767
    outp[base * 3 + j] = lx[(j / 3) * 67 + (j % 3)];
  }
#pragma unroll 8
  for (int j = t; j < 256 * 64; j += 256)
    feat[base * 64 + j] = lx[(j >> 6) * 67 + 3 + (j & 63)];
}

#define KNQ 64
#define KNS 8
__global__ void __launch_bounds__(512) k_knn(const float4* __restrict__ xyz4,
                                             int* __restrict__ idxb)
{
  __shared__ float sbd[KNS][KNQ][21];
  __shared__ float stau[KNQ];
  __shared__ int   scnt[KNQ];
  __shared__ int   stcnt[KNQ];
  __shared__ int   sties[KNQ * 16];
  int t = threadIdx.x;
  int q = t & 63, s = t >> 6;           // s wave-uniform
  int b = blockIdx.x >> 6;
  int n = ((blockIdx.x & 63) << 6) + q;
  const float4* pts = xyz4 + (size_t)b * NN;
  float4 me = pts[n];
  if (t < KNQ) { scnt[t] = 0; stcnt[t] = 0; }
  int m0 = s << 9;
  float bd[KK];
#pragma unroll
  for (int j = 0; j < KK; ++j) bd[j] = 3.4e38f;
  // phase 1: x4 batched, software-prefetched (wave-uniform -> wide s_load)
  float4 pc0 = pts[m0], pc1 = pts[m0 + 1], pc2 = pts[m0 + 2], pc3 = pts[m0 + 3];
#pragma unroll 1
  for (int m = m0; m < m0 + 512; m += 4) {
    float4 pn0 = pts[m + 4], pn1 = pts[m + 5], pn2 = pts[m + 6], pn3 = pts[m + 7];
    float d0 = pdist(me, pc0);
    float d1 = pdist(me, pc1);
    float d2 = pdist(me, pc2);
    float d3 = pdist(me, pc3);
#pragma unroll
    for (int j = KK - 1; j >= 1; --j)
      bd[j] = __builtin_amdgcn_fmed3f(d0, bd[j - 1], bd[j]);
    bd[0] = fminf(bd[0], d0);
#pragma unroll
    for (int j = KK - 1; j >= 1; --j)
      bd[j] = __builtin_amdgcn_fmed3f(d1, bd[j - 1], bd[j]);
    bd[0] = fminf(bd[0], d1);
#pragma unroll
    for (int j = KK - 1; j >= 1; --j)
      bd[j] = __builtin_amdgcn_fmed3f(d2, bd[j - 1], bd[j]);
    bd[0] = fminf(bd[0], d2);
#pragma unroll
    for (int j = KK - 1; j >= 1; --j)
      bd[j] = __builtin_amdgcn_fmed3f(d3, bd[j - 1], bd[j]);
    bd[0] = fminf(bd[0], d3);
    pc0 = pn0; pc1 = pn1; pc2 = pn2; pc3 = pn3;
  }
#pragma unroll
  for (int j = 0; j < KK; ++j) sbd[s][q][j] = bd[j];
  sbd[s][q][KK] = 3.4e38f;
  __syncthreads();
  if (t < KNQ) {
    int ia[KNS];
#pragma unroll
    for (int ss = 0; ss < KNS; ++ss) ia[ss] = 0;
    float tau = 0.f;
#pragma unroll 1
    for (int r = 0; r < KK; ++r) {
      float best = 3.5e38f; int bs = 0;
#pragma unroll
      for (int ss = 0; ss < KNS; ++ss) {
        float v = sbd[ss][t][ia[ss]];
        if (v < best) { best = v; bs = ss; }
      }
      ia[bs]++;
      tau = best;
    }
    stau[t] = tau;
  }
  __syncthreads();
  float tau = stau[q];
  size_t obase = ((size_t)b * NN + n) * KK;
#pragma unroll 2
  for (int m = m0; m < m0 + 512; ++m) {
    float4 p = pts[m];
    float d = pdist(me, p);
    if (d < tau) {
      int slot = atomicAdd(&scnt[q], 1);
      idxb[obase + slot] = m;
    } else if (d == tau) {
      int ts_ = atomicAdd(&stcnt[q], 1);
      if (ts_ < 16) sties[q * 16 + ts_] = m;
    }
  }
  __syncthreads();
  if (t < KNQ) {
    int c1 = scnt[t];
    int tc = min(stcnt[t], 16);
    int need = KK - c1;
    size_t ob = ((size_t)b * NN + (((blockIdx.x & 63) << 6) + t)) * KK;
    int last = -1;
#pragma unroll 1
    for (int r = 0; r < need; ++r) {
      int best = 0x7fffffff;
      for (int u = 0; u < tc; ++u) {
        int mv = sties[t * 16 + u];
        if (mv > last && mv < best) best = mv;
      }
      if (best == 0x7fffffff) best = 0;
      idxb[ob + c1 + r] = best;
      last = best;
    }
  }
}

__global__ void k_red1(const float* __restrict__ st1, const float* __restrict__ g1,
                       const float* __restrict__ b1, const float* __restrict__ gv,
                       const float* __restrict__ bv, float* __restrict__ par)
{
  int o = threadIdx.x;
  const float inv = 1.f / (float)ITEMS;
  if (o < 64) {
    float s = 0.f, s2 = 0.f;
    for (int j = 0; j < 64; ++j) { s += st1[j * 160 + o]; s2 += st1[j * 160 + 64 + o]; }
    float mu = s * inv, var = s2 * inv - mu * mu;
    float a = g1[o] * rsqrtf(var + EPSV);
    par[o] = a; par[64 + o] = b1[o] - mu * a;
  } else if (o < 80) {
    int v = o - 64;
    float s = 0.f, s2 = 0.f;
    for (int j = 0; j < 64; ++j) { s += st1[j * 160 + 128 + v]; s2 += st1[j * 160 + 144 + v]; }
    float mu = s * inv, var = s2 * inv - mu * mu;
    float a = gv[v] * rsqrtf(var + EPSV);
    par[128 + v] = a; par[144 + v] = bv[v] - mu * a;
  }
}

__global__ void k_red2(const float* __restrict__ st2, const float* __restrict__ g2,
                       const float* __restrict__ b2, float* __restrict__ par)
{
  int o = threadIdx.x; // 64
  float s = 0.f, s2 = 0.f;
  for (int j = 0; j < 64; ++j) { s += st2[j * 128 + o]; s2 += st2[j * 128 + 64 + o]; }
  const float inv = 1.f / (float)ITEMS;
  float mu = s * inv, var = s2 * inv - mu * mu;
  float a = g2[o] * rsqrtf(var + EPSV);
  par[160 + o] = a; par[224 + o] = b2[o] - mu * a;
}

// ---------- MFMA PATH ----------

// GEMM1: fcat[M=ITEMS x K=160(144)] @ W^T -> [t1:64 | tv:16 | ak:32], bf16 out,
// + BN1 stats for t1/tv. One wave = 16-item M-tile, 4 tiles/wave.
__global__ void __launch_bounds__(256, 2) k_g1(
    const float4* __restrict__ xyz4, const float* __restrict__ feat,
    const int* __restrict__ idxb, const float* __restrict__ W1,
    const float* __restrict__ Wv, const float* __restrict__ Wk,
    const float* __restrict__ Wh, float* __restrict__ st1,
    ushort_t* __restrict__ t1g, ushort_t* __restrict__ akg,
    ushort_t* __restrict__ tvg)
{
  __shared__ ushort_t lds[4][16][120];
  int tid = threadIdx.x;
  int w = tid >> 6, lane = tid & 63;
  int m = lane & 15, quad = lane >> 4;

  bf16x8 Bf[7][5];
#pragma unroll
  for (int nt = 0; nt < 7; ++nt) {
    const float* wrow = (nt < 4) ? (W1 + (nt * 16 + m) * CCAT)
                      : (nt == 4) ? (Wv + m * CCAT)
                      : (Wk + ((nt - 5) * 16 + m) * CCAT);
#pragma unroll
    for (int ks = 0; ks < 5; ++ks) {
      int c0 = ks * 32 + quad * 8;
      bf16x8 f;
      if (c0 < 144) {
        float4 u = *(const float4*)(wrow + c0);
        float4 v = *(const float4*)(wrow + c0 + 4);
        f[0] = (short)f2bf(u.x); f[1] = (short)f2bf(u.y);
        f[2] = (short)f2bf(u.z); f[3] = (short)f2bf(u.w);
        f[4] = (short)f2bf(v.x); f[5] = (short)f2bf(v.y);
        f[6] = (short)f2bf(v.z); f[7] = (short)f2bf(v.w);
      } else {
#pragma unroll
        for (int j = 0; j < 8; ++j) f[j] = 0;
      }
      Bf[nt][ks] = f;
    }
  }

  float ss[5], sq[5];
#pragma unroll
  for (int i = 0; i < 5; ++i) { ss[i] = 0.f; sq[i] = 0.f; }

#pragma unroll 1
  for (int t = 0; t < 4; ++t) {
    int tile = blockIdx.x * 16 + w * 4 + t;
    int item = tile * 16 + m;
    int bn = item / 20;
    int b = bn >> 12;
    int nb = idxb[item];
    const float* fme = feat + (size_t)bn * CFEAT;
    const float* fnb = feat + ((size_t)b * NN + nb) * CFEAT;
    float4 pm = xyz4[bn];
    float4 pn = xyz4[(size_t)b * NN + nb];
    float rx = pn.x - pm.x, ry = pn.y - pm.y, rz = pn.z - pm.z;

    f32x4 acc[7];
#pragma unroll
    for (int nt = 0; nt < 7; ++nt)
#pragma unroll
      for (int r = 0; r < 4; ++r) acc[nt][r] = 0.f;

#pragma unroll
    for (int ks = 0; ks < 5; ++ks) {
      int c0 = ks * 32 + quad * 8;
      bf16x8 A;
      if (c0 < 64) {
        float4 a0 = *(const float4*)(fnb + c0);
        float4 a1 = *(const float4*)(fnb + c0 + 4);
        float4 m0 = *(const float4*)(fme + c0);
        float4 m1 = *(const float4*)(fme + c0 + 4);
        A[0] = (short)f2bf(a0.x - m0.x); A[1] = (short)f2bf(a0.y - m0.y);
        A[2] = (short)f2bf(a0.z - m0.z); A[3] = (short)f2bf(a0.w - m0.w);
        A[4] = (short)f2bf(a1.x - m1.x); A[5] = (short)f2bf(a1.y - m1.y);
        A[6] = (short)f2bf(a1.z - m1.z); A[7] = (short)f2bf(a1.w - m1.w);
      } else if (c0 < 128) {
        int c = c0 - 64;
        float4 m0 = *(const float4*)(fme + c);
        float4 m1 = *(const float4*)(fme + c + 4);
        A[0] = (short)f2bf(m0.x); A[1] = (short)f2bf(m0.y);
        A[2] = (short)f2bf(m0.z); A[3] = (short)f2bf(m0.w);
        A[4] = (short)f2bf(m1.x); A[5] = (short)f2bf(m1.y);
        A[6] = (short)f2bf(m1.z); A[7] = (short)f2bf(m1.w);
      } else if (c0 < 144) {
        int v0 = c0 - 128;
#pragma unroll
        for (int j = 0; j < 8; ++j) {
          float pv = fmaf(Wh[(v0 + j) * 3], rx,
                     fmaf(Wh[(v0 + j) * 3 + 1], ry, Wh[(v0 + j) * 3 + 2] * rz));
          A[j] = (short)f2bf(pv);
        }
      } else {
#pragma unroll
        for (int j = 0; j < 8; ++j) A[j] = 0;
      }
#pragma unroll
      for (int nt = 0; nt < 7; ++nt)
        acc[nt] = __builtin_amdgcn_mfma_f32_16x16x32_bf16(A, Bf[nt][ks], acc[nt], 0, 0, 0);
    }

#pragma unroll
    for (int nt = 0; nt < 5; ++nt)
#pragma unroll
      for (int r = 0; r < 4; ++r) {
        float v = acc[nt][r];
        ss[nt] += v; sq[nt] += v * v;
      }

#pragma unroll
    for (int nt = 0; nt < 7; ++nt)
#pragma unroll
      for (int r = 0; r < 4; ++r)
        lds[w][quad * 4 + r][nt * 16 + m] = f2bf(acc[nt][r]);
    __syncthreads();

    {
      int it = lane >> 2, sg = lane & 3;
      const uint4* sp = (const uint4*)&lds[w][it][sg * 16];
      uint4 d0 = sp[0], d1 = sp[1];
      *(uint4*)(t1g + (size_t)tile * 1024 + lane * 16) = d0;
      *(uint4*)(t1g + (size_t)tile * 1024 + lane * 16 + 8) = d1;
      const uint4* spk = (const uint4*)&lds[w][it][80 + sg * 8];
      *(uint4*)(akg + (size_t)tile * 512 + lane * 8) = spk[0];
      if (lane < 32) {
        const uint4* spv = (const uint4*)&lds[w][lane >> 1][64 + (lane & 1) * 8];
        *(uint4*)(tvg + (size_t)tile * 256 + lane * 8) = spv[0];
      }
    }
    __syncthreads();
  }

  float* slot = st1 + (blockIdx.x & 63) * 160;
#pragma unroll
  for (int nt = 0; nt < 5; ++nt) {
    float s = ss[nt];
    s += __shfl_xor(s, 16); s += __shfl_xor(s, 32);
    float q = sq[nt];
    q += __shfl_xor(q, 16); q += __shfl_xor(q, 32);
    if (lane < 16) {
      if (nt < 4) {
        atomicAdd(&slot[nt * 16 + lane], s);
        atomicAdd(&slot[64 + nt * 16 + lane], q);
      } else {
        atomicAdd(&slot[128 + lane], s);
        atomicAdd(&slot[144 + lane], q);
      }
    }
  }
}

// GEMM2: t2 = W2 @ relu(bn1(t1)); per-bn max/min of t2 -> fqpre; BN2 stats
__global__ void __launch_bounds__(256) k_g2(
    const ushort_t* __restrict__ t1g, const float* __restrict__ W2,
    const float* __restrict__ par, float* __restrict__ st2,
    float* __restrict__ fqpre)
{
  __shared__ ushort_t lds[4][80][68];
  int tid = threadIdx.x;
  int w = tid >> 6, lane = tid & 63;
  int m = lane & 15, quad = lane >> 4;
  int gw = blockIdx.x * 4 + w;

  bf16x8 Bf[4][2];
#pragma unroll
  for (int nt = 0; nt < 4; ++nt) {
    const float* wrow = W2 + (nt * 16 + m) * CHN;
#pragma unroll
    for (int ks = 0; ks < 2; ++ks) {
      int c0 = ks * 32 + quad * 8;
      float4 u = *(const float4*)(wrow + c0);
      float4 v = *(const float4*)(wrow + c0 + 4);
      bf16x8 f;
      f[0] = (short)f2bf(u.x); f[1] = (short)f2bf(u.y);
      f[2] = (short)f2bf(u.z); f[3] = (short)f2bf(u.w);
      f[4] = (short)f2bf(v.x); f[5] = (short)f2bf(v.y);
      f[6] = (short)f2bf(v.z); f[7] = (short)f2bf(v.w);
      Bf[nt][ks] = f;
    }
  }
  float pa[2][8], pb[2][8];
#pragma unroll
  for (int ks = 0; ks < 2; ++ks) {
    int c0 = ks * 32 + quad * 8;
    float4 a0 = *(const float4*)(par + c0);
    float4 a1 = *(const float4*)(par + c0 + 4);
    float4 b0 = *(const float4*)(par + 64 + c0);
    float4 b1 = *(const float4*)(par + 64 + c0 + 4);
    pa[ks][0] = a0.x; pa[ks][1] = a0.y; pa[ks][2] = a0.z; pa[ks][3] = a0.w;
    pa[ks][4] = a1.x; pa[ks][5] = a1.y; pa[ks][6] = a1.z; pa[ks][7] = a1.w;
    pb[ks][0] = b0.x; pb[ks][1] = b0.y; pb[ks][2] = b0.z; pb[ks][3] = b0.w;
    pb[ks][4] = b1.x; pb[ks][5] = b1.y; pb[ks][6] = b1.z; pb[ks][7] = b1.w;
  }

  float ss[4] = {0.f, 0.f, 0.f, 0.f}, sq[4] = {0.f, 0.f, 0.f, 0.f};

#pragma unroll 1
  for (int t5 = 0; t5 < 5; ++t5) {
    int tile = gw * 5 + t5;
    int item = tile * 16 + m;
    f32x4 acc[4];
#pragma unroll
    for (int nt = 0; nt < 4; ++nt)
#pragma unroll
      for (int r = 0; r < 4; ++r) acc[nt][r] = 0.f;
#pragma unroll
    for (int ks = 0; ks < 2; ++ks) {
      const ushort_t* tp = t1g + (size_t)item * 64 + ks * 32 + quad * 8;
      uint4 raw = *(const uint4*)tp;
      unsigned rw[4] = {raw.x, raw.y, raw.z, raw.w};
      bf16x8 A;
#pragma unroll
      for (int i = 0; i < 4; ++i) {
        float lo = bf2f((ushort_t)(rw[i] & 0xffffu));
        float hi = bf2f((ushort_t)(rw[i] >> 16));
        float h0 = fmaxf(fmaf(lo, pa[ks][2 * i], pb[ks][2 * i]), 0.f);
        float h1 = fmaxf(fmaf(hi, pa[ks][2 * i + 1], pb[ks][2 * i + 1]), 0.f);
        A[2 * i] = (short)f2bf(h0);
        A[2 * i + 1] = (short)f2bf(h1);
      }
#pragma unroll
      for (int nt = 0; nt < 4; ++nt)
        acc[nt] = __builtin_amdgcn_mfma_f32_16x16x32_bf16(A, Bf[nt][ks], acc[nt], 0, 0, 0);
    }
#pragma unroll
    for (int nt = 0; nt < 4; ++nt)
#pragma unroll
      for (int r = 0; r < 4; ++r) {
        float v = acc[nt][r];
        ss[nt] += v; sq[nt] += v * v;
        lds[w][t5 * 16 + quad * 4 + r][nt * 16 + m] = f2bf(v);
      }
  }
  __syncthreads();

  {
    int bnl = lane >> 4;
    int chb = (lane & 15) * 4;
    float mx0 = -3.4e38f, mx1 = -3.4e38f, mx2 = -3.4e38f, mx3 = -3.4e38f;
    float mn0 = 3.4e38f, mn1 = 3.4e38f, mn2 = 3.4e38f, mn3 = 3.4e38f;
#pragma unroll
    for (int j = 0; j < KK; ++j) {
      const uint2 rv = *(const uint2*)&lds[w][bnl * 20 + j][chb];
      float v0 = bf2f((ushort_t)(rv.x & 0xffffu));
      float v1 = bf2f((ushort_t)(rv.x >> 16));
      float v2 = bf2f((ushort_t)(rv.y & 0xffffu));
      float v3 = bf2f((ushort_t)(rv.y >> 16));
      mx0 = fmaxf(mx0, v0); mn0 = fminf(mn0, v0);
      mx1 = fmaxf(mx1, v1); mn1 = fminf(mn1, v1);
      mx2 = fmaxf(mx2, v2); mn2 = fminf(mn2, v2);
      mx3 = fmaxf(mx3, v3); mn3 = fminf(mn3, v3);
    }
    int bn = gw * 4 + bnl;
    *(float4*)(fqpre + (size_t)bn * 128 + chb) = make_float4(mx0, mx1, mx2, mx3);
    *(float4*)(fqpre + (size_t)bn * 128 + 64 + chb) = make_float4(mn0, mn1, mn2, mn3);
  }

  float* slot = st2 + (blockIdx.x & 63) * 128;
#pragma unroll
  for (int nt = 0; nt < 4; ++nt) {
    float s = ss[nt];
    s += __shfl_xor(s, 16); s += __shfl_xor(s, 32);
    float q = sq[nt];
    q += __shfl_xor(q, 16); q += __shfl_xor(q, 32);
    if (lane < 16) {
      atomicAdd(&slot[nt * 16 + lane], s);
      atomicAdd(&slot[64 + nt * 16 + lane], q);
    }
  }
}

// softmax over k + kv from cached ak/tv
#define P3P 16
__global__ void __launch_bounds__(320, 2) k_p3s(
    const ushort_t* __restrict__ akg, const ushort_t* __restrict__ tvg,
    const float* __restrict__ par, __hip_bfloat16* __restrict__ kvg)
{
  __shared__ float sl[P3P][KK][DKK + 1];
  __shared__ float sv[P3P][KK][DVV + 1];
  __shared__ float sm[P3P][DKK], ssi[P3P][DKK];
  int tid = threadIdx.x;
  int p = tid / KK, k = tid - p * KK;
  size_t item = (size_t)(blockIdx.x * P3P + p) * KK + k;
  const unsigned* ap = (const unsigned*)(akg + item * DKK);
#pragma unroll
  for (int i = 0; i < DKK / 2; ++i) {
    unsigned wv = ap[i];
    sl[p][k][2 * i]     = __uint_as_float(wv << 16);
    sl[p][k][2 * i + 1] = __uint_as_float(wv & 0xffff0000u);
  }
  const unsigned* vp = (const unsigned*)(tvg + item * DVV);
#pragma unroll
  for (int i = 0; i < DVV / 2; ++i) {
    unsigned wv = vp[i];
    float lo = __uint_as_float(wv << 16);
    float hi = __uint_as_float(wv & 0xffff0000u);
    sv[p][k][2 * i]     = fmaf(lo, par[128 + 2 * i],     par[144 + 2 * i]);
    sv[p][k][2 * i + 1] = fmaf(hi, par[128 + 2 * i + 1], par[144 + 2 * i + 1]);
  }
  __syncthreads();
  for (int pd = tid; pd < P3P * DKK; pd += 320) {
    int pp = pd >> 5, d = pd & 31;
    float m = -1e30f;
#pragma unroll
    for (int q = 0; q < KK; ++q) m = fmaxf(m, sl[pp][q][d]);
    float S = 0.f;
#pragma unroll
    for (int q = 0; q < KK; ++q) S += __expf(sl[pp][q][d] - m);
    sm[pp][d] = m; ssi[pp][d] = 1.f / S;
  }
  __syncthreads();
  for (int pd = tid; pd < P3P * DKK; pd += 320) {
    int pp = pd >> 5, d = pd & 31;
    float m = sm[pp][d], Si = ssi[pp][d];
    float a[DVV];
#pragma unroll
    for (int v = 0; v < DVV; ++v) a[v] = 0.f;
#pragma unroll
    for (int q = 0; q < KK; ++q) {
      float wgt = __expf(sl[pp][q][d] - m) * Si;
#pragma unroll
      for (int v = 0; v < DVV; ++v) a[v] = fmaf(wgt, sv[pp][q][v], a[v]);
    }
    __hip_bfloat162* dst = (__hip_bfloat162*)
        (kvg + ((size_t)(blockIdx.x * P3P + pp) * DKK + d) * DVV);
#pragma unroll
    for (int v = 0; v < DVV; v += 2) {
      float2 f2; f2.x = a[v]; f2.y = a[v + 1];
      dst[v >> 1] = __float22bfloat162_rn(f2);
    }
  }
}

// MFMA GEMM: q2 = Wq @ fq, fq reconstructed inline from fqpre (sign-aware).
__global__ void __launch_bounds__(256) k_gq(
    const float* __restrict__ fqpre, const float* __restrict__ Wq,
    const float* __restrict__ par, float* __restrict__ stq,
    float* __restrict__ q2g)
{
  int tid = threadIdx.x;
  int w = tid >> 6, lane = tid & 63;
  int m = lane & 15, quad = lane >> 4;
  int nt0 = (w & 1) * 8;
  int mt = blockIdx.x * 2 + (w >> 1);

  bf16x8 Bf[8][2];
#pragma unroll
  for (int nt = 0; nt < 8; ++nt) {
    const float* wrow = Wq + ((nt0 + nt) * 16 + m) * CHN;
#pragma unroll
    for (int ks = 0; ks < 2; ++ks) {
      int c0 = ks * 32 + quad * 8;
      float4 u = *(const float4*)(wrow + c0);
      float4 v = *(const float4*)(wrow + c0 + 4);
      bf16x8 f;
      f[0] = (short)f2bf(u.x); f[1] = (short)f2bf(u.y);
      f[2] = (short)f2bf(u.z); f[3] = (short)f2bf(u.w);
      f[4] = (short)f2bf(v.x); f[5] = (short)f2bf(v.y);
      f[6] = (short)f2bf(v.z); f[7] = (short)f2bf(v.w);
      Bf[nt][ks] = f;
    }
  }

  f32x4 acc[8];
#pragma unroll
  for (int nt = 0; nt < 8; ++nt)
#pragma unroll
    for (int r = 0; r < 4; ++r) acc[nt][r] = 0.f;

  int item = mt * 16 + m;
  const float* fp = fqpre + (size_t)item * 128;
#pragma unroll
  for (int ks = 0; ks < 2; ++ks) {
    int c0 = ks * 32 + quad * 8;
    float mxv[8], mnv[8], av[8], bv[8];
    *(float4*)&mxv[0] = *(const float4*)(fp + c0);
    *(float4*)&mxv[4] = *(const float4*)(fp + c0 + 4);
    *(float4*)&mnv[0] = *(const float4*)(fp + 64 + c0);
    *(float4*)&mnv[4] = *(const float4*)(fp + 64 + c0 + 4);
    *(float4*)&av[0] = *(const float4*)(par + 160 + c0);
    *(float4*)&av[4] = *(const float4*)(par + 160 + c0 + 4);
    *(float4*)&bv[0] = *(const float4*)(par + 224 + c0);
    *(float4*)&bv[4] = *(const float4*)(par + 224 + c0 + 4);
    bf16x8 A;
#pragma unroll
    for (int j = 0; j < 8; ++j) {
      float pick = (av[j] >= 0.f) ? mxv[j] : mnv[j];
      float fq = fmaxf(fmaf(av[j], pick, bv[j]), 0.f);
      A[j] = (short)f2bf(fq);
    }
#pragma unroll
    for (int nt = 0; nt < 8; ++nt)
      acc[nt] = __builtin_amdgcn_mfma_f32_16x16x32_bf16(A, Bf[nt][ks], acc[nt], 0, 0, 0);
  }

  float* slot = stq + (blockIdx.x & 63) * 512;
#pragma unroll
  for (int nt = 0; nt < 8; ++nt) {
    int o = (nt0 + nt) * 16 + m;
    float s = 0.f, q = 0.f;
#pragma unroll
    for (int r = 0; r < 4; ++r) {
      float v = acc[nt][r];
      q2g[(size_t)(mt * 16 + quad * 4 + r) * NQC + o] = v;
      s += v; q += v * v;
    }
    s += __shfl_xor(s, 16); s += __shfl_xor(s, 32);
    q += __shfl_xor(q, 16); q += __shfl_xor(q, 32);
    if (lane < 16) {
      atomicAdd(&slot[(nt0 + nt) * 16 + lane], s);
      atomicAdd(&slot[256 + (nt0 + nt) * 16 + lane], q);
    }
  }
}

__global__ void k_redq(const float* __restrict__ stq, const float* __restrict__ gq,
                       const float* __restrict__ bq, float* __restrict__ par)
{
  int o = threadIdx.x; // 256
  float s = 0.f, s2 = 0.f;
  for (int j = 0; j < 64; ++j) { s += stq[j * 512 + o]; s2 += stq[j * 512 + 256 + o]; }
  const float inv = 1.f / (float)BNTOT;
  float mu = s * inv, var = s2 * inv - mu * mu;
  float a = gq[o] * rsqrtf(var + EPSV);
  par[288 + o] = a; par[544 + o] = bq[o] - mu * a;
}

// out[h*16+v] = sum_d relu(bnq(q2))[h*32+d] * kv[d][v] ; 4 bn per block
__global__ void __launch_bounds__(256) k_p4(const float* __restrict__ q2g,
                                            const __hip_bfloat16* __restrict__ kvg,
                                            const float* __restrict__ par,
                                            float* __restrict__ outp)
{
  __shared__ float sq2[4][NQC];
  __shared__ float skv[4][DKK * DVV];
  int t = threadIdx.x & 63, sub = threadIdx.x >> 6;
  int v = blockIdx.x * 4 + sub;
  int b = v & 7, n = v >> 3;
  int bn = (b << 12) | n;
#pragma unroll
  for (int j = 0; j < 8; ++j)
    skv[sub][t + 64 * j] = __bfloat162float(kvg[(size_t)bn * 512 + t + 64 * j]);
#pragma unroll
  for (int j = 0; j < 4; ++j) {
    int o = t + 64 * j;
    float q = q2g[(size_t)bn * NQC + o];
    sq2[sub][o] = fmaxf(fmaf(q, par[288 + o], par[544 + o]), 0.f);
  }
  __syncthreads();
#pragma unroll
  for (int j = 0; j < 2; ++j) {
    int ch = t + 64 * j, h = ch >> 4, vv = ch & 15;
    float a = 0.f;
#pragma unroll
    for (int d = 0; d < DKK; ++d) a = fmaf(sq2[sub][h * DKK + d], skv[sub][d * DVV + vv], a);
    outp[(size_t)BNTOT * 3 + ((size_t)(b * 128 + ch)) * NN + n] = a;
  }
}

// ---------- FALLBACK (round-5 proven path) ----------

__global__ void __launch_bounds__(256, 3) k_s1f(
    const float4* __restrict__ xyz4, const float* __restrict__ feat,
    const int* __restrict__ idxb, const float* __restrict__ W1,
    const float* __restrict__ Wv, const float* __restrict__ Wh,
    float* __restrict__ st1,
    __hip_bfloat16* __restrict__ t1g, __hip_bfloat16* __restrict__ tvg)
{
  int t = blockIdx.x * 256 + threadIdx.x;
  int bn = t / KK, k = t - bn * KK, b = bn >> 12;
  int nb = idxb[(size_t)bn * KK + k];
  const float* fme = feat + (size_t)bn * CFEAT;
  const float* fnb = feat + ((size_t)b * NN + nb) * CFEAT;
  float4 pn = xyz4[(size_t)b * NN + nb];
  float4 pm = xyz4[bn];
  float rx = pn.x - pm.x, ry = pn.y - pm.y, rz = pn.z - pm.z;
  float a1[CHN], av[DVV];
#pragma unroll
  for (int o = 0; o < CHN; ++o) a1[o] = 0.f;
#pragma unroll
  for (int o = 0; o < DVV; ++o) av[o] = 0.f;
#pragma unroll 1
  for (int ch = 0; ch < 9; ++ch) {
    float fc[16];
    build_chunk(ch, fme, fnb, rx, ry, rz, Wh, fc);
    accum_chunk<CHN>(W1, ch, fc, a1);
    accum_chunk<DVV>(Wv, ch, fc, av);
  }
  __hip_bfloat162* t1p = (__hip_bfloat162*)(t1g + (size_t)t * CHN);
#pragma unroll
  for (int o = 0; o < CHN; o += 2) {
    float2 f2; f2.x = a1[o]; f2.y = a1[o + 1];
    t1p[o >> 1] = __float22bfloat162_rn(f2);
  }
  __hip_bfloat162* tvp = (__hip_bfloat162*)(tvg + (size_t)t * DVV);
#pragma unroll
  for (int o = 0; o < DVV; o += 2) {
    float2 f2; f2.x = av[o]; f2.y = av[o + 1];
    tvp[o >> 1] = __float22bfloat162_rn(f2);
  }
  float* slot = st1 + (blockIdx.x & 63) * 160;
  int lane = threadIdx.x & 63;
#pragma unroll
  for (int o = 0; o < CHN; ++o) {
    float s = wred(a1[o]), s2 = wred(a1[o] * a1[o]);
    if (lane == 0) { atomicAdd(&slot[o], s); atomicAdd(&slot[CHN + o], s2); }
  }
#pragma unroll
  for (int o = 0; o < DVV; ++o) {
    float s = wred(av[o]), s2 = wred(av[o] * av[o]);
    if (lane == 0) { atomicAdd(&slot[128 + o], s); atomicAdd(&slot[128 + DVV + o], s2); }
  }
}

__global__ void __launch_bounds__(256, 4) k_skf(
    const float4* __restrict__ xyz4, const float* __restrict__ feat,
    const int* __restrict__ idxb, const float* __restrict__ Wk,
    const float* __restrict__ Wh, __hip_bfloat16* __restrict__ akg)
{
  int t = blockIdx.x * 256 + threadIdx.x;
  int bn = t / KK, k = t - bn * KK, b = bn >> 12;
  int nb = idxb[(size_t)bn * KK + k];
  const float* fme = feat + (size_t)bn * CFEAT;
  const float* fnb = feat + ((size_t)b * NN + nb) * CFEAT;
  float4 pn = xyz4[(size_t)b * NN + nb];
  float4 pm = xyz4[bn];
  float rx = pn.x - pm.x, ry = pn.y - pm.y, rz = pn.z - pm.z;
  float ak[DKK];
#pragma unroll
  for (int o = 0; o < DKK; ++o) ak[o] = 0.f;
#pragma unroll 1
  for (int ch = 0; ch < 9; ++ch) {
    float fc[16];
    build_chunk(ch, fme, fnb, rx, ry, rz, Wh, fc);
    accum_chunk<DKK>(Wk, ch, fc, ak);
  }
  __hip_bfloat162* akp = (__hip_bfloat162*)(akg + (size_t)t * DKK);
#pragma unroll
  for (int o = 0; o < DKK; o += 2) {
    float2 f2; f2.x = ak[o]; f2.y = ak[o + 1];
    akp[o >> 1] = __float22bfloat162_rn(f2);
  }
}

__global__ void __launch_bounds__(256, 4) k_s2f(
    const __hip_bfloat16* __restrict__ t1g, const float* __restrict__ W2,
    const float* __restrict__ par, float* __restrict__ st2)
{
  int t = blockIdx.x * 256 + threadIdx.x;
  const unsigned* tp = (const unsigned*)(t1g + (size_t)t * CHN);
  float h1[CHN];
#pragma unroll
  for (int i = 0; i < CHN / 2; ++i) {
    unsigned w = tp[i];
    float lo = __uint_as_float(w << 16);
    float hi = __uint_as_float(w & 0xffff0000u);
    h1[2 * i]     = fmaxf(fmaf(lo, par[2 * i],     par[64 + 2 * i]),     0.f);
    h1[2 * i + 1] = fmaxf(fmaf(hi, par[2 * i + 1], par[64 + 2 * i + 1]), 0.f);
  }
  float* slot = st2 + (blockIdx.x & 63) * 128;
  int lane = threadIdx.x & 63;
#pragma unroll 1
  for (int o = 0; o < CHN; ++o) {
    const float* w = W2 + o * CHN;
    float c0 = 0.f, c1 = 0.f, c2 = 0.f, c3 = 0.f;
#pragma unroll
    for (int c = 0; c < CHN; c += 4) {
      c0 = fmaf(w[c + 0], h1[c + 0], c0); c1 = fmaf(w[c + 1], h1[c + 1], c1);
      c2 = fmaf(w[c + 2], h1[c + 2], c2); c3 = fmaf(w[c + 3], h1[c + 3], c3);
    }
    float v = (c0 + c1) + (c2 + c3);
    float s = wred(v), s2 = wred(v * v);
    if (lane == 0) { atomicAdd(&slot[o], s); atomicAdd(&slot[64 + o], s2); }
  }
}

__global__ void __launch_bounds__(320, 2) k_p3f(
    const __hip_bfloat16* __restrict__ t1g, const __hip_bfloat16* __restrict__ akg,
    const __hip_bfloat16* __restrict__ tvg, const float* __restrict__ W2,
    const float* __restrict__ par, float* __restrict__ fqg,
    __hip_bfloat16* __restrict__ kvg)
{
  __shared__ float sl[P3P][KK][DKK + 1];
  __shared__ float sv[P3P][KK][DVV + 1];
  __shared__ unsigned sfq[P3P][CHN];
  __shared__ float sm[P3P][DKK], ssi[P3P][DKK];
  int tid = threadIdx.x;
  for (int i = tid; i < P3P * CHN; i += 320) ((unsigned*)sfq)[i] = 0u;
  __syncthreads();
  int p = tid / KK, k = tid - p * KK;
  size_t item = (size_t)(blockIdx.x * P3P + p) * KK + k;
  const unsigned* ap = (const unsigned*)(akg + item * DKK);
#pragma unroll
  for (int i = 0; i < DKK / 2; ++i) {
    unsigned w = ap[i];
    sl[p][k][2 * i]     = __uint_as_float(w << 16);
    sl[p][k][2 * i + 1] = __uint_as_float(w & 0xffff0000u);
  }
  const unsigned* vp = (const unsigned*)(tvg + item * DVV);
#pragma unroll
  for (int i = 0; i < DVV / 2; ++i) {
    unsigned w = vp[i];
    float lo = __uint_as_float(w << 16);
    float hi = __uint_as_float(w & 0xffff0000u);
    sv[p][k][2 * i]     = fmaf(lo, par[128 + 2 * i],     par[144 + 2 * i]);
    sv[p][k][2 * i + 1] = fmaf(hi, par[128 + 2 * i + 1], par[144 + 2 * i + 1]);
  }
  const unsigned* tp = (const unsigned*)(t1g + item * CHN);
  float h1[CHN];
#pragma unroll
  for (int i = 0; i < CHN / 2; ++i) {
    unsigned w = tp[i];
    float lo = __uint_as_float(w << 16);
    float hi = __uint_as_float(w & 0xffff0000u);
    h1[2 * i]     = fmaxf(fmaf(lo, par[2 * i],     par[64 + 2 * i]),     0.f);
    h1[2 * i + 1] = fmaxf(fmaf(hi, par[2 * i + 1], par[64 + 2 * i + 1]), 0.f);
  }
#pragma unroll 1
  for (int o = 0; o < CHN; ++o) {
    const float* w = W2 + o * CHN;
    float c0 = 0.f, c1 = 0.f, c2 = 0.f, c3 = 0.f;
#pragma unroll
    for (int c = 0; c < CHN; c += 4) {
      c0 = fmaf(w[c + 0], h1[c + 0], c0); c1 = fmaf(w[c + 1], h1[c + 1], c1);
      c2 = fmaf(w[c + 2], h1[c + 2], c2); c3 = fmaf(w[c + 3], h1[c + 3], c3);
    }
    float v = (c0 + c1) + (c2 + c3);
    float h2 = fmaxf(fmaf(v, par[160 + o], par[224 + o]), 0.f);
    atomicMax(&sfq[p][o], __float_as_uint(h2));
  }
  __syncthreads();
  for (int i = tid; i < P3P * CHN; i += 320)
    fqg[(size_t)blockIdx.x * (P3P * CHN) + i] = __uint_as_float(sfq[i >> 6][i & 63]);
  for (int pd = tid; pd < P3P * DKK; pd += 320) {
    int pp = pd >> 5, d = pd & 31;
    float m = -1e30f;
#pragma unroll
    for (int q = 0; q < KK; ++q) m = fmaxf(m, sl[pp][q][d]);
    float S = 0.f;
#pragma unroll
    for (int q = 0; q < KK; ++q) S += __expf(sl[pp][q][d] - m);
    sm[pp][d] = m; ssi[pp][d] = 1.f / S;
  }
  __syncthreads();
  for (int pd = tid; pd < P3P * DKK; pd += 320) {
    int pp = pd >> 5, d = pd & 31;
    float m = sm[pp][d], Si = ssi[pp][d];
    float a[DVV];
#pragma unroll
    for (int v = 0; v < DVV; ++v) a[v] = 0.f;
#pragma unroll
    for (int q = 0; q < KK; ++q) {
      float wgt = __expf(sl[pp][q][d] - m) * Si;
#pragma unroll
      for (int v = 0; v < DVV; ++v) a[v] = fmaf(wgt, sv[pp][q][v], a[v]);
    }
    __hip_bfloat162* dst = (__hip_bfloat162*)
        (kvg + ((size_t)(blockIdx.x * P3P + pp) * DKK + d) * DVV);
#pragma unroll
    for (int v = 0; v < DVV; v += 2) {
      float2 f2; f2.x = a[v]; f2.y = a[v + 1];
      dst[v >> 1] = __float22bfloat162_rn(f2);
    }
  }
}

__global__ void __launch_bounds__(128, 2) k_pqf(const float* __restrict__ fqg,
                                                const float* __restrict__ Wq,
                                                float* __restrict__ stq,
                                                float* __restrict__ q2g)
{
  int bn = blockIdx.x * 128 + threadIdx.x;
  float fq[CHN];
#pragma unroll
  for (int c = 0; c < CHN; c += 4) {
    float4 v4 = *(const float4*)(fqg + (size_t)bn * CHN + c);
    fq[c] = v4.x; fq[c + 1] = v4.y; fq[c + 2] = v4.z; fq[c + 3] = v4.w;
  }
  float* slot = stq + (blockIdx.x & 63) * 512;
  int lane = threadIdx.x & 63;
#pragma unroll 1
  for (int o = 0; o < NQC; ++o) {
    const float* w = Wq + o * CHN;
    float a0 = 0.f, a1 = 0.f, a2 = 0.f, a3 = 0.f;
#pragma unroll
    for (int c = 0; c < CHN; c += 4) {
      a0 = fmaf(w[c], fq[c], a0); a1 = fmaf(w[c + 1], fq[c + 1], a1);
      a2 = fmaf(w[c + 2], fq[c + 2], a2); a3 = fmaf(w[c + 3], fq[c + 3], a3);
    }
    float v = (a0 + a1) + (a2 + a3);
    q2g[(size_t)bn * NQC + o] = v;
    float s = wred(v), s2 = wred(v * v);
    if (lane == 0) { atomicAdd(&slot[o], s); atomicAdd(&slot[256 + o], s2); }
  }
}

__global__ void __launch_bounds__(64) k_p4f(const float* __restrict__ q2g,
                                            const __hip_bfloat16* __restrict__ kvg,
                                            const float* __restrict__ par,
                                            float* __restrict__ outp)
{
  __shared__ float sq2[NQC], skv[DKK * DVV];
  int t = threadIdx.x;
  int b = blockIdx.x & 7, n = blockIdx.x >> 3;
  int bn = (b << 12) | n;
#pragma unroll
  for (int j = 0; j < 8; ++j)
    skv[t + 64 * j] = __bfloat162float(kvg[(size_t)bn * 512 + t + 64 * j]);
#pragma unroll
  for (int j = 0; j < 4; ++j) {
    int o = t + 64 * j;
    float v = q2g[(size_t)bn * NQC + o];
    sq2[o] = fmaxf(fmaf(v, par[288 + o], par[544 + o]), 0.f);
  }
  __syncthreads();
#pragma unroll
  for (int j = 0; j < 2; ++j) {
    int ch = t + 64 * j, h = ch >> 4, vv = ch & 15;
    float a = 0.f;
#pragma unroll
    for (int d = 0; d < DKK; ++d) a = fmaf(sq2[h * DKK + d], skv[d * DVV + vv], a);
    outp[(size_t)BNTOT * 3 + ((size_t)(b * 128 + ch)) * NN + n] = a;
  }
}

// ---------- launch ----------

extern "C" void kernel_launch(void* const* d_in, const int* in_sizes, int n_in,
                              void* d_out, int out_size, void* d_ws, size_t ws_size,
                              hipStream_t stream)
{
  const float* x  = (const float*)d_in[0];
  const float* W1 = (const float*)d_in[1];
  const float* g1 = (const float*)d_in[2];
  const float* b1 = (const float*)d_in[3];
  const float* W2 = (const float*)d_in[4];
  const float* g2 = (const float*)d_in[5];
  const float* b2 = (const float*)d_in[6];
  const float* Wv = (const float*)d_in[7];
  const float* gv = (const float*)d_in[8];
  const float* bv = (const float*)d_in[9];
  const float* Wk = (const float*)d_in[10];
  const float* Wq = (const float*)d_in[11];
  const float* gq = (const float*)d_in[12];
  const float* bq = (const float*)d_in[13];
  const float* Wh = (const float*)d_in[14];

  float* ws = (float*)d_ws;
  float4* xyz4 = (float4*)ws;                      // 131072
  float*  feat = ws + 131072;                      // 2097152
  int*    idxb = (int*)(ws + 2228224);             // 655360
  float*  st1  = ws + 2883584;                     // 10240
  float*  st2  = ws + 2893824;                     // 8192
  float*  stq  = ws + 2902016;                     // 32768
  float*  par  = ws + 2934784;                     // 800
  float*  fqg  = ws + 2935584;                     // 2097152
  __hip_bfloat16* kvg = (__hip_bfloat16*)(ws + 5032736);  // 8388608 fw
  float*  outp = (float*)d_out;

  ushort_t* t1g = (ushort_t*)(ws + 13421344);      // 20971520 fw
  ushort_t* akg = (ushort_t*)(ws + 34392864);      // 10485760 fw
  ushort_t* tvg = (ushort_t*)(ws + 44878624);      //  5242880 fw
  float*    fqpre = ws + 50121504;                 //  4194304 fw
  float*    q2g = ws + 13421344;                   // alias t1g (dead after k_g2)

  const size_t NEW_NEED  = (size_t)54315808 * 4;   // ~217.3 MB (MFMA path)

  hipMemsetAsync(st1, 0, (size_t)(10240 + 8192 + 32768) * sizeof(float), stream);
  k_prep<<<128, 256, 0, stream>>>(x, xyz4, feat, outp);
  k_knn <<<512, 512, 0, stream>>>(xyz4, idxb);

  if (ws_size >= NEW_NEED) {
    k_g1  <<<2560, 256, 0, stream>>>(xyz4, feat, idxb, W1, Wv, Wk, Wh, st1, t1g, akg, tvg);
    k_red1<<<1, 128, 0, stream>>>(st1, g1, b1, gv, bv, par);
    k_g2  <<<2048, 256, 0, stream>>>(t1g, W2, par, st2, fqpre);
    k_red2<<<1, 64, 0, stream>>>(st2, g2, b2, par);
    k_p3s <<<2048, 320, 0, stream>>>(akg, tvg, par, kvg);
    k_gq  <<<1024, 256, 0, stream>>>(fqpre, Wq, par, stq, q2g);
    k_redq<<<1, 256, 0, stream>>>(stq, gq, bq, par);
    k_p4  <<<8192, 256, 0, stream>>>(q2g, kvg, par, outp);
  } else {
    __hip_bfloat16* t1b = (__hip_bfloat16*)t1g;
    __hip_bfloat16* akb = (__hip_bfloat16*)akg;
    __hip_bfloat16* tvb = (__hip_bfloat16*)tvg;
    float* q2f = ws + 34392864;                    // alias akg region
    k_s1f <<<2560, 256, 0, stream>>>(xyz4, feat, idxb, W1, Wv, Wh, st1, t1b, tvb);
    k_skf <<<2560, 256, 0, stream>>>(xyz4, feat, idxb, Wk, Wh, akb);
    k_red1<<<1, 128, 0, stream>>>(st1, g1, b1, gv, bv, par);
    k_s2f <<<2560, 256, 0, stream>>>(t1b, W2, par, st2);
    k_red2<<<1, 64, 0, stream>>>(st2, g2, b2, par);
    k_p3f <<<2048, 320, 0, stream>>>(t1b, akb, tvb, W2, par, fqg, kvg);
    k_pqf <<<256, 128, 0, stream>>>(fqg, Wq, stq, q2f);
    k_redq<<<1, 256, 0, stream>>>(stq, gq, bq, par);
    k_p4f <<<32768, 64, 0, stream>>>(q2f, kvg, par, outp);
  }
}

// Round 9
// 573.617 us; speedup vs baseline: 9.6822x; 1.0516x over previous
//
#include <hip/hip_runtime.h>
#include <hip/hip_bf16.h>

#define NB 8
#define NN 4096
#define KK 20
#define CFEAT 64
#define CCAT 144
#define CHN 64
#define NHEAD 8
#define DKK 32
#define DVV 16
#define NQC 256
#define EPSV 1e-5f
#define BNTOT (NB*NN)      /* 32768 */
#define ITEMS (BNTOT*KK)   /* 655360 */

typedef unsigned short ushort_t;
typedef __attribute__((ext_vector_type(8))) short bf16x8;
typedef __attribute__((ext_vector_type(4))) float f32x4;

// ---------- helpers ----------

__device__ __forceinline__ float wred(float v) {
#pragma unroll
  for (int off = 32; off > 0; off >>= 1) v += __shfl_down(v, off);
  return v;
}

__device__ __forceinline__ ushort_t f2bf(float f) {
  unsigned u = __float_as_uint(f);
  return (ushort_t)((u + 0x7fffu + ((u >> 16) & 1u)) >> 16);
}
__device__ __forceinline__ float bf2f(ushort_t h) {
  return __uint_as_float(((unsigned)h) << 16);
}

// identical in phase1/phase2 so d is bit-identical
__device__ __forceinline__ float pdist(float4 me, float4 p) {
  float dot = fmaf(me.x, p.x, fmaf(me.y, p.y, me.z * p.z));
  return fmaf(-2.f, dot, me.w + p.w);
}

__device__ __forceinline__ void insert20(float* bd, float d) {
#pragma unroll
  for (int j = KK - 1; j >= 1; --j)
    bd[j] = __builtin_amdgcn_fmed3f(d, bd[j - 1], bd[j]);
  bd[0] = fminf(bd[0], d);
}

// build 16 channels of fcat (fallback path)
__device__ __forceinline__ void build_chunk(int ch,
    const float* __restrict__ fme, const float* __restrict__ fnb,
    float rx, float ry, float rz, const float* __restrict__ Wh, float* fc)
{
  if (ch < 4) {
    int c0 = ch * 16;
#pragma unroll
    for (int j = 0; j < 16; j += 4) {
      float4 a = *(const float4*)(fnb + c0 + j);
      float4 m = *(const float4*)(fme + c0 + j);
      fc[j + 0] = a.x - m.x; fc[j + 1] = a.y - m.y;
      fc[j + 2] = a.z - m.z; fc[j + 3] = a.w - m.w;
    }
  } else if (ch < 8) {
    int c0 = (ch - 4) * 16;
#pragma unroll
    for (int j = 0; j < 16; j += 4) {
      float4 m = *(const float4*)(fme + c0 + j);
      fc[j + 0] = m.x; fc[j + 1] = m.y; fc[j + 2] = m.z; fc[j + 3] = m.w;
    }
  } else {
#pragma unroll
    for (int v = 0; v < 16; ++v)
      fc[v] = fmaf(Wh[v * 3], rx, fmaf(Wh[v * 3 + 1], ry, Wh[v * 3 + 2] * rz));
  }
}

template<int NO>
__device__ __forceinline__ void accum_chunk(const float* __restrict__ W, int ch,
                                            const float* fc, float* acc)
{
  const float* wb = W + ch * 16;
#pragma unroll
  for (int o = 0; o < NO; ++o) {
    const float* w = wb + o * CCAT;
#pragma unroll
    for (int j = 0; j < 16; ++j) acc[o] = fmaf(w[j], fc[j], acc[o]);
  }
}

// ---------- shared kernels ----------

// fully-coalesced prep via LDS staging: block = 256 points
__global__ void __launch_bounds__(256) k_prep(const float* __restrict__ x,
                                              float4* __restrict__ xyz4,
                                              float* __restrict__ feat,
                                              float* __restrict__ outp)
{
  __shared__ float lx[256 * 67];        // 68608 B
  int t = threadIdx.x;
  size_t base = (size_t)blockIdx.x * 256;
  const float* xb = x + base * 67;
#pragma unroll 4
  for (int j = t; j < 256 * 67; j += 256) lx[j] = xb[j];
  __syncthreads();
  {
    float a = lx[t * 67], b = lx[t * 67 + 1], c = lx[t * 67 + 2];
    xyz4[base + t] = make_float4(a, b, c, a * a + b * b + c * c);
  }
#pragma unroll
  for (int r = 0; r < 3; ++r) {
    int j = r * 256 + t;
    outp[base * 3 + j] = lx[(j / 3) * 67 + (j % 3)];
  }
#pragma unroll 8
  for (int j = t; j < 256 * 64; j += 256)
    feat[base * 64 + j] = lx[(j >> 6) * 67 + 3 + (j & 63)];
}

// exact K=20 NN. Block = 64 queries x 12 segments (768 thr = 12 waves;
// 2 blocks/CU -> 24 waves/CU). Wave-uniform segment -> scalar point loads.
#define KNQ 64
#define KNS 12
__global__ void __launch_bounds__(768) k_knn(const float4* __restrict__ xyz4,
                                             int* __restrict__ idxb)
{
  __shared__ float sbd[KNS][KNQ][21];   // 64.5 KB; pad 21 + sentinel
  __shared__ float stau[KNQ];
  __shared__ int   scnt[KNQ];
  __shared__ int   stcnt[KNQ];
  __shared__ int   sties[KNQ * 16];
  int t = threadIdx.x;
  int q = t & 63, s = t >> 6;           // s wave-uniform (0..11)
  int b = blockIdx.x >> 6;
  int n = ((blockIdx.x & 63) << 6) + q;
  const float4* pts = xyz4 + (size_t)b * NN;
  float4 me = pts[n];
  if (t < KNQ) { scnt[t] = 0; stcnt[t] = 0; }
  int m_lo = (s * NN) / KNS;
  int m_hi = ((s + 1) * NN) / KNS;
  int m4e = m_lo + ((m_hi - m_lo) & ~3);
  float bd[KK];
#pragma unroll
  for (int j = 0; j < KK; ++j) bd[j] = 3.4e38f;
  // phase 1: x4 batched, software-prefetched (wave-uniform -> wide s_load)
  float4 pc0 = pts[m_lo], pc1 = pts[m_lo + 1], pc2 = pts[m_lo + 2], pc3 = pts[m_lo + 3];
#pragma unroll 1
  for (int m = m_lo; m < m4e; m += 4) {
    float4 pn0 = pts[m + 4], pn1 = pts[m + 5], pn2 = pts[m + 6], pn3 = pts[m + 7];
    float d0 = pdist(me, pc0);
    float d1 = pdist(me, pc1);
    float d2 = pdist(me, pc2);
    float d3 = pdist(me, pc3);
    insert20(bd, d0);
    insert20(bd, d1);
    insert20(bd, d2);
    insert20(bd, d3);
    pc0 = pn0; pc1 = pn1; pc2 = pn2; pc3 = pn3;
  }
#pragma unroll 1
  for (int m = m4e; m < m_hi; ++m) {    // tail (<=3 points)
    float d = pdist(me, pts[m]);
    insert20(bd, d);
  }
#pragma unroll
  for (int j = 0; j < KK; ++j) sbd[s][q][j] = bd[j];
  sbd[s][q][KK] = 3.4e38f;              // sentinel
  __syncthreads();
  if (t < KNQ) {
    int ia[KNS];
#pragma unroll
    for (int ss = 0; ss < KNS; ++ss) ia[ss] = 0;
    float tau = 0.f;
#pragma unroll 1
    for (int r = 0; r < KK; ++r) {
      float best = 3.5e38f; int bs = 0;
#pragma unroll
      for (int ss = 0; ss < KNS; ++ss) {
        float v = sbd[ss][t][ia[ss]];
        if (v < best) { best = v; bs = ss; }
      }
      ia[bs]++;
      tau = best;
    }
    stau[t] = tau;
  }
  __syncthreads();
  float tau = stau[q];
  size_t obase = ((size_t)b * NN + n) * KK;
#pragma unroll 2
  for (int m = m_lo; m < m_hi; ++m) {
    float4 p = pts[m];
    float d = pdist(me, p);
    if (d < tau) {
      int slot = atomicAdd(&scnt[q], 1);
      idxb[obase + slot] = m;
    } else if (d == tau) {
      int ts_ = atomicAdd(&stcnt[q], 1);
      if (ts_ < 16) sties[q * 16 + ts_] = m;
    }
  }
  __syncthreads();
  if (t < KNQ) {
    int c1 = scnt[t];
    int tc = min(stcnt[t], 16);
    int need = KK - c1;
    size_t ob = ((size_t)b * NN + (((blockIdx.x & 63) << 6) + t)) * KK;
    int last = -1;
#pragma unroll 1
    for (int r = 0; r < need; ++r) {
      int best = 0x7fffffff;
      for (int u = 0; u < tc; ++u) {
        int mv = sties[t * 16 + u];
        if (mv > last && mv < best) best = mv;
      }
      if (best == 0x7fffffff) best = 0;
      idxb[ob + c1 + r] = best;
      last = best;
    }
  }
}

__global__ void k_red1(const float* __restrict__ st1, const float* __restrict__ g1,
                       const float* __restrict__ b1, const float* __restrict__ gv,
                       const float* __restrict__ bv, float* __restrict__ par)
{
  int o = threadIdx.x;
  const float inv = 1.f / (float)ITEMS;
  if (o < 64) {
    float s = 0.f, s2 = 0.f;
    for (int j = 0; j < 64; ++j) { s += st1[j * 160 + o]; s2 += st1[j * 160 + 64 + o]; }
    float mu = s * inv, var = s2 * inv - mu * mu;
    float a = g1[o] * rsqrtf(var + EPSV);
    par[o] = a; par[64 + o] = b1[o] - mu * a;
  } else if (o < 80) {
    int v = o - 64;
    float s = 0.f, s2 = 0.f;
    for (int j = 0; j < 64; ++j) { s += st1[j * 160 + 128 + v]; s2 += st1[j * 160 + 144 + v]; }
    float mu = s * inv, var = s2 * inv - mu * mu;
    float a = gv[v] * rsqrtf(var + EPSV);
    par[128 + v] = a; par[144 + v] = bv[v] - mu * a;
  }
}

__global__ void k_red2(const float* __restrict__ st2, const float* __restrict__ g2,
                       const float* __restrict__ b2, float* __restrict__ par)
{
  int o = threadIdx.x; // 64
  float s = 0.f, s2 = 0.f;
  for (int j = 0; j < 64; ++j) { s += st2[j * 128 + o]; s2 += st2[j * 128 + 64 + o]; }
  const float inv = 1.f / (float)ITEMS;
  float mu = s * inv, var = s2 * inv - mu * mu;
  float a = g2[o] * rsqrtf(var + EPSV);
  par[160 + o] = a; par[224 + o] = b2[o] - mu * a;
}

// ---------- MFMA PATH ----------

// GEMM1: fcat[M=ITEMS x K=160(144)] @ W^T -> [t1:64 | tv:16 | ak:32], bf16 out,
// + BN1 stats for t1/tv. One wave = 16-item M-tile, 4 tiles/wave.
__global__ void __launch_bounds__(256, 2) k_g1(
    const float4* __restrict__ xyz4, const float* __restrict__ feat,
    const int* __restrict__ idxb, const float* __restrict__ W1,
    const float* __restrict__ Wv, const float* __restrict__ Wk,
    const float* __restrict__ Wh, float* __restrict__ st1,
    ushort_t* __restrict__ t1g, ushort_t* __restrict__ akg,
    ushort_t* __restrict__ tvg)
{
  __shared__ ushort_t lds[4][16][120];
  int tid = threadIdx.x;
  int w = tid >> 6, lane = tid & 63;
  int m = lane & 15, quad = lane >> 4;

  bf16x8 Bf[7][5];
#pragma unroll
  for (int nt = 0; nt < 7; ++nt) {
    const float* wrow = (nt < 4) ? (W1 + (nt * 16 + m) * CCAT)
                      : (nt == 4) ? (Wv + m * CCAT)
                      : (Wk + ((nt - 5) * 16 + m) * CCAT);
#pragma unroll
    for (int ks = 0; ks < 5; ++ks) {
      int c0 = ks * 32 + quad * 8;
      bf16x8 f;
      if (c0 < 144) {
        float4 u = *(const float4*)(wrow + c0);
        float4 v = *(const float4*)(wrow + c0 + 4);
        f[0] = (short)f2bf(u.x); f[1] = (short)f2bf(u.y);
        f[2] = (short)f2bf(u.z); f[3] = (short)f2bf(u.w);
        f[4] = (short)f2bf(v.x); f[5] = (short)f2bf(v.y);
        f[6] = (short)f2bf(v.z); f[7] = (short)f2bf(v.w);
      } else {
#pragma unroll
        for (int j = 0; j < 8; ++j) f[j] = 0;
      }
      Bf[nt][ks] = f;
    }
  }

  float ss[5], sq[5];
#pragma unroll
  for (int i = 0; i < 5; ++i) { ss[i] = 0.f; sq[i] = 0.f; }

#pragma unroll 1
  for (int t = 0; t < 4; ++t) {
    int tile = blockIdx.x * 16 + w * 4 + t;
    int item = tile * 16 + m;
    int bn = item / 20;
    int b = bn >> 12;
    int nb = idxb[item];
    const float* fme = feat + (size_t)bn * CFEAT;
    const float* fnb = feat + ((size_t)b * NN + nb) * CFEAT;
    float4 pm = xyz4[bn];
    float4 pn = xyz4[(size_t)b * NN + nb];
    float rx = pn.x - pm.x, ry = pn.y - pm.y, rz = pn.z - pm.z;

    f32x4 acc[7];
#pragma unroll
    for (int nt = 0; nt < 7; ++nt)
#pragma unroll
      for (int r = 0; r < 4; ++r) acc[nt][r] = 0.f;

#pragma unroll
    for (int ks = 0; ks < 5; ++ks) {
      int c0 = ks * 32 + quad * 8;
      bf16x8 A;
      if (c0 < 64) {
        float4 a0 = *(const float4*)(fnb + c0);
        float4 a1 = *(const float4*)(fnb + c0 + 4);
        float4 m0 = *(const float4*)(fme + c0);
        float4 m1 = *(const float4*)(fme + c0 + 4);
        A[0] = (short)f2bf(a0.x - m0.x); A[1] = (short)f2bf(a0.y - m0.y);
        A[2] = (short)f2bf(a0.z - m0.z); A[3] = (short)f2bf(a0.w - m0.w);
        A[4] = (short)f2bf(a1.x - m1.x); A[5] = (short)f2bf(a1.y - m1.y);
        A[6] = (short)f2bf(a1.z - m1.z); A[7] = (short)f2bf(a1.w - m1.w);
      } else if (c0 < 128) {
        int c = c0 - 64;
        float4 m0 = *(const float4*)(fme + c);
        float4 m1 = *(const float4*)(fme + c + 4);
        A[0] = (short)f2bf(m0.x); A[1] = (short)f2bf(m0.y);
        A[2] = (short)f2bf(m0.z); A[3] = (short)f2bf(m0.w);
        A[4] = (short)f2bf(m1.x); A[5] = (short)f2bf(m1.y);
        A[6] = (short)f2bf(m1.z); A[7] = (short)f2bf(m1.w);
      } else if (c0 < 144) {
        int v0 = c0 - 128;
#pragma unroll
        for (int j = 0; j < 8; ++j) {
          float pv = fmaf(Wh[(v0 + j) * 3], rx,
                     fmaf(Wh[(v0 + j) * 3 + 1], ry, Wh[(v0 + j) * 3 + 2] * rz));
          A[j] = (short)f2bf(pv);
        }
      } else {
#pragma unroll
        for (int j = 0; j < 8; ++j) A[j] = 0;
      }
#pragma unroll
      for (int nt = 0; nt < 7; ++nt)
        acc[nt] = __builtin_amdgcn_mfma_f32_16x16x32_bf16(A, Bf[nt][ks], acc[nt], 0, 0, 0);
    }

#pragma unroll
    for (int nt = 0; nt < 5; ++nt)
#pragma unroll
      for (int r = 0; r < 4; ++r) {
        float v = acc[nt][r];
        ss[nt] += v; sq[nt] += v * v;
      }

#pragma unroll
    for (int nt = 0; nt < 7; ++nt)
#pragma unroll
      for (int r = 0; r < 4; ++r)
        lds[w][quad * 4 + r][nt * 16 + m] = f2bf(acc[nt][r]);
    __syncthreads();

    {
      int it = lane >> 2, sg = lane & 3;
      const uint4* sp = (const uint4*)&lds[w][it][sg * 16];
      uint4 d0 = sp[0], d1 = sp[1];
      *(uint4*)(t1g + (size_t)tile * 1024 + lane * 16) = d0;
      *(uint4*)(t1g + (size_t)tile * 1024 + lane * 16 + 8) = d1;
      const uint4* spk = (const uint4*)&lds[w][it][80 + sg * 8];
      *(uint4*)(akg + (size_t)tile * 512 + lane * 8) = spk[0];
      if (lane < 32) {
        const uint4* spv = (const uint4*)&lds[w][lane >> 1][64 + (lane & 1) * 8];
        *(uint4*)(tvg + (size_t)tile * 256 + lane * 8) = spv[0];
      }
    }
    __syncthreads();
  }

  float* slot = st1 + (blockIdx.x & 63) * 160;
#pragma unroll
  for (int nt = 0; nt < 5; ++nt) {
    float s = ss[nt];
    s += __shfl_xor(s, 16); s += __shfl_xor(s, 32);
    float q = sq[nt];
    q += __shfl_xor(q, 16); q += __shfl_xor(q, 32);
    if (lane < 16) {
      if (nt < 4) {
        atomicAdd(&slot[nt * 16 + lane], s);
        atomicAdd(&slot[64 + nt * 16 + lane], q);
      } else {
        atomicAdd(&slot[128 + lane], s);
        atomicAdd(&slot[144 + lane], q);
      }
    }
  }
}

// GEMM2: t2 = W2 @ relu(bn1(t1)); per-bn max/min of t2 -> fqpre; BN2 stats
__global__ void __launch_bounds__(256) k_g2(
    const ushort_t* __restrict__ t1g, const float* __restrict__ W2,
    const float* __restrict__ par, float* __restrict__ st2,
    float* __restrict__ fqpre)
{
  __shared__ ushort_t lds[4][80][68];
  int tid = threadIdx.x;
  int w = tid >> 6, lane = tid & 63;
  int m = lane & 15, quad = lane >> 4;
  int gw = blockIdx.x * 4 + w;

  bf16x8 Bf[4][2];
#pragma unroll
  for (int nt = 0; nt < 4; ++nt) {
    const float* wrow = W2 + (nt * 16 + m) * CHN;
#pragma unroll
    for (int ks = 0; ks < 2; ++ks) {
      int c0 = ks * 32 + quad * 8;
      float4 u = *(const float4*)(wrow + c0);
      float4 v = *(const float4*)(wrow + c0 + 4);
      bf16x8 f;
      f[0] = (short)f2bf(u.x); f[1] = (short)f2bf(u.y);
      f[2] = (short)f2bf(u.z); f[3] = (short)f2bf(u.w);
      f[4] = (short)f2bf(v.x); f[5] = (short)f2bf(v.y);
      f[6] = (short)f2bf(v.z); f[7] = (short)f2bf(v.w);
      Bf[nt][ks] = f;
    }
  }
  float pa[2][8], pb[2][8];
#pragma unroll
  for (int ks = 0; ks < 2; ++ks) {
    int c0 = ks * 32 + quad * 8;
    float4 a0 = *(const float4*)(par + c0);
    float4 a1 = *(const float4*)(par + c0 + 4);
    float4 b0 = *(const float4*)(par + 64 + c0);
    float4 b1 = *(const float4*)(par + 64 + c0 + 4);
    pa[ks][0] = a0.x; pa[ks][1] = a0.y; pa[ks][2] = a0.z; pa[ks][3] = a0.w;
    pa[ks][4] = a1.x; pa[ks][5] = a1.y; pa[ks][6] = a1.z; pa[ks][7] = a1.w;
    pb[ks][0] = b0.x; pb[ks][1] = b0.y; pb[ks][2] = b0.z; pb[ks][3] = b0.w;
    pb[ks][4] = b1.x; pb[ks][5] = b1.y; pb[ks][6] = b1.z; pb[ks][7] = b1.w;
  }

  float ss[4] = {0.f, 0.f, 0.f, 0.f}, sq[4] = {0.f, 0.f, 0.f, 0.f};

#pragma unroll 1
  for (int t5 = 0; t5 < 5; ++t5) {
    int tile = gw * 5 + t5;
    int item = tile * 16 + m;
    f32x4 acc[4];
#pragma unroll
    for (int nt = 0; nt < 4; ++nt)
#pragma unroll
      for (int r = 0; r < 4; ++r) acc[nt][r] = 0.f;
#pragma unroll
    for (int ks = 0; ks < 2; ++ks) {
      const ushort_t* tp = t1g + (size_t)item * 64 + ks * 32 + quad * 8;
      uint4 raw = *(const uint4*)tp;
      unsigned rw[4] = {raw.x, raw.y, raw.z, raw.w};
      bf16x8 A;
#pragma unroll
      for (int i = 0; i < 4; ++i) {
        float lo = bf2f((ushort_t)(rw[i] & 0xffffu));
        float hi = bf2f((ushort_t)(rw[i] >> 16));
        float h0 = fmaxf(fmaf(lo, pa[ks][2 * i], pb[ks][2 * i]), 0.f);
        float h1 = fmaxf(fmaf(hi, pa[ks][2 * i + 1], pb[ks][2 * i + 1]), 0.f);
        A[2 * i] = (short)f2bf(h0);
        A[2 * i + 1] = (short)f2bf(h1);
      }
#pragma unroll
      for (int nt = 0; nt < 4; ++nt)
        acc[nt] = __builtin_amdgcn_mfma_f32_16x16x32_bf16(A, Bf[nt][ks], acc[nt], 0, 0, 0);
    }
#pragma unroll
    for (int nt = 0; nt < 4; ++nt)
#pragma unroll
      for (int r = 0; r < 4; ++r) {
        float v = acc[nt][r];
        ss[nt] += v; sq[nt] += v * v;
        lds[w][t5 * 16 + quad * 4 + r][nt * 16 + m] = f2bf(v);
      }
  }
  __syncthreads();

  {
    int bnl = lane >> 4;
    int chb = (lane & 15) * 4;
    float mx0 = -3.4e38f, mx1 = -3.4e38f, mx2 = -3.4e38f, mx3 = -3.4e38f;
    float mn0 = 3.4e38f, mn1 = 3.4e38f, mn2 = 3.4e38f, mn3 = 3.4e38f;
#pragma unroll
    for (int j = 0; j < KK; ++j) {
      const uint2 rv = *(const uint2*)&lds[w][bnl * 20 + j][chb];
      float v0 = bf2f((ushort_t)(rv.x & 0xffffu));
      float v1 = bf2f((ushort_t)(rv.x >> 16));
      float v2 = bf2f((ushort_t)(rv.y & 0xffffu));
      float v3 = bf2f((ushort_t)(rv.y >> 16));
      mx0 = fmaxf(mx0, v0); mn0 = fminf(mn0, v0);
      mx1 = fmaxf(mx1, v1); mn1 = fminf(mn1, v1);
      mx2 = fmaxf(mx2, v2); mn2 = fminf(mn2, v2);
      mx3 = fmaxf(mx3, v3); mn3 = fminf(mn3, v3);
    }
    int bn = gw * 4 + bnl;
    *(float4*)(fqpre + (size_t)bn * 128 + chb) = make_float4(mx0, mx1, mx2, mx3);
    *(float4*)(fqpre + (size_t)bn * 128 + 64 + chb) = make_float4(mn0, mn1, mn2, mn3);
  }

  float* slot = st2 + (blockIdx.x & 63) * 128;
#pragma unroll
  for (int nt = 0; nt < 4; ++nt) {
    float s = ss[nt];
    s += __shfl_xor(s, 16); s += __shfl_xor(s, 32);
    float q = sq[nt];
    q += __shfl_xor(q, 16); q += __shfl_xor(q, 32);
    if (lane < 16) {
      atomicAdd(&slot[nt * 16 + lane], s);
      atomicAdd(&slot[64 + nt * 16 + lane], q);
    }
  }
}

// softmax over k + kv from cached ak/tv
#define P3P 16
__global__ void __launch_bounds__(320, 2) k_p3s(
    const ushort_t* __restrict__ akg, const ushort_t* __restrict__ tvg,
    const float* __restrict__ par, __hip_bfloat16* __restrict__ kvg)
{
  __shared__ float sl[P3P][KK][DKK + 1];
  __shared__ float sv[P3P][KK][DVV + 1];
  __shared__ float sm[P3P][DKK], ssi[P3P][DKK];
  int tid = threadIdx.x;
  int p = tid / KK, k = tid - p * KK;
  size_t item = (size_t)(blockIdx.x * P3P + p) * KK + k;
  const unsigned* ap = (const unsigned*)(akg + item * DKK);
#pragma unroll
  for (int i = 0; i < DKK / 2; ++i) {
    unsigned wv = ap[i];
    sl[p][k][2 * i]     = __uint_as_float(wv << 16);
    sl[p][k][2 * i + 1] = __uint_as_float(wv & 0xffff0000u);
  }
  const unsigned* vp = (const unsigned*)(tvg + item * DVV);
#pragma unroll
  for (int i = 0; i < DVV / 2; ++i) {
    unsigned wv = vp[i];
    float lo = __uint_as_float(wv << 16);
    float hi = __uint_as_float(wv & 0xffff0000u);
    sv[p][k][2 * i]     = fmaf(lo, par[128 + 2 * i],     par[144 + 2 * i]);
    sv[p][k][2 * i + 1] = fmaf(hi, par[128 + 2 * i + 1], par[144 + 2 * i + 1]);
  }
  __syncthreads();
  for (int pd = tid; pd < P3P * DKK; pd += 320) {
    int pp = pd >> 5, d = pd & 31;
    float m = -1e30f;
#pragma unroll
    for (int q = 0; q < KK; ++q) m = fmaxf(m, sl[pp][q][d]);
    float S = 0.f;
#pragma unroll
    for (int q = 0; q < KK; ++q) S += __expf(sl[pp][q][d] - m);
    sm[pp][d] = m; ssi[pp][d] = 1.f / S;
  }
  __syncthreads();
  for (int pd = tid; pd < P3P * DKK; pd += 320) {
    int pp = pd >> 5, d = pd & 31;
    float m = sm[pp][d], Si = ssi[pp][d];
    float a[DVV];
#pragma unroll
    for (int v = 0; v < DVV; ++v) a[v] = 0.f;
#pragma unroll
    for (int q = 0; q < KK; ++q) {
      float wgt = __expf(sl[pp][q][d] - m) * Si;
#pragma unroll
      for (int v = 0; v < DVV; ++v) a[v] = fmaf(wgt, sv[pp][q][v], a[v]);
    }
    __hip_bfloat162* dst = (__hip_bfloat162*)
        (kvg + ((size_t)(blockIdx.x * P3P + pp) * DKK + d) * DVV);
#pragma unroll
    for (int v = 0; v < DVV; v += 2) {
      float2 f2; f2.x = a[v]; f2.y = a[v + 1];
      dst[v >> 1] = __float22bfloat162_rn(f2);
    }
  }
}

// MFMA GEMM: q2 = Wq @ fq, fq reconstructed inline from fqpre (sign-aware).
__global__ void __launch_bounds__(256) k_gq(
    const float* __restrict__ fqpre, const float* __restrict__ Wq,
    const float* __restrict__ par, float* __restrict__ stq,
    float* __restrict__ q2g)
{
  int tid = threadIdx.x;
  int w = tid >> 6, lane = tid & 63;
  int m = lane & 15, quad = lane >> 4;
  int nt0 = (w & 1) * 8;
  int mt = blockIdx.x * 2 + (w >> 1);

  bf16x8 Bf[8][2];
#pragma unroll
  for (int nt = 0; nt < 8; ++nt) {
    const float* wrow = Wq + ((nt0 + nt) * 16 + m) * CHN;
#pragma unroll
    for (int ks = 0; ks < 2; ++ks) {
      int c0 = ks * 32 + quad * 8;
      float4 u = *(const float4*)(wrow + c0);
      float4 v = *(const float4*)(wrow + c0 + 4);
      bf16x8 f;
      f[0] = (short)f2bf(u.x); f[1] = (short)f2bf(u.y);
      f[2] = (short)f2bf(u.z); f[3] = (short)f2bf(u.w);
      f[4] = (short)f2bf(v.x); f[5] = (short)f2bf(v.y);
      f[6] = (short)f2bf(v.z); f[7] = (short)f2bf(v.w);
      Bf[nt][ks] = f;
    }
  }

  f32x4 acc[8];
#pragma unroll
  for (int nt = 0; nt < 8; ++nt)
#pragma unroll
    for (int r = 0; r < 4; ++r) acc[nt][r] = 0.f;

  int item = mt * 16 + m;
  const float* fp = fqpre + (size_t)item * 128;
#pragma unroll
  for (int ks = 0; ks < 2; ++ks) {
    int c0 = ks * 32 + quad * 8;
    float mxv[8], mnv[8], av[8], bv[8];
    *(float4*)&mxv[0] = *(const float4*)(fp + c0);
    *(float4*)&mxv[4] = *(const float4*)(fp + c0 + 4);
    *(float4*)&mnv[0] = *(const float4*)(fp + 64 + c0);
    *(float4*)&mnv[4] = *(const float4*)(fp + 64 + c0 + 4);
    *(float4*)&av[0] = *(const float4*)(par + 160 + c0);
    *(float4*)&av[4] = *(const float4*)(par + 160 + c0 + 4);
    *(float4*)&bv[0] = *(const float4*)(par + 224 + c0);
    *(float4*)&bv[4] = *(const float4*)(par + 224 + c0 + 4);
    bf16x8 A;
#pragma unroll
    for (int j = 0; j < 8; ++j) {
      float pick = (av[j] >= 0.f) ? mxv[j] : mnv[j];
      float fq = fmaxf(fmaf(av[j], pick, bv[j]), 0.f);
      A[j] = (short)f2bf(fq);
    }
#pragma unroll
    for (int nt = 0; nt < 8; ++nt)
      acc[nt] = __builtin_amdgcn_mfma_f32_16x16x32_bf16(A, Bf[nt][ks], acc[nt], 0, 0, 0);
  }

  float* slot = stq + (blockIdx.x & 63) * 512;
#pragma unroll
  for (int nt = 0; nt < 8; ++nt) {
    int o = (nt0 + nt) * 16 + m;
    float s = 0.f, q = 0.f;
#pragma unroll
    for (int r = 0; r < 4; ++r) {
      float v = acc[nt][r];
      q2g[(size_t)(mt * 16 + quad * 4 + r) * NQC + o] = v;
      s += v; q += v * v;
    }
    s += __shfl_xor(s, 16); s += __shfl_xor(s, 32);
    q += __shfl_xor(q, 16); q += __shfl_xor(q, 32);
    if (lane < 16) {
      atomicAdd(&slot[(nt0 + nt) * 16 + lane], s);
      atomicAdd(&slot[256 + (nt0 + nt) * 16 + lane], q);
    }
  }
}

__global__ void k_redq(const float* __restrict__ stq, const float* __restrict__ gq,
                       const float* __restrict__ bq, float* __restrict__ par)
{
  int o = threadIdx.x; // 256
  float s = 0.f, s2 = 0.f;
  for (int j = 0; j < 64; ++j) { s += stq[j * 512 + o]; s2 += stq[j * 512 + 256 + o]; }
  const float inv = 1.f / (float)BNTOT;
  float mu = s * inv, var = s2 * inv - mu * mu;
  float a = gq[o] * rsqrtf(var + EPSV);
  par[288 + o] = a; par[544 + o] = bq[o] - mu * a;
}

// out[b][h*16+v][n] = sum_d relu(bnq(q2))·kv. Block = (b, 32 n); LDS transposed
// [o][n] (+pad) so lanes read consecutive banks; 128B-contiguous out stores.
__global__ void __launch_bounds__(256) k_p4(const float* __restrict__ q2g,
                                            const __hip_bfloat16* __restrict__ kvg,
                                            const float* __restrict__ par,
                                            float* __restrict__ outp)
{
  __shared__ float sq2[NQC][33];        // [o][n]
  __shared__ unsigned skv[NQC][33];     // [dv/2][n], packed bf16 pair
  int t = threadIdx.x;
  int b = blockIdx.x >> 7, nc = blockIdx.x & 127;
  int bn0 = (b << 12) | (nc << 5);
#pragma unroll 4
  for (int i = t; i < 32 * NQC; i += 256) {
    int n = i >> 8, o = i & 255;
    float q = q2g[(size_t)(bn0 + n) * NQC + o];
    sq2[o][n] = fmaxf(fmaf(q, par[288 + o], par[544 + o]), 0.f);
  }
  const unsigned* kvp = (const unsigned*)kvg;
#pragma unroll 4
  for (int i = t; i < 32 * 256; i += 256) {
    int n = i >> 8, dv2 = i & 255;
    skv[dv2][n] = kvp[(size_t)(bn0 + n) * 256 + dv2];
  }
  __syncthreads();
  int n = t & 31, h = t >> 5;           // h = head 0..7
  float qr[DKK];
#pragma unroll
  for (int d = 0; d < DKK; ++d) qr[d] = sq2[h * DKK + d][n];
  int n_out = (nc << 5) + n;
  size_t ob = (size_t)BNTOT * 3 + (size_t)(b * 128 + h * 16) * NN + n_out;
#pragma unroll
  for (int vv = 0; vv < DVV; vv += 2) {
    float a0 = 0.f, a1 = 0.f;
#pragma unroll
    for (int d = 0; d < DKK; ++d) {
      unsigned pk = skv[(d * DVV + vv) >> 1][n];
      a0 = fmaf(qr[d], bf2f((ushort_t)(pk & 0xffffu)), a0);
      a1 = fmaf(qr[d], bf2f((ushort_t)(pk >> 16)), a1);
    }
    outp[ob + (size_t)vv * NN] = a0;
    outp[ob + (size_t)(vv + 1) * NN] = a1;
  }
}

// ---------- FALLBACK (round-5 proven path) ----------

__global__ void __launch_bounds__(256, 3) k_s1f(
    const float4* __restrict__ xyz4, const float* __restrict__ feat,
    const int* __restrict__ idxb, const float* __restrict__ W1,
    const float* __restrict__ Wv, const float* __restrict__ Wh,
    float* __restrict__ st1,
    __hip_bfloat16* __restrict__ t1g, __hip_bfloat16* __restrict__ tvg)
{
  int t = blockIdx.x * 256 + threadIdx.x;
  int bn = t / KK, k = t - bn * KK, b = bn >> 12;
  int nb = idxb[(size_t)bn * KK + k];
  const float* fme = feat + (size_t)bn * CFEAT;
  const float* fnb = feat + ((size_t)b * NN + nb) * CFEAT;
  float4 pn = xyz4[(size_t)b * NN + nb];
  float4 pm = xyz4[bn];
  float rx = pn.x - pm.x, ry = pn.y - pm.y, rz = pn.z - pm.z;
  float a1[CHN], av[DVV];
#pragma unroll
  for (int o = 0; o < CHN; ++o) a1[o] = 0.f;
#pragma unroll
  for (int o = 0; o < DVV; ++o) av[o] = 0.f;
#pragma unroll 1
  for (int ch = 0; ch < 9; ++ch) {
    float fc[16];
    build_chunk(ch, fme, fnb, rx, ry, rz, Wh, fc);
    accum_chunk<CHN>(W1, ch, fc, a1);
    accum_chunk<DVV>(Wv, ch, fc, av);
  }
  __hip_bfloat162* t1p = (__hip_bfloat162*)(t1g + (size_t)t * CHN);
#pragma unroll
  for (int o = 0; o < CHN; o += 2) {
    float2 f2; f2.x = a1[o]; f2.y = a1[o + 1];
    t1p[o >> 1] = __float22bfloat162_rn(f2);
  }
  __hip_bfloat162* tvp = (__hip_bfloat162*)(tvg + (size_t)t * DVV);
#pragma unroll
  for (int o = 0; o < DVV; o += 2) {
    float2 f2; f2.x = av[o]; f2.y = av[o + 1];
    tvp[o >> 1] = __float22bfloat162_rn(f2);
  }
  float* slot = st1 + (blockIdx.x & 63) * 160;
  int lane = threadIdx.x & 63;
#pragma unroll
  for (int o = 0; o < CHN; ++o) {
    float s = wred(a1[o]), s2 = wred(a1[o] * a1[o]);
    if (lane == 0) { atomicAdd(&slot[o], s); atomicAdd(&slot[CHN + o], s2); }
  }
#pragma unroll
  for (int o = 0; o < DVV; ++o) {
    float s = wred(av[o]), s2 = wred(av[o] * av[o]);
    if (lane == 0) { atomicAdd(&slot[128 + o], s); atomicAdd(&slot[128 + DVV + o], s2); }
  }
}

__global__ void __launch_bounds__(256, 4) k_skf(
    const float4* __restrict__ xyz4, const float* __restrict__ feat,
    const int* __restrict__ idxb, const float* __restrict__ Wk,
    const float* __restrict__ Wh, __hip_bfloat16* __restrict__ akg)
{
  int t = blockIdx.x * 256 + threadIdx.x;
  int bn = t / KK, k = t - bn * KK, b = bn >> 12;
  int nb = idxb[(size_t)bn * KK + k];
  const float* fme = feat + (size_t)bn * CFEAT;
  const float* fnb = feat + ((size_t)b * NN + nb) * CFEAT;
  float4 pn = xyz4[(size_t)b * NN + nb];
  float4 pm = xyz4[bn];
  float rx = pn.x - pm.x, ry = pn.y - pm.y, rz = pn.z - pm.z;
  float ak[DKK];
#pragma unroll
  for (int o = 0; o < DKK; ++o) ak[o] = 0.f;
#pragma unroll 1
  for (int ch = 0; ch < 9; ++ch) {
    float fc[16];
    build_chunk(ch, fme, fnb, rx, ry, rz, Wh, fc);
    accum_chunk<DKK>(Wk, ch, fc, ak);
  }
  __hip_bfloat162* akp = (__hip_bfloat162*)(akg + (size_t)t * DKK);
#pragma unroll
  for (int o = 0; o < DKK; o += 2) {
    float2 f2; f2.x = ak[o]; f2.y = ak[o + 1];
    akp[o >> 1] = __float22bfloat162_rn(f2);
  }
}

__global__ void __launch_bounds__(256, 4) k_s2f(
    const __hip_bfloat16* __restrict__ t1g, const float* __restrict__ W2,
    const float* __restrict__ par, float* __restrict__ st2)
{
  int t = blockIdx.x * 256 + threadIdx.x;
  const unsigned* tp = (const unsigned*)(t1g + (size_t)t * CHN);
  float h1[CHN];
#pragma unroll
  for (int i = 0; i < CHN / 2; ++i) {
    unsigned w = tp[i];
    float lo = __uint_as_float(w << 16);
    float hi = __uint_as_float(w & 0xffff0000u);
    h1[2 * i]     = fmaxf(fmaf(lo, par[2 * i],     par[64 + 2 * i]),     0.f);
    h1[2 * i + 1] = fmaxf(fmaf(hi, par[2 * i + 1], par[64 + 2 * i + 1]), 0.f);
  }
  float* slot = st2 + (blockIdx.x & 63) * 128;
  int lane = threadIdx.x & 63;
#pragma unroll 1
  for (int o = 0; o < CHN; ++o) {
    const float* w = W2 + o * CHN;
    float c0 = 0.f, c1 = 0.f, c2 = 0.f, c3 = 0.f;
#pragma unroll
    for (int c = 0; c < CHN; c += 4) {
      c0 = fmaf(w[c + 0], h1[c + 0], c0); c1 = fmaf(w[c + 1], h1[c + 1], c1);
      c2 = fmaf(w[c + 2], h1[c + 2], c2); c3 = fmaf(w[c + 3], h1[c + 3], c3);
    }
    float v = (c0 + c1) + (c2 + c3);
    float s = wred(v), s2 = wred(v * v);
    if (lane == 0) { atomicAdd(&slot[o], s); atomicAdd(&slot[64 + o], s2); }
  }
}

__global__ void __launch_bounds__(320, 2) k_p3f(
    const __hip_bfloat16* __restrict__ t1g, const __hip_bfloat16* __restrict__ akg,
    const __hip_bfloat16* __restrict__ tvg, const float* __restrict__ W2,
    const float* __restrict__ par, float* __restrict__ fqg,
    __hip_bfloat16* __restrict__ kvg)
{
  __shared__ float sl[P3P][KK][DKK + 1];
  __shared__ float sv[P3P][KK][DVV + 1];
  __shared__ unsigned sfq[P3P][CHN];
  __shared__ float sm[P3P][DKK], ssi[P3P][DKK];
  int tid = threadIdx.x;
  for (int i = tid; i < P3P * CHN; i += 320) ((unsigned*)sfq)[i] = 0u;
  __syncthreads();
  int p = tid / KK, k = tid - p * KK;
  size_t item = (size_t)(blockIdx.x * P3P + p) * KK + k;
  const unsigned* ap = (const unsigned*)(akg + item * DKK);
#pragma unroll
  for (int i = 0; i < DKK / 2; ++i) {
    unsigned w = ap[i];
    sl[p][k][2 * i]     = __uint_as_float(w << 16);
    sl[p][k][2 * i + 1] = __uint_as_float(w & 0xffff0000u);
  }
  const unsigned* vp = (const unsigned*)(tvg + item * DVV);
#pragma unroll
  for (int i = 0; i < DVV / 2; ++i) {
    unsigned w = vp[i];
    float lo = __uint_as_float(w << 16);
    float hi = __uint_as_float(w & 0xffff0000u);
    sv[p][k][2 * i]     = fmaf(lo, par[128 + 2 * i],     par[144 + 2 * i]);
    sv[p][k][2 * i + 1] = fmaf(hi, par[128 + 2 * i + 1], par[144 + 2 * i + 1]);
  }
  const unsigned* tp = (const unsigned*)(t1g + item * CHN);
  float h1[CHN];
#pragma unroll
  for (int i = 0; i < CHN / 2; ++i) {
    unsigned w = tp[i];
    float lo = __uint_as_float(w << 16);
    float hi = __uint_as_float(w & 0xffff0000u);
    h1[2 * i]     = fmaxf(fmaf(lo, par[2 * i],     par[64 + 2 * i]),     0.f);
    h1[2 * i + 1] = fmaxf(fmaf(hi, par[2 * i + 1], par[64 + 2 * i + 1]), 0.f);
  }
#pragma unroll 1
  for (int o = 0; o < CHN; ++o) {
    const float* w = W2 + o * CHN;
    float c0 = 0.f, c1 = 0.f, c2 = 0.f, c3 = 0.f;
#pragma unroll
    for (int c = 0; c < CHN; c += 4) {
      c0 = fmaf(w[c + 0], h1[c + 0], c0); c1 = fmaf(w[c + 1], h1[c + 1], c1);
      c2 = fmaf(w[c + 2], h1[c + 2], c2); c3 = fmaf(w[c + 3], h1[c + 3], c3);
    }
    float v = (c0 + c1) + (c2 + c3);
    float h2 = fmaxf(fmaf(v, par[160 + o], par[224 + o]), 0.f);
    atomicMax(&sfq[p][o], __float_as_uint(h2));
  }
  __syncthreads();
  for (int i = tid; i < P3P * CHN; i += 320)
    fqg[(size_t)blockIdx.x * (P3P * CHN) + i] = __uint_as_float(sfq[i >> 6][i & 63]);
  for (int pd = tid; pd < P3P * DKK; pd += 320) {
    int pp = pd >> 5, d = pd & 31;
    float m = -1e30f;
#pragma unroll
    for (int q = 0; q < KK; ++q) m = fmaxf(m, sl[pp][q][d]);
    float S = 0.f;
#pragma unroll
    for (int q = 0; q < KK; ++q) S += __expf(sl[pp][q][d] - m);
    sm[pp][d] = m; ssi[pp][d] = 1.f / S;
  }
  __syncthreads();
  for (int pd = tid; pd < P3P * DKK; pd += 320) {
    int pp = pd >> 5, d = pd & 31;
    float m = sm[pp][d], Si = ssi[pp][d];
    float a[DVV];
#pragma unroll
    for (int v = 0; v < DVV; ++v) a[v] = 0.f;
#pragma unroll
    for (int q = 0; q < KK; ++q) {
      float wgt = __expf(sl[pp][q][d] - m) * Si;
#pragma unroll
      for (int v = 0; v < DVV; ++v) a[v] = fmaf(wgt, sv[pp][q][v], a[v]);
    }
    __hip_bfloat162* dst = (__hip_bfloat162*)
        (kvg + ((size_t)(blockIdx.x * P3P + pp) * DKK + d) * DVV);
#pragma unroll
    for (int v = 0; v < DVV; v += 2) {
      float2 f2; f2.x = a[v]; f2.y = a[v + 1];
      dst[v >> 1] = __float22bfloat162_rn(f2);
    }
  }
}

__global__ void __launch_bounds__(128, 2) k_pqf(const float* __restrict__ fqg,
                                                const float* __restrict__ Wq,
                                                float* __restrict__ stq,
                                                float* __restrict__ q2g)
{
  int bn = blockIdx.x * 128 + threadIdx.x;
  float fq[CHN];
#pragma unroll
  for (int c = 0; c < CHN; c += 4) {
    float4 v4 = *(const float4*)(fqg + (size_t)bn * CHN + c);
    fq[c] = v4.x; fq[c + 1] = v4.y; fq[c + 2] = v4.z; fq[c + 3] = v4.w;
  }
  float* slot = stq + (blockIdx.x & 63) * 512;
  int lane = threadIdx.x & 63;
#pragma unroll 1
  for (int o = 0; o < NQC; ++o) {
    const float* w = Wq + o * CHN;
    float a0 = 0.f, a1 = 0.f, a2 = 0.f, a3 = 0.f;
#pragma unroll
    for (int c = 0; c < CHN; c += 4) {
      a0 = fmaf(w[c], fq[c], a0); a1 = fmaf(w[c + 1], fq[c + 1], a1);
      a2 = fmaf(w[c + 2], fq[c + 2], a2); a3 = fmaf(w[c + 3], fq[c + 3], a3);
    }
    float v = (a0 + a1) + (a2 + a3);
    q2g[(size_t)bn * NQC + o] = v;
    float s = wred(v), s2 = wred(v * v);
    if (lane == 0) { atomicAdd(&slot[o], s); atomicAdd(&slot[256 + o], s2); }
  }
}

__global__ void __launch_bounds__(64) k_p4f(const float* __restrict__ q2g,
                                            const __hip_bfloat16* __restrict__ kvg,
                                            const float* __restrict__ par,
                                            float* __restrict__ outp)
{
  __shared__ float sq2[NQC], skv[DKK * DVV];
  int t = threadIdx.x;
  int b = blockIdx.x & 7, n = blockIdx.x >> 3;
  int bn = (b << 12) | n;
#pragma unroll
  for (int j = 0; j < 8; ++j)
    skv[t + 64 * j] = __bfloat162float(kvg[(size_t)bn * 512 + t + 64 * j]);
#pragma unroll
  for (int j = 0; j < 4; ++j) {
    int o = t + 64 * j;
    float v = q2g[(size_t)bn * NQC + o];
    sq2[o] = fmaxf(fmaf(v, par[288 + o], par[544 + o]), 0.f);
  }
  __syncthreads();
#pragma unroll
  for (int j = 0; j < 2; ++j) {
    int ch = t + 64 * j, h = ch >> 4, vv = ch & 15;
    float a = 0.f;
#pragma unroll
    for (int d = 0; d < DKK; ++d) a = fmaf(sq2[h * DKK + d], skv[d * DVV + vv], a);
    outp[(size_t)BNTOT * 3 + ((size_t)(b * 128 + ch)) * NN + n] = a;
  }
}

// ---------- launch ----------

extern "C" void kernel_launch(void* const* d_in, const int* in_sizes, int n_in,
                              void* d_out, int out_size, void* d_ws, size_t ws_size,
                              hipStream_t stream)
{
  const float* x  = (const float*)d_in[0];
  const float* W1 = (const float*)d_in[1];
  const float* g1 = (const float*)d_in[2];
  const float* b1 = (const float*)d_in[3];
  const float* W2 = (const float*)d_in[4];
  const float* g2 = (const float*)d_in[5];
  const float* b2 = (const float*)d_in[6];
  const float* Wv = (const float*)d_in[7];
  const float* gv = (const float*)d_in[8];
  const float* bv = (const float*)d_in[9];
  const float* Wk = (const float*)d_in[10];
  const float* Wq = (const float*)d_in[11];
  const float* gq = (const float*)d_in[12];
  const float* bq = (const float*)d_in[13];
  const float* Wh = (const float*)d_in[14];

  float* ws = (float*)d_ws;
  float4* xyz4 = (float4*)ws;                      // 131072
  float*  feat = ws + 131072;                      // 2097152
  int*    idxb = (int*)(ws + 2228224);             // 655360
  float*  st1  = ws + 2883584;                     // 10240
  float*  st2  = ws + 2893824;                     // 8192
  float*  stq  = ws + 2902016;                     // 32768
  float*  par  = ws + 2934784;                     // 800
  float*  fqg  = ws + 2935584;                     // 2097152
  __hip_bfloat16* kvg = (__hip_bfloat16*)(ws + 5032736);  // 8388608 fw
  float*  outp = (float*)d_out;

  ushort_t* t1g = (ushort_t*)(ws + 13421344);      // 20971520 fw
  ushort_t* akg = (ushort_t*)(ws + 34392864);      // 10485760 fw
  ushort_t* tvg = (ushort_t*)(ws + 44878624);      //  5242880 fw
  float*    fqpre = ws + 50121504;                 //  4194304 fw
  float*    q2g = ws + 13421344;                   // alias t1g (dead after k_g2)

  const size_t NEW_NEED  = (size_t)54315808 * 4;   // ~217.3 MB (MFMA path)

  hipMemsetAsync(st1, 0, (size_t)(10240 + 8192 + 32768) * sizeof(float), stream);
  k_prep<<<128, 256, 0, stream>>>(x, xyz4, feat, outp);
  k_knn <<<512, 768, 0, stream>>>(xyz4, idxb);

  if (ws_size >= NEW_NEED) {
    k_g1  <<<2560, 256, 0, stream>>>(xyz4, feat, idxb, W1, Wv, Wk, Wh, st1, t1g, akg, tvg);
    k_red1<<<1, 128, 0, stream>>>(st1, g1, b1, gv, bv, par);
    k_g2  <<<2048, 256, 0, stream>>>(t1g, W2, par, st2, fqpre);
    k_red2<<<1, 64, 0, stream>>>(st2, g2, b2, par);
    k_p3s <<<2048, 320, 0, stream>>>(akg, tvg, par, kvg);
    k_gq  <<<1024, 256, 0, stream>>>(fqpre, Wq, par, stq, q2g);
    k_redq<<<1, 256, 0, stream>>>(stq, gq, bq, par);
    k_p4  <<<1024, 256, 0, stream>>>(q2g, kvg, par, outp);
  } else {
    __hip_bfloat16* t1b = (__hip_bfloat16*)t1g;
    __hip_bfloat16* akb = (__hip_bfloat16*)akg;
    __hip_bfloat16* tvb = (__hip_bfloat16*)tvg;
    float* q2f = ws + 34392864;                    // alias akg region
    k_s1f <<<2560, 256, 0, stream>>>(xyz4, feat, idxb, W1, Wv, Wh, st1, t1b, tvb);
    k_skf <<<2560, 256, 0, stream>>>(xyz4, feat, idxb, Wk, Wh, akb);
    k_red1<<<1, 128, 0, stream>>>(st1, g1, b1, gv, bv, par);
    k_s2f <<<2560, 256, 0, stream>>>(t1b, W2, par, st2);
    k_red2<<<1, 64, 0, stream>>>(st2, g2, b2, par);
    k_p3f <<<2048, 320, 0, stream>>>(t1b, akb, tvb, W2, par, fqg, kvg);
    k_pqf <<<256, 128, 0, stream>>>(fqg, Wq, stq, q2f);
    k_redq<<<1, 256, 0, stream>>>(stq, gq, bq, par);
    k_p4f <<<32768, 64, 0, stream>>>(q2f, kvg, par, outp);
  }
}